// Round 1
// baseline (567.176 us; speedup 1.0000x reference)
//
#include <hip/hip_runtime.h>

#define DEV static __device__ __forceinline__

typedef __attribute__((ext_vector_type(8))) short bf16x8;
typedef __attribute__((ext_vector_type(4))) short short4v;
typedef __attribute__((ext_vector_type(4))) float f32x4;

DEV f32x4 mfma16(bf16x8 a, bf16x8 b, f32x4 c){
  return __builtin_amdgcn_mfma_f32_16x16x32_bf16(a, b, c, 0, 0, 0);
}
DEV float bf2f(short s){ union{unsigned u; float f;} v; v.u=((unsigned)(unsigned short)s)<<16; return v.f; }
DEV short f2bf(float f){ union{float f; unsigned u;} v; v.f=f; unsigned r=v.u+0x7fffu+((v.u>>16)&1u); return (short)(r>>16); }
DEV void gload16(const void* g, void* l){
  __builtin_amdgcn_global_load_lds((const __attribute__((address_space(1))) void*)g,
                                   (__attribute__((address_space(3))) void*)l, 16, 0, 0);
}

enum { EPI_BF16=0, EPI_SWIGLU=1, EPI_RESID=2, EPI_FINAL=3, EPI_V=4, EPI_K=5, EPI_Q=6 };

// ---------------- weight convert f32 -> bf16 ----------------
__global__ void k_convert(const float* __restrict__ in, short* __restrict__ out, int n){
  int i = (blockIdx.x * 256 + threadIdx.x) * 4;
  if (i >= n) return;
  float4 v = *(const float4*)(in + i);
  short4v o; o.x=f2bf(v.x); o.y=f2bf(v.y); o.z=f2bf(v.z); o.w=f2bf(v.w);
  *(short4v*)(out + i) = o;
}

// ---------------- RMSNorm over 768 f32 -> bf16 (1 wave / row) ----------------
__global__ void k_rmsnorm(const float* __restrict__ x, const float* __restrict__ g,
                          short* __restrict__ out){
  int row = blockIdx.x*4 + (threadIdx.x>>6);
  int lane = threadIdx.x & 63;
  const float* xr = x + (size_t)row*768;
  float4 v[3];
  float ss = 0.f;
  #pragma unroll
  for (int i=0;i<3;i++){
    v[i] = *(const float4*)(xr + i*256 + lane*4);
    ss += v[i].x*v[i].x + v[i].y*v[i].y + v[i].z*v[i].z + v[i].w*v[i].w;
  }
  #pragma unroll
  for (int d=32; d>0; d>>=1) ss += __shfl_xor(ss, d);
  float sc = rsqrtf(ss*(1.f/768.f) + 1.1920929e-7f);
  #pragma unroll
  for (int i=0;i<3;i++){
    int c0 = i*256 + lane*4;
    float4 gv = *(const float4*)(g + c0);
    short4v o;
    o.x = f2bf(v[i].x*sc*gv.x); o.y = f2bf(v[i].y*sc*gv.y);
    o.z = f2bf(v[i].z*sc*gv.z); o.w = f2bf(v[i].w*sc*gv.w);
    *(short4v*)(out + (size_t)row*768 + c0) = o;
  }
}

// ---------------- NT GEMM: C[M,N] = A[M,K] * B[N,K]^T, m97 structure ----------------
// 128x128 tile, BK=32, 4 waves (each 64x64 = 4x4 frags of 16x16x32 MFMA).
template<int EPI>
__launch_bounds__(256, 2)
__global__ void k_gemm(const short* __restrict__ Aptr, const short* __restrict__ Bptr,
                       void* __restrict__ Cout, const float* __restrict__ bias,
                       const void* __restrict__ aux, int M, int N, int K){
  __shared__ short ldsA[128*32];
  __shared__ short ldsB[128*32];
  const int t = threadIdx.x;
  const int wave = t >> 6, lane = t & 63;
  const int l15 = lane & 15, l4 = lane >> 4;
  const int bm = blockIdx.y, bn = blockIdx.x;
  const int wr = wave >> 1, wc = wave & 1;

  f32x4 acc[4][4] = {};

  // staging: wave stages rows [wave*32, wave*32+32); lane -> row wave*32+(lane>>2)+{0,16}, 16B chunk (lane&3)
  const short* Ag = Aptr + (size_t)(bm*128 + wave*32 + (lane>>2))*K + (lane&3)*8;
  const short* Bg = Bptr + (size_t)(bn*128 + wave*32 + (lane>>2))*K + (lane&3)*8;
  short* lA = ldsA + wave*1024;  // wave-uniform LDS dest (1KB per gload16 call)
  short* lB = ldsB + wave*1024;

  for (int k0 = 0; k0 < K; k0 += 32){
    __syncthreads();
    gload16(Ag + k0,               lA);
    gload16(Ag + k0 + 16*(size_t)K, lA + 512);
    gload16(Bg + k0,               lB);
    gload16(Bg + k0 + 16*(size_t)K, lB + 512);
    __syncthreads();
    bf16x8 af[4], bfr[4];
    #pragma unroll
    for (int m=0;m<4;m++) af[m]  = *(const bf16x8*)(ldsA + (wr*64 + m*16 + l15)*32 + l4*8);
    #pragma unroll
    for (int n=0;n<4;n++) bfr[n] = *(const bf16x8*)(ldsB + (wc*64 + n*16 + l15)*32 + l4*8);
    #pragma unroll
    for (int m=0;m<4;m++)
      #pragma unroll
      for (int n=0;n<4;n++)
        acc[m][n] = mfma16(af[m], bfr[n], acc[m][n]);
  }

  const int row0 = bm*128 + wr*64;
  const int col0 = bn*128 + wc*64;

  if constexpr (EPI == EPI_BF16){
    short* C = (short*)Cout;
    float bvv[4];
    #pragma unroll
    for (int n=0;n<4;n++) bvv[n] = bias ? bias[col0 + n*16 + l15] : 0.f;
    #pragma unroll
    for (int m=0;m<4;m++)
      #pragma unroll
      for (int j=0;j<4;j++){
        size_t rb = (size_t)(row0 + m*16 + l4*4 + j)*N + col0 + l15;
        #pragma unroll
        for (int n=0;n<4;n++) C[rb + n*16] = f2bf(acc[m][n][j] + bvv[n]);
      }
  } else if constexpr (EPI == EPI_SWIGLU){
    short* C = (short*)Cout;
    const short* hinp = (const short*)aux;
    #pragma unroll
    for (int m=0;m<4;m++)
      #pragma unroll
      for (int j=0;j<4;j++){
        size_t rb = (size_t)(row0 + m*16 + l4*4 + j)*N + col0 + l15;
        #pragma unroll
        for (int n=0;n<4;n++){
          float gt = acc[m][n][j];
          C[rb + n*16] = f2bf(bf2f(hinp[rb + n*16]) * gt / (1.f + __expf(-gt)));
        }
      }
  } else if constexpr (EPI == EPI_RESID){
    float* C = (float*)Cout;
    const float* srcf = (const float*)aux;
    float bvv[4];
    #pragma unroll
    for (int n=0;n<4;n++) bvv[n] = bias[col0 + n*16 + l15];
    #pragma unroll
    for (int m=0;m<4;m++)
      #pragma unroll
      for (int j=0;j<4;j++){
        size_t rb = (size_t)(row0 + m*16 + l4*4 + j)*N + col0 + l15;
        #pragma unroll
        for (int n=0;n<4;n++) C[rb + n*16] = acc[m][n][j] + bvv[n] + srcf[rb + n*16];
      }
  } else if constexpr (EPI == EPI_FINAL){
    float* C = (float*)Cout;
    const short* yv = (const short*)aux;
    float bvv[4];
    #pragma unroll
    for (int n=0;n<4;n++) bvv[n] = bias[col0 + n*16 + l15];
    #pragma unroll
    for (int m=0;m<4;m++)
      #pragma unroll
      for (int j=0;j<4;j++){
        size_t rb = (size_t)(row0 + m*16 + l4*4 + j)*N + col0 + l15;
        #pragma unroll
        for (int n=0;n<4;n++) C[rb + n*16] = acc[m][n][j] + bvv[n] + bf2f(yv[rb + n*16]);
      }
  } else { // EPI_V / EPI_K / EPI_Q : remap to [B,H,S,DH]; rope for Q,K; 0.125 scale for Q
    short* Obuf = (short*)Cout;
    const int h = col0 >> 6;  // wave's 64 cols == exactly one head
    float bvv[4];
    #pragma unroll
    for (int n=0;n<4;n++) bvv[n] = bias[col0 + n*16 + l15];
    float invf0 = 0.f, invf1 = 0.f;
    if constexpr (EPI != EPI_V){
      const float RC = 0.41524101186092034f;  // log2(10000)/32
      invf0 = exp2f(-(float)l15 * RC);
      invf1 = exp2f(-(float)(16 + l15) * RC);
    }
    #pragma unroll
    for (int m=0;m<4;m++){
      #pragma unroll
      for (int j=0;j<4;j++){
        int row = row0 + m*16 + l4*4 + j;
        int b = row >> 11, s = row & 2047;
        size_t obase = ((size_t)(b*12 + h)*2048 + (size_t)s)*64;
        float a0 = acc[m][0][j] + bvv[0];
        float a1 = acc[m][1][j] + bvv[1];
        float a2 = acc[m][2][j] + bvv[2];
        float a3 = acc[m][3][j] + bvv[3];
        float o0, o1, o2, o3;
        if constexpr (EPI == EPI_V){
          o0=a0; o1=a1; o2=a2; o3=a3;
        } else {
          float sn0, cs0, sn1, cs1;
          __sincosf((float)s * invf0, &sn0, &cs0);
          __sincosf((float)s * invf1, &sn1, &cs1);
          o0 = a0*cs0 - a2*sn0;   // dh<32: x*cos - x[dh+32]*sin
          o1 = a1*cs1 - a3*sn1;
          o2 = a2*cs0 + a0*sn0;   // dh>=32: x*cos + x[dh-32]*sin
          o3 = a3*cs1 + a1*sn1;
          if constexpr (EPI == EPI_Q){ o0*=0.125f; o1*=0.125f; o2*=0.125f; o3*=0.125f; }
        }
        Obuf[obase + l15]      = f2bf(o0);
        Obuf[obase + 16 + l15] = f2bf(o1);
        Obuf[obase + 32 + l15] = f2bf(o2);
        Obuf[obase + 48 + l15] = f2bf(o3);
      }
    }
  }
}

// ---------------- Flash attention (non-causal), Q pre-scaled by 1/8 ----------------
// grid (S/128, B*H). 4 waves; wave owns 32 q-rows. KV tile = 128.
__launch_bounds__(256, 2)
__global__ void k_attn(const short* __restrict__ Q, const short* __restrict__ Kb,
                       const short* __restrict__ Vb, short* __restrict__ ctx){
  __shared__ short Kt[128*64];     // row 128B, 16B chunk c stored at c^(r&7)
  __shared__ short Vt[64*128];     // transposed, row dh 256B, chunk c at c^(dh&15)
  __shared__ short Plds[4*32*128]; // per-wave P, row qr 256B, chunk c at c^(qr&15)
  const int t = threadIdx.x, wave = t>>6, lane = t&63;
  const int l15 = lane&15, l4 = lane>>4;
  const int qt = blockIdx.x, bh = blockIdx.y;
  const short* Qh = Q  + (size_t)bh*2048*64;
  const short* Kh = Kb + (size_t)bh*2048*64;
  const short* Vh = Vb + (size_t)bh*2048*64;

  bf16x8 qf[2][2];
  #pragma unroll
  for (int m=0;m<2;m++)
    #pragma unroll
    for (int kf=0;kf<2;kf++)
      qf[m][kf] = *(const bf16x8*)(Qh + (size_t)(qt*128 + wave*32 + m*16 + l15)*64 + kf*32 + l4*8);

  f32x4 cacc[2][4] = {};
  float mrun[2][4], lrun[2][4];
  #pragma unroll
  for (int m=0;m<2;m++)
    #pragma unroll
    for (int j=0;j<4;j++){ mrun[m][j] = -1e30f; lrun[m][j] = 0.f; }

  short* Pw = Plds + wave*4096;

  for (int kv0 = 0; kv0 < 2048; kv0 += 128){
    __syncthreads();
    #pragma unroll
    for (int i=0;i<4;i++){
      int id = i*256 + t;
      int r = id >> 3, c = id & 7;
      bf16x8 kv = *(const bf16x8*)(Kh + (size_t)(kv0+r)*64 + c*8);
      *(bf16x8*)(Kt + r*64 + ((c ^ (r&7))<<3)) = kv;
      bf16x8 vv = *(const bf16x8*)(Vh + (size_t)(kv0+r)*64 + c*8);
      #pragma unroll
      for (int j=0;j<8;j++){
        int dh = c*8 + j;
        Vt[dh*128 + (((r>>3) ^ (dh&15))<<3) + (r&7)] = vv[j];
      }
    }
    __syncthreads();

    f32x4 sacc[2][8] = {};
    #pragma unroll
    for (int kf=0;kf<2;kf++){
      #pragma unroll
      for (int n=0;n<8;n++){
        int r = n*16 + l15;
        int c = kf*4 + l4;
        bf16x8 bfr = *(const bf16x8*)(Kt + r*64 + ((c ^ (r&7))<<3));
        sacc[0][n] = mfma16(qf[0][kf], bfr, sacc[0][n]);
        sacc[1][n] = mfma16(qf[1][kf], bfr, sacc[1][n]);
      }
    }

    // online softmax: row qr lives across the 16 lanes sharing l4; reduce over lane bits 0..3
    #pragma unroll
    for (int m=0;m<2;m++){
      #pragma unroll
      for (int j=0;j<4;j++){
        float mx = sacc[m][0][j];
        #pragma unroll
        for (int n=1;n<8;n++) mx = fmaxf(mx, sacc[m][n][j]);
        #pragma unroll
        for (int d=1; d<16; d<<=1) mx = fmaxf(mx, __shfl_xor(mx, d));
        float mnew = fmaxf(mrun[m][j], mx);
        float fac = __expf(mrun[m][j] - mnew);
        mrun[m][j] = mnew;
        float psum = 0.f;
        #pragma unroll
        for (int n=0;n<8;n++){
          float p = __expf(sacc[m][n][j] - mnew);
          sacc[m][n][j] = p;
          psum += p;
        }
        #pragma unroll
        for (int d=1; d<16; d<<=1) psum += __shfl_xor(psum, d);
        lrun[m][j] = lrun[m][j]*fac + psum;
        #pragma unroll
        for (int nf=0;nf<4;nf++) cacc[m][nf][j] *= fac;
      }
    }

    // P -> LDS (bf16), swizzled; same-wave RAW handled by compiler lgkmcnt
    #pragma unroll
    for (int m=0;m<2;m++){
      #pragma unroll
      for (int j=0;j<4;j++){
        int qr = m*16 + l4*4 + j;
        #pragma unroll
        for (int n=0;n<8;n++){
          int kc = n*16 + l15;
          Pw[qr*128 + (((kc>>3) ^ (qr&15))<<3) + (kc&7)] = f2bf(sacc[m][n][j]);
        }
      }
    }

    // PV
    #pragma unroll
    for (int ks=0;ks<4;ks++){
      bf16x8 pa[2];
      #pragma unroll
      for (int m=0;m<2;m++)
        pa[m] = *(const bf16x8*)(Pw + (m*16 + l15)*128 + (((ks*4 + l4) ^ l15)<<3));
      #pragma unroll
      for (int nf=0;nf<4;nf++){
        int dh = nf*16 + l15;
        bf16x8 vf = *(const bf16x8*)(Vt + dh*128 + (((ks*4 + l4) ^ (dh&15))<<3));
        cacc[0][nf] = mfma16(pa[0], vf, cacc[0][nf]);
        cacc[1][nf] = mfma16(pa[1], vf, cacc[1][nf]);
      }
    }
  }

  const int b = bh / 12, h = bh % 12;
  #pragma unroll
  for (int m=0;m<2;m++){
    #pragma unroll
    for (int j=0;j<4;j++){
      float inv = 1.f / lrun[m][j];
      int s = qt*128 + wave*32 + m*16 + l4*4 + j;
      size_t base = ((size_t)b*2048 + s)*768 + h*64;
      #pragma unroll
      for (int nf=0;nf<4;nf++)
        ctx[base + nf*16 + l15] = f2bf(cacc[m][nf][j] * inv);
    }
  }
}

extern "C" void kernel_launch(void* const* d_in, const int* in_sizes, int n_in,
                              void* d_out, int out_size, void* d_ws, size_t ws_size,
                              hipStream_t stream){
  (void)in_sizes; (void)n_in; (void)out_size;
  const float* src   = (const float*)d_in[0];
  const float* wq    = (const float*)d_in[1];
  const float* bq    = (const float*)d_in[2];
  const float* wk    = (const float*)d_in[3];
  const float* bk    = (const float*)d_in[4];
  const float* wv    = (const float*)d_in[5];
  const float* bv    = (const float*)d_in[6];
  const float* wo    = (const float*)d_in[7];
  const float* bo    = (const float*)d_in[8];
  const float* wfc1  = (const float*)d_in[9];
  const float* bfc1  = (const float*)d_in[10];
  const float* win   = (const float*)d_in[11];
  const float* wgate = (const float*)d_in[12];
  const float* wfc2  = (const float*)d_in[13];
  const float* bfc2  = (const float*)d_in[14];
  const float* gattn = (const float*)d_in[15];
  const float* gffn  = (const float*)d_in[16];

  char* ws = (char*)d_ws;
  constexpr size_t SZ_W768  = 768ull*768*2;
  constexpr size_t SZ_WFC   = 3072ull*768*2;
  constexpr size_t SZ_WFF   = 3072ull*3072*2;
  constexpr size_t SZ_ACT   = 4096ull*768*2;
  constexpr size_t SZ_ACTF  = 4096ull*768*4;
  constexpr size_t SZ_H     = 4096ull*3072*2;
  constexpr size_t OFF_WQ    = 0;
  constexpr size_t OFF_WK    = OFF_WQ + SZ_W768;
  constexpr size_t OFF_WV    = OFF_WK + SZ_W768;
  constexpr size_t OFF_WO    = OFF_WV + SZ_W768;
  constexpr size_t OFF_WFC1  = OFF_WO + SZ_W768;
  constexpr size_t OFF_WIN   = OFF_WFC1 + SZ_WFC;
  constexpr size_t OFF_WGATE = OFF_WIN + SZ_WFF;
  constexpr size_t OFF_WFC2  = OFF_WGATE + SZ_WFF;
  constexpr size_t OFF_XN    = OFF_WFC2 + SZ_WFC;   // xn, later ctx
  constexpr size_t OFF_Q     = OFF_XN + SZ_ACT;     // q, later y
  constexpr size_t OFF_K     = OFF_Q + SZ_ACT;      // k; h1 region starts here
  constexpr size_t OFF_V     = OFF_K + SZ_ACT;
  constexpr size_t OFF_RES   = OFF_V + SZ_ACT;      // f32 resid
  constexpr size_t OFF_HIN   = OFF_RES + SZ_ACTF;
  constexpr size_t OFF_H2    = OFF_HIN + SZ_H;
  constexpr size_t WS_NEED   = OFF_H2 + SZ_H;       // ~140 MB
  if (ws_size < WS_NEED) return;

  short* wq_b    = (short*)(ws+OFF_WQ);
  short* wk_b    = (short*)(ws+OFF_WK);
  short* wv_b    = (short*)(ws+OFF_WV);
  short* wo_b    = (short*)(ws+OFF_WO);
  short* wfc1_b  = (short*)(ws+OFF_WFC1);
  short* win_b   = (short*)(ws+OFF_WIN);
  short* wgate_b = (short*)(ws+OFF_WGATE);
  short* wfc2_b  = (short*)(ws+OFF_WFC2);
  short* xn      = (short*)(ws+OFF_XN);
  short* ctxb    = (short*)(ws+OFF_XN);   // reuse
  short* qb      = (short*)(ws+OFF_Q);
  short* yb      = (short*)(ws+OFF_Q);    // reuse
  short* kb2     = (short*)(ws+OFF_K);
  short* vb2     = (short*)(ws+OFF_V);
  float* resid   = (float*)(ws+OFF_RES);
  short* h1      = (short*)(ws+OFF_K);    // reuse k+v+resid (exactly 25165824 B)
  short* hin     = (short*)(ws+OFF_HIN);
  short* h2      = (short*)(ws+OFF_H2);

  k_convert<<<576,  256, 0, stream>>>(wq,    wq_b,    589824);
  k_convert<<<576,  256, 0, stream>>>(wk,    wk_b,    589824);
  k_convert<<<576,  256, 0, stream>>>(wv,    wv_b,    589824);
  k_convert<<<576,  256, 0, stream>>>(wo,    wo_b,    589824);
  k_convert<<<2304, 256, 0, stream>>>(wfc1,  wfc1_b,  2359296);
  k_convert<<<9216, 256, 0, stream>>>(win,   win_b,   9437184);
  k_convert<<<9216, 256, 0, stream>>>(wgate, wgate_b, 9437184);
  k_convert<<<2304, 256, 0, stream>>>(wfc2,  wfc2_b,  2359296);

  k_rmsnorm<<<1024, 256, 0, stream>>>(src, gattn, xn);

  dim3 g768(6, 32), g3072(24, 32);
  k_gemm<EPI_Q><<<g768, 256, 0, stream>>>(xn, wq_b, qb,  bq, nullptr, 4096, 768, 768);
  k_gemm<EPI_K><<<g768, 256, 0, stream>>>(xn, wk_b, kb2, bk, nullptr, 4096, 768, 768);
  k_gemm<EPI_V><<<g768, 256, 0, stream>>>(xn, wv_b, vb2, bv, nullptr, 4096, 768, 768);

  k_attn<<<dim3(16, 24), 256, 0, stream>>>(qb, kb2, vb2, ctxb);

  k_gemm<EPI_RESID><<<g768, 256, 0, stream>>>(ctxb, wo_b, resid, bo, src, 4096, 768, 768);
  k_rmsnorm<<<1024, 256, 0, stream>>>(resid, gffn, yb);
  k_gemm<EPI_BF16><<<g3072, 256, 0, stream>>>(yb, wfc1_b, h1, bfc1, nullptr, 4096, 3072, 768);
  k_gemm<EPI_BF16><<<g3072, 256, 0, stream>>>(h1, win_b, hin, nullptr, nullptr, 4096, 3072, 3072);
  k_gemm<EPI_SWIGLU><<<g3072, 256, 0, stream>>>(h1, wgate_b, h2, nullptr, hin, 4096, 3072, 3072);
  k_gemm<EPI_FINAL><<<g768, 256, 0, stream>>>(h2, wfc2_b, d_out, bfc2, yb, 4096, 768, 3072);
}

// Round 2
// 501.669 us; speedup vs baseline: 1.1306x; 1.1306x over previous
//
#include <hip/hip_runtime.h>

#define DEV static __device__ __forceinline__

typedef __attribute__((ext_vector_type(8))) short bf16x8;
typedef __attribute__((ext_vector_type(4))) short short4v;
typedef __attribute__((ext_vector_type(4))) float f32x4;

DEV f32x4 mfma16(bf16x8 a, bf16x8 b, f32x4 c){
  return __builtin_amdgcn_mfma_f32_16x16x32_bf16(a, b, c, 0, 0, 0);
}
DEV float bf2f(short s){ union{unsigned u; float f;} v; v.u=((unsigned)(unsigned short)s)<<16; return v.f; }
DEV short f2bf(float f){ union{float f; unsigned u;} v; v.f=f; unsigned r=v.u+0x7fffu+((v.u>>16)&1u); return (short)(r>>16); }
DEV void gload16(const void* g, void* l){
  __builtin_amdgcn_global_load_lds((const __attribute__((address_space(1))) void*)g,
                                   (__attribute__((address_space(3))) void*)l, 16, 0, 0);
}
DEV int cvtpk(float lo, float hi){
  int r; asm("v_cvt_pk_bf16_f32 %0, %1, %2" : "=v"(r) : "v"(lo), "v"(hi)); return r;
}

enum { EPI_BF16=0, EPI_SWIGLU=1, EPI_RESID=2, EPI_FINAL=3, EPI_V=4, EPI_K=5, EPI_Q=6 };

// ---------------- weight convert f32 -> bf16 ----------------
__global__ void k_convert(const float* __restrict__ in, short* __restrict__ out, int n){
  int i = (blockIdx.x * 256 + threadIdx.x) * 4;
  if (i >= n) return;
  float4 v = *(const float4*)(in + i);
  short4v o; o.x=f2bf(v.x); o.y=f2bf(v.y); o.z=f2bf(v.z); o.w=f2bf(v.w);
  *(short4v*)(out + i) = o;
}

// ---------------- RMSNorm over 768 f32 -> bf16 (1 wave / row) ----------------
__global__ void k_rmsnorm(const float* __restrict__ x, const float* __restrict__ g,
                          short* __restrict__ out){
  int row = blockIdx.x*4 + (threadIdx.x>>6);
  int lane = threadIdx.x & 63;
  const float* xr = x + (size_t)row*768;
  float4 v[3];
  float ss = 0.f;
  #pragma unroll
  for (int i=0;i<3;i++){
    v[i] = *(const float4*)(xr + i*256 + lane*4);
    ss += v[i].x*v[i].x + v[i].y*v[i].y + v[i].z*v[i].z + v[i].w*v[i].w;
  }
  #pragma unroll
  for (int d=32; d>0; d>>=1) ss += __shfl_xor(ss, d);
  float sc = rsqrtf(ss*(1.f/768.f) + 1.1920929e-7f);
  #pragma unroll
  for (int i=0;i<3;i++){
    int c0 = i*256 + lane*4;
    float4 gv = *(const float4*)(g + c0);
    short4v o;
    o.x = f2bf(v[i].x*sc*gv.x); o.y = f2bf(v[i].y*sc*gv.y);
    o.z = f2bf(v[i].z*sc*gv.z); o.w = f2bf(v[i].w*sc*gv.w);
    *(short4v*)(out + (size_t)row*768 + c0) = o;
  }
}

// ---------------- NT GEMM: C[M,N] = A[M,K] * B[N,K]^T, m97 structure ----------------
template<int EPI>
__launch_bounds__(256, 2)
__global__ void k_gemm(const short* __restrict__ Aptr, const short* __restrict__ Bptr,
                       void* __restrict__ Cout, const float* __restrict__ bias,
                       const void* __restrict__ aux, int M, int N, int K){
  __shared__ short ldsA[128*32];
  __shared__ short ldsB[128*32];
  const int t = threadIdx.x;
  const int wave = t >> 6, lane = t & 63;
  const int l15 = lane & 15, l4 = lane >> 4;
  // XCD-aware bijective swizzle (grid counts are multiples of 8)
  const int nwg = gridDim.x * gridDim.y;
  const int bid0 = blockIdx.y * gridDim.x + blockIdx.x;
  const int cpx = nwg >> 3;
  const int bid = (bid0 & 7) * cpx + (bid0 >> 3);
  const int bm = bid / gridDim.x, bn = bid % gridDim.x;
  const int wr = wave >> 1, wc = wave & 1;

  f32x4 acc[4][4] = {};

  const short* Ag = Aptr + (size_t)(bm*128 + wave*32 + (lane>>2))*K + (lane&3)*8;
  const short* Bg = Bptr + (size_t)(bn*128 + wave*32 + (lane>>2))*K + (lane&3)*8;
  short* lA = ldsA + wave*1024;
  short* lB = ldsB + wave*1024;

  for (int k0 = 0; k0 < K; k0 += 32){
    __syncthreads();
    gload16(Ag + k0,                lA);
    gload16(Ag + k0 + 16*(size_t)K, lA + 512);
    gload16(Bg + k0,                lB);
    gload16(Bg + k0 + 16*(size_t)K, lB + 512);
    __syncthreads();
    bf16x8 af[4], bfr[4];
    #pragma unroll
    for (int m=0;m<4;m++) af[m]  = *(const bf16x8*)(ldsA + (wr*64 + m*16 + l15)*32 + l4*8);
    #pragma unroll
    for (int n=0;n<4;n++) bfr[n] = *(const bf16x8*)(ldsB + (wc*64 + n*16 + l15)*32 + l4*8);
    #pragma unroll
    for (int m=0;m<4;m++)
      #pragma unroll
      for (int n=0;n<4;n++)
        acc[m][n] = mfma16(af[m], bfr[n], acc[m][n]);
  }

  const int row0 = bm*128 + wr*64;
  const int col0 = bn*128 + wc*64;

  if constexpr (EPI == EPI_BF16){
    short* C = (short*)Cout;
    float bvv[4];
    #pragma unroll
    for (int n=0;n<4;n++) bvv[n] = bias ? bias[col0 + n*16 + l15] : 0.f;
    #pragma unroll
    for (int m=0;m<4;m++)
      #pragma unroll
      for (int j=0;j<4;j++){
        size_t rb = (size_t)(row0 + m*16 + l4*4 + j)*N + col0 + l15;
        #pragma unroll
        for (int n=0;n<4;n++) C[rb + n*16] = f2bf(acc[m][n][j] + bvv[n]);
      }
  } else if constexpr (EPI == EPI_SWIGLU){
    short* C = (short*)Cout;
    const short* hinp = (const short*)aux;
    #pragma unroll
    for (int m=0;m<4;m++)
      #pragma unroll
      for (int j=0;j<4;j++){
        size_t rb = (size_t)(row0 + m*16 + l4*4 + j)*N + col0 + l15;
        #pragma unroll
        for (int n=0;n<4;n++){
          float gt = acc[m][n][j];
          C[rb + n*16] = f2bf(bf2f(hinp[rb + n*16]) * gt / (1.f + __expf(-gt)));
        }
      }
  } else if constexpr (EPI == EPI_RESID){
    float* C = (float*)Cout;
    const float* srcf = (const float*)aux;
    float bvv[4];
    #pragma unroll
    for (int n=0;n<4;n++) bvv[n] = bias[col0 + n*16 + l15];
    #pragma unroll
    for (int m=0;m<4;m++)
      #pragma unroll
      for (int j=0;j<4;j++){
        size_t rb = (size_t)(row0 + m*16 + l4*4 + j)*N + col0 + l15;
        #pragma unroll
        for (int n=0;n<4;n++) C[rb + n*16] = acc[m][n][j] + bvv[n] + srcf[rb + n*16];
      }
  } else if constexpr (EPI == EPI_FINAL){
    float* C = (float*)Cout;
    const short* yv = (const short*)aux;
    float bvv[4];
    #pragma unroll
    for (int n=0;n<4;n++) bvv[n] = bias[col0 + n*16 + l15];
    #pragma unroll
    for (int m=0;m<4;m++)
      #pragma unroll
      for (int j=0;j<4;j++){
        size_t rb = (size_t)(row0 + m*16 + l4*4 + j)*N + col0 + l15;
        #pragma unroll
        for (int n=0;n<4;n++) C[rb + n*16] = acc[m][n][j] + bvv[n] + bf2f(yv[rb + n*16]);
      }
  } else { // EPI_V / EPI_K / EPI_Q : remap to [B,H,S,DH]; rope for Q,K; 0.125 scale for Q
    short* Obuf = (short*)Cout;
    const int h = col0 >> 6;
    float bvv[4];
    #pragma unroll
    for (int n=0;n<4;n++) bvv[n] = bias[col0 + n*16 + l15];
    float invf0 = 0.f, invf1 = 0.f;
    if constexpr (EPI != EPI_V){
      const float RC = 0.41524101186092034f;  // log2(10000)/32
      invf0 = exp2f(-(float)l15 * RC);
      invf1 = exp2f(-(float)(16 + l15) * RC);
    }
    #pragma unroll
    for (int m=0;m<4;m++){
      #pragma unroll
      for (int j=0;j<4;j++){
        int row = row0 + m*16 + l4*4 + j;
        int b = row >> 11, s = row & 2047;
        size_t obase = ((size_t)(b*12 + h)*2048 + (size_t)s)*64;
        float a0 = acc[m][0][j] + bvv[0];
        float a1 = acc[m][1][j] + bvv[1];
        float a2 = acc[m][2][j] + bvv[2];
        float a3 = acc[m][3][j] + bvv[3];
        float o0, o1, o2, o3;
        if constexpr (EPI == EPI_V){
          o0=a0; o1=a1; o2=a2; o3=a3;
        } else {
          float sn0, cs0, sn1, cs1;
          __sincosf((float)s * invf0, &sn0, &cs0);
          __sincosf((float)s * invf1, &sn1, &cs1);
          o0 = a0*cs0 - a2*sn0;
          o1 = a1*cs1 - a3*sn1;
          o2 = a2*cs0 + a0*sn0;
          o3 = a3*cs1 + a1*sn1;
          if constexpr (EPI == EPI_Q){ o0*=0.125f; o1*=0.125f; o2*=0.125f; o3*=0.125f; }
        }
        Obuf[obase + l15]      = f2bf(o0);
        Obuf[obase + 16 + l15] = f2bf(o1);
        Obuf[obase + 32 + l15] = f2bf(o2);
        Obuf[obase + 48 + l15] = f2bf(o3);
      }
    }
  }
}

// ---------------- Flash attention, swapped-QK (S^T) structure ----------------
// grid (S/64, B*H), 4 waves; each wave owns 16 q-rows. KV tile = 128.
// S^T = mfma(K_frag, Q_frag): lane holds full P row for q=lane&15 (8 frags x 4).
// PV A-frags built in-register via cvt_pk_bf16 + shfl. No P in LDS.
__launch_bounds__(256, 4)
__global__ void k_attn(const short* __restrict__ Q, const short* __restrict__ Kb,
                       const short* __restrict__ Vb, short* __restrict__ ctx){
  __shared__ short Kt[128*64];   // [r][chunk c at c^(r&7)] (8-short chunks)
  __shared__ short Vt[64*128];   // V^T [dh][k], chunk cc at cc^g(dh), g=(dh>>3)^(((dh&7)<<1)&7)
  const int t = threadIdx.x, wave = t>>6, lane = t&63;
  const int l15 = lane&15, l4 = lane>>4;
  const int qt = blockIdx.x, bh = blockIdx.y;
  const short* Qh = Q  + (size_t)bh*2048*64;
  const short* Kh = Kb + (size_t)bh*2048*64;
  const short* Vh = Vb + (size_t)bh*2048*64;

  // Q fragment (B operand): lane holds Q[q=l15][d = kf*32 + l4*8 + e]
  bf16x8 qf[2];
  #pragma unroll
  for (int kf=0;kf<2;kf++)
    qf[kf] = *(const bf16x8*)(Qh + (size_t)(qt*64 + wave*16 + l15)*64 + kf*32 + l4*8);

  f32x4 cacc[4] = {};
  float mrun = -1e30f, lrun = 0.f;

  for (int kv0 = 0; kv0 < 2048; kv0 += 128){
    __syncthreads();
    // K: global->LDS async, source pre-swizzled so LDS[r][c] = K[r][chunk c^(r&7)]
    #pragma unroll
    for (int i=0;i<4;i++){
      int r7 = lane>>3;              // r&7
      int r  = i*32 + wave*8 + r7;
      int c  = lane&7;
      gload16(Kh + (size_t)(kv0 + r)*64 + ((c ^ r7)<<3),
              Kt + (i*256 + wave*64)*8);
    }
    // V: global->reg (b128), pair-transpose via shfl_xor(.,8), b32 writes to Vt
    #pragma unroll
    for (int i=0;i<4;i++){
      int ch = i*256 + t;
      int r = ch>>3, c = ch&7;
      union { bf16x8 v; int w[4]; unsigned short s[8]; } u, p;
      u.v = *(const bf16x8*)(Vh + (size_t)(kv0 + r)*64 + c*8);
      #pragma unroll
      for (int w=0;w<4;w++) p.w[w] = __shfl_xor(u.w[w], 8);
      int rodd = r & 1;
      #pragma unroll
      for (int a=0;a<4;a++){
        int j = rodd*4 + a;
        unsigned short mys = u.s[j], ps = p.s[j];
        int lo = rodd ? ps : mys;
        int hi = rodd ? mys : ps;
        int dh = c*8 + j;
        int g = (c ^ ((j&3)<<1)) & 7;
        int addr = dh*128 + (((r>>3) ^ g)<<3) + (r&6);
        *(int*)(Vt + addr) = (lo & 0xffff) | (hi<<16);
      }
    }
    __syncthreads();

    // QK^T (swapped): sacc[mk] holds S[q=l15][k = mk*16 + l4*4 + j]
    f32x4 sacc[8] = {};
    #pragma unroll
    for (int kf=0;kf<2;kf++){
      #pragma unroll
      for (int mk=0;mk<8;mk++){
        int r = mk*16 + l15;
        bf16x8 kfr = *(const bf16x8*)(Kt + r*64 + (((kf*4 + l4) ^ (r&7))<<3));
        sacc[mk] = mfma16(kfr, qf[kf], sacc[mk]);
      }
    }

    // online softmax: whole row in this lane (+ its 3 l4-partners)
    float mx = -1e30f;
    #pragma unroll
    for (int mk=0;mk<8;mk++)
      #pragma unroll
      for (int j=0;j<4;j++) mx = fmaxf(mx, sacc[mk][j]);
    mx = fmaxf(mx, __shfl_xor(mx, 16));
    mx = fmaxf(mx, __shfl_xor(mx, 32));
    float mnew = fmaxf(mrun, mx);
    float fac = __expf(mrun - mnew);
    mrun = mnew;
    float psum = 0.f;
    #pragma unroll
    for (int mk=0;mk<8;mk++)
      #pragma unroll
      for (int j=0;j<4;j++){
        float pv = __expf(sacc[mk][j] - mnew);
        sacc[mk][j] = pv; psum += pv;
      }
    psum += __shfl_xor(psum, 16);
    psum += __shfl_xor(psum, 32);
    lrun = lrun*fac + psum;
    // rescale O (rows q = l4*4+j)
    #pragma unroll
    for (int j=0;j<4;j++){
      float fj = __shfl(fac, l4*4 + j);
      #pragma unroll
      for (int nf=0;nf<4;nf++) cacc[nf][j] *= fj;
    }

    // P -> bf16 pairs in-register
    int pk01[8], pk23[8];
    #pragma unroll
    for (int mk=0;mk<8;mk++){
      pk01[mk] = cvtpk(sacc[mk][0], sacc[mk][1]);
      pk23[mk] = cvtpk(sacc[mk][2], sacc[mk][3]);
    }

    // PV: A-frag ks gathered via shfl; B-frag = V^T rows from Vt
    #pragma unroll
    for (int ks=0;ks<4;ks++){
      int srcA = l15 + ((l4&1)<<5);
      int srcB = srcA + 16;
      int hi = l4>>1;
      int w0a = __shfl(pk01[2*ks], srcA), w0b = __shfl(pk01[2*ks+1], srcA);
      int w1a = __shfl(pk23[2*ks], srcA), w1b = __shfl(pk23[2*ks+1], srcA);
      int w2a = __shfl(pk01[2*ks], srcB), w2b = __shfl(pk01[2*ks+1], srcB);
      int w3a = __shfl(pk23[2*ks], srcB), w3b = __shfl(pk23[2*ks+1], srcB);
      union { int w[4]; bf16x8 v; } pa;
      pa.w[0] = hi ? w0b : w0a;
      pa.w[1] = hi ? w1b : w1a;
      pa.w[2] = hi ? w2b : w2a;
      pa.w[3] = hi ? w3b : w3a;
      #pragma unroll
      for (int nf=0;nf<4;nf++){
        int dh = nf*16 + l15;
        int g = ((dh>>3) ^ ((dh&7)<<1)) & 7;
        bf16x8 vf = *(const bf16x8*)(Vt + dh*128 + (((ks*4 + l4) ^ g)<<3));
        cacc[nf] = mfma16(pa.v, vf, cacc[nf]);
      }
    }
  }

  const int b = bh/12, h = bh%12;
  #pragma unroll
  for (int j=0;j<4;j++){
    float inv = 1.f / __shfl(lrun, l4*4 + j);
    int s = qt*64 + wave*16 + l4*4 + j;
    size_t base = ((size_t)b*2048 + s)*768 + h*64;
    #pragma unroll
    for (int nf=0;nf<4;nf++)
      ctx[base + nf*16 + l15] = f2bf(cacc[nf][j] * inv);
  }
}

extern "C" void kernel_launch(void* const* d_in, const int* in_sizes, int n_in,
                              void* d_out, int out_size, void* d_ws, size_t ws_size,
                              hipStream_t stream){
  (void)in_sizes; (void)n_in; (void)out_size;
  const float* src   = (const float*)d_in[0];
  const float* wq    = (const float*)d_in[1];
  const float* bq    = (const float*)d_in[2];
  const float* wk    = (const float*)d_in[3];
  const float* bk    = (const float*)d_in[4];
  const float* wv    = (const float*)d_in[5];
  const float* bv    = (const float*)d_in[6];
  const float* wo    = (const float*)d_in[7];
  const float* bo    = (const float*)d_in[8];
  const float* wfc1  = (const float*)d_in[9];
  const float* bfc1  = (const float*)d_in[10];
  const float* win   = (const float*)d_in[11];
  const float* wgate = (const float*)d_in[12];
  const float* wfc2  = (const float*)d_in[13];
  const float* bfc2  = (const float*)d_in[14];
  const float* gattn = (const float*)d_in[15];
  const float* gffn  = (const float*)d_in[16];

  char* ws = (char*)d_ws;
  constexpr size_t SZ_W768  = 768ull*768*2;
  constexpr size_t SZ_WFC   = 3072ull*768*2;
  constexpr size_t SZ_WFF   = 3072ull*3072*2;
  constexpr size_t SZ_ACT   = 4096ull*768*2;
  constexpr size_t SZ_ACTF  = 4096ull*768*4;
  constexpr size_t SZ_H     = 4096ull*3072*2;
  constexpr size_t OFF_WQ    = 0;
  constexpr size_t OFF_WK    = OFF_WQ + SZ_W768;
  constexpr size_t OFF_WV    = OFF_WK + SZ_W768;
  constexpr size_t OFF_WO    = OFF_WV + SZ_W768;
  constexpr size_t OFF_WFC1  = OFF_WO + SZ_W768;
  constexpr size_t OFF_WIN   = OFF_WFC1 + SZ_WFC;
  constexpr size_t OFF_WGATE = OFF_WIN + SZ_WFF;
  constexpr size_t OFF_WFC2  = OFF_WGATE + SZ_WFF;
  constexpr size_t OFF_XN    = OFF_WFC2 + SZ_WFC;
  constexpr size_t OFF_Q     = OFF_XN + SZ_ACT;
  constexpr size_t OFF_K     = OFF_Q + SZ_ACT;
  constexpr size_t OFF_V     = OFF_K + SZ_ACT;
  constexpr size_t OFF_RES   = OFF_V + SZ_ACT;
  constexpr size_t OFF_HIN   = OFF_RES + SZ_ACTF;
  constexpr size_t OFF_H2    = OFF_HIN + SZ_H;
  constexpr size_t WS_NEED   = OFF_H2 + SZ_H;
  if (ws_size < WS_NEED) return;

  short* wq_b    = (short*)(ws+OFF_WQ);
  short* wk_b    = (short*)(ws+OFF_WK);
  short* wv_b    = (short*)(ws+OFF_WV);
  short* wo_b    = (short*)(ws+OFF_WO);
  short* wfc1_b  = (short*)(ws+OFF_WFC1);
  short* win_b   = (short*)(ws+OFF_WIN);
  short* wgate_b = (short*)(ws+OFF_WGATE);
  short* wfc2_b  = (short*)(ws+OFF_WFC2);
  short* xn      = (short*)(ws+OFF_XN);
  short* ctxb    = (short*)(ws+OFF_XN);
  short* qb      = (short*)(ws+OFF_Q);
  short* yb      = (short*)(ws+OFF_Q);
  short* kb2     = (short*)(ws+OFF_K);
  short* vb2     = (short*)(ws+OFF_V);
  float* resid   = (float*)(ws+OFF_RES);
  short* h1      = (short*)(ws+OFF_K);
  short* hin     = (short*)(ws+OFF_HIN);
  short* h2      = (short*)(ws+OFF_H2);

  k_convert<<<576,  256, 0, stream>>>(wq,    wq_b,    589824);
  k_convert<<<576,  256, 0, stream>>>(wk,    wk_b,    589824);
  k_convert<<<576,  256, 0, stream>>>(wv,    wv_b,    589824);
  k_convert<<<576,  256, 0, stream>>>(wo,    wo_b,    589824);
  k_convert<<<2304, 256, 0, stream>>>(wfc1,  wfc1_b,  2359296);
  k_convert<<<9216, 256, 0, stream>>>(win,   win_b,   9437184);
  k_convert<<<9216, 256, 0, stream>>>(wgate, wgate_b, 9437184);
  k_convert<<<2304, 256, 0, stream>>>(wfc2,  wfc2_b,  2359296);

  k_rmsnorm<<<1024, 256, 0, stream>>>(src, gattn, xn);

  dim3 g768(6, 32), g3072(24, 32);
  k_gemm<EPI_Q><<<g768, 256, 0, stream>>>(xn, wq_b, qb,  bq, nullptr, 4096, 768, 768);
  k_gemm<EPI_K><<<g768, 256, 0, stream>>>(xn, wk_b, kb2, bk, nullptr, 4096, 768, 768);
  k_gemm<EPI_V><<<g768, 256, 0, stream>>>(xn, wv_b, vb2, bv, nullptr, 4096, 768, 768);

  k_attn<<<dim3(32, 24), 256, 0, stream>>>(qb, kb2, vb2, ctxb);

  k_gemm<EPI_RESID><<<g768, 256, 0, stream>>>(ctxb, wo_b, resid, bo, src, 4096, 768, 768);
  k_rmsnorm<<<1024, 256, 0, stream>>>(resid, gffn, yb);
  k_gemm<EPI_BF16><<<g3072, 256, 0, stream>>>(yb, wfc1_b, h1, bfc1, nullptr, 4096, 3072, 768);
  k_gemm<EPI_BF16><<<g3072, 256, 0, stream>>>(h1, win_b, hin, nullptr, nullptr, 4096, 3072, 3072);
  k_gemm<EPI_SWIGLU><<<g3072, 256, 0, stream>>>(h1, wgate_b, h2, nullptr, hin, 4096, 3072, 3072);
  k_gemm<EPI_FINAL><<<g768, 256, 0, stream>>>(h2, wfc2_b, d_out, bfc2, yb, 4096, 768, 3072);
}

// Round 3
// 448.976 us; speedup vs baseline: 1.2633x; 1.1174x over previous
//
#include <hip/hip_runtime.h>

#define DEV static __device__ __forceinline__

typedef __attribute__((ext_vector_type(8))) short bf16x8;
typedef __attribute__((ext_vector_type(4))) short short4v;
typedef __attribute__((ext_vector_type(4))) float f32x4;

DEV f32x4 mfma16(bf16x8 a, bf16x8 b, f32x4 c){
  return __builtin_amdgcn_mfma_f32_16x16x32_bf16(a, b, c, 0, 0, 0);
}
DEV float bf2f(short s){ union{unsigned u; float f;} v; v.u=((unsigned)(unsigned short)s)<<16; return v.f; }
DEV short f2bf(float f){ union{float f; unsigned u;} v; v.f=f; unsigned r=v.u+0x7fffu+((v.u>>16)&1u); return (short)(r>>16); }
DEV void gload16(const void* g, void* l){
  __builtin_amdgcn_global_load_lds((const __attribute__((address_space(1))) void*)g,
                                   (__attribute__((address_space(3))) void*)l, 16, 0, 0);
}
DEV int cvtpk(float lo, float hi){
  int r; asm("v_cvt_pk_bf16_f32 %0, %1, %2" : "=v"(r) : "v"(lo), "v"(hi)); return r;
}

enum { EPI_BF16=0, EPI_SWIGLU=1, EPI_RESID=2, EPI_FINAL=3, EPI_V=4, EPI_K=5, EPI_Q=6 };

// ---------------- weight convert f32 -> bf16 ----------------
__global__ void k_convert(const float* __restrict__ in, short* __restrict__ out, int n){
  int i = (blockIdx.x * 256 + threadIdx.x) * 4;
  if (i >= n) return;
  float4 v = *(const float4*)(in + i);
  short4v o; o.x=f2bf(v.x); o.y=f2bf(v.y); o.z=f2bf(v.z); o.w=f2bf(v.w);
  *(short4v*)(out + i) = o;
}

// ---------------- RMSNorm over 768 f32 -> bf16 (1 wave / row) ----------------
__global__ void k_rmsnorm(const float* __restrict__ x, const float* __restrict__ g,
                          short* __restrict__ out){
  int row = blockIdx.x*4 + (threadIdx.x>>6);
  int lane = threadIdx.x & 63;
  const float* xr = x + (size_t)row*768;
  float4 v[3];
  float ss = 0.f;
  #pragma unroll
  for (int i=0;i<3;i++){
    v[i] = *(const float4*)(xr + i*256 + lane*4);
    ss += v[i].x*v[i].x + v[i].y*v[i].y + v[i].z*v[i].z + v[i].w*v[i].w;
  }
  #pragma unroll
  for (int d=32; d>0; d>>=1) ss += __shfl_xor(ss, d);
  float sc = rsqrtf(ss*(1.f/768.f) + 1.1920929e-7f);
  #pragma unroll
  for (int i=0;i<3;i++){
    int c0 = i*256 + lane*4;
    float4 gv = *(const float4*)(g + c0);
    short4v o;
    o.x = f2bf(v[i].x*sc*gv.x); o.y = f2bf(v[i].y*sc*gv.y);
    o.z = f2bf(v[i].z*sc*gv.z); o.w = f2bf(v[i].w*sc*gv.w);
    *(short4v*)(out + (size_t)row*768 + c0) = o;
  }
}

// ---------------- NT GEMM: C[M,N] = A[M,K] * B[N,K]^T, m97 structure ----------------
template<int EPI>
__launch_bounds__(256, 2)
__global__ void k_gemm(const short* __restrict__ Aptr, const short* __restrict__ Bptr,
                       void* __restrict__ Cout, const float* __restrict__ bias,
                       const void* __restrict__ aux, int M, int N, int K){
  __shared__ short ldsA[128*32];
  __shared__ short ldsB[128*32];
  const int t = threadIdx.x;
  const int wave = t >> 6, lane = t & 63;
  const int l15 = lane & 15, l4 = lane >> 4;
  const int nwg = gridDim.x * gridDim.y;
  const int bid0 = blockIdx.y * gridDim.x + blockIdx.x;
  const int cpx = nwg >> 3;
  const int bid = (bid0 & 7) * cpx + (bid0 >> 3);
  const int bm = bid / gridDim.x, bn = bid % gridDim.x;
  const int wr = wave >> 1, wc = wave & 1;

  f32x4 acc[4][4] = {};

  const short* Ag = Aptr + (size_t)(bm*128 + wave*32 + (lane>>2))*K + (lane&3)*8;
  const short* Bg = Bptr + (size_t)(bn*128 + wave*32 + (lane>>2))*K + (lane&3)*8;
  short* lA = ldsA + wave*1024;
  short* lB = ldsB + wave*1024;

  for (int k0 = 0; k0 < K; k0 += 32){
    __syncthreads();
    gload16(Ag + k0,                lA);
    gload16(Ag + k0 + 16*(size_t)K, lA + 512);
    gload16(Bg + k0,                lB);
    gload16(Bg + k0 + 16*(size_t)K, lB + 512);
    __syncthreads();
    bf16x8 af[4], bfr[4];
    #pragma unroll
    for (int m=0;m<4;m++) af[m]  = *(const bf16x8*)(ldsA + (wr*64 + m*16 + l15)*32 + l4*8);
    #pragma unroll
    for (int n=0;n<4;n++) bfr[n] = *(const bf16x8*)(ldsB + (wc*64 + n*16 + l15)*32 + l4*8);
    #pragma unroll
    for (int m=0;m<4;m++)
      #pragma unroll
      for (int n=0;n<4;n++)
        acc[m][n] = mfma16(af[m], bfr[n], acc[m][n]);
  }

  const int row0 = bm*128 + wr*64;
  const int col0 = bn*128 + wc*64;

  if constexpr (EPI == EPI_BF16){
    short* C = (short*)Cout;
    float bvv[4];
    #pragma unroll
    for (int n=0;n<4;n++) bvv[n] = bias ? bias[col0 + n*16 + l15] : 0.f;
    #pragma unroll
    for (int m=0;m<4;m++)
      #pragma unroll
      for (int j=0;j<4;j++){
        size_t rb = (size_t)(row0 + m*16 + l4*4 + j)*N + col0 + l15;
        #pragma unroll
        for (int n=0;n<4;n++) C[rb + n*16] = f2bf(acc[m][n][j] + bvv[n]);
      }
  } else if constexpr (EPI == EPI_SWIGLU){
    short* C = (short*)Cout;
    const short* hinp = (const short*)aux;
    #pragma unroll
    for (int m=0;m<4;m++)
      #pragma unroll
      for (int j=0;j<4;j++){
        size_t rb = (size_t)(row0 + m*16 + l4*4 + j)*N + col0 + l15;
        #pragma unroll
        for (int n=0;n<4;n++){
          float gt = acc[m][n][j];
          C[rb + n*16] = f2bf(bf2f(hinp[rb + n*16]) * gt / (1.f + __expf(-gt)));
        }
      }
  } else if constexpr (EPI == EPI_RESID){
    float* C = (float*)Cout;
    const float* srcf = (const float*)aux;
    float bvv[4];
    #pragma unroll
    for (int n=0;n<4;n++) bvv[n] = bias[col0 + n*16 + l15];
    #pragma unroll
    for (int m=0;m<4;m++)
      #pragma unroll
      for (int j=0;j<4;j++){
        size_t rb = (size_t)(row0 + m*16 + l4*4 + j)*N + col0 + l15;
        #pragma unroll
        for (int n=0;n<4;n++) C[rb + n*16] = acc[m][n][j] + bvv[n] + srcf[rb + n*16];
      }
  } else if constexpr (EPI == EPI_FINAL){
    float* C = (float*)Cout;
    const short* yv = (const short*)aux;
    float bvv[4];
    #pragma unroll
    for (int n=0;n<4;n++) bvv[n] = bias[col0 + n*16 + l15];
    #pragma unroll
    for (int m=0;m<4;m++)
      #pragma unroll
      for (int j=0;j<4;j++){
        size_t rb = (size_t)(row0 + m*16 + l4*4 + j)*N + col0 + l15;
        #pragma unroll
        for (int n=0;n<4;n++) C[rb + n*16] = acc[m][n][j] + bvv[n] + bf2f(yv[rb + n*16]);
      }
  } else if constexpr (EPI == EPI_V){
    // write V^T: [B,H,DH=64,S=2048]
    short* Obuf = (short*)Cout;
    const int h = col0 >> 6;
    float bvv[4];
    #pragma unroll
    for (int n=0;n<4;n++) bvv[n] = bias[col0 + n*16 + l15];
    #pragma unroll
    for (int m=0;m<4;m++){
      #pragma unroll
      for (int j=0;j<4;j++){
        int row = row0 + m*16 + l4*4 + j;
        int b = row >> 11, s = row & 2047;
        size_t obase = ((size_t)(b*12 + h)*64)*2048 + (size_t)s;
        #pragma unroll
        for (int n=0;n<4;n++)
          Obuf[obase + (size_t)(n*16 + l15)*2048] = f2bf(acc[m][n][j] + bvv[n]);
      }
    }
  } else { // EPI_K / EPI_Q : remap to [B,H,S,DH]; rope; 0.125 scale for Q
    short* Obuf = (short*)Cout;
    const int h = col0 >> 6;
    float bvv[4];
    #pragma unroll
    for (int n=0;n<4;n++) bvv[n] = bias[col0 + n*16 + l15];
    const float RC = 0.41524101186092034f;  // log2(10000)/32
    float invf0 = exp2f(-(float)l15 * RC);
    float invf1 = exp2f(-(float)(16 + l15) * RC);
    #pragma unroll
    for (int m=0;m<4;m++){
      #pragma unroll
      for (int j=0;j<4;j++){
        int row = row0 + m*16 + l4*4 + j;
        int b = row >> 11, s = row & 2047;
        size_t obase = ((size_t)(b*12 + h)*2048 + (size_t)s)*64;
        float a0 = acc[m][0][j] + bvv[0];
        float a1 = acc[m][1][j] + bvv[1];
        float a2 = acc[m][2][j] + bvv[2];
        float a3 = acc[m][3][j] + bvv[3];
        float sn0, cs0, sn1, cs1;
        __sincosf((float)s * invf0, &sn0, &cs0);
        __sincosf((float)s * invf1, &sn1, &cs1);
        float o0 = a0*cs0 - a2*sn0;
        float o1 = a1*cs1 - a3*sn1;
        float o2 = a2*cs0 + a0*sn0;
        float o3 = a3*cs1 + a1*sn1;
        if constexpr (EPI == EPI_Q){ o0*=0.125f; o1*=0.125f; o2*=0.125f; o3*=0.125f; }
        Obuf[obase + l15]      = f2bf(o0);
        Obuf[obase + 16 + l15] = f2bf(o1);
        Obuf[obase + 32 + l15] = f2bf(o2);
        Obuf[obase + 48 + l15] = f2bf(o3);
      }
    }
  }
}

// ---------------- Flash attention v3: swapped-QK, double-buffered KV, counted vmcnt ----------------
// grid (S/64, B*H), 4 waves, 16 q-rows/wave. KVBLK=64. V pre-transposed [B,H,DH,S].
__launch_bounds__(256, 3)
__global__ void k_attn(const short* __restrict__ Q, const short* __restrict__ Kb,
                       const short* __restrict__ Vb, short* __restrict__ ctx){
  __shared__ short Kt[2][4096];   // [r 0..63][chunk cc holds src chunk cc^(r&7)] rows of 64 shorts
  __shared__ short Vt[2][4096];   // V^T [dh 0..63][chunk cc holds src chunk cc^(dh&7)] rows of 64 shorts
  const int t = threadIdx.x, wave = t>>6, lane = t&63;
  const int l15 = lane&15, l4 = lane>>4;
  const int qt = blockIdx.x, bh = blockIdx.y;
  const short* Qh  = Q  + (size_t)bh*2048*64;
  const short* Kh  = Kb + (size_t)bh*2048*64;
  const short* Vth = Vb + (size_t)bh*64*2048;

  // staging offsets (loop-invariant): call i stages rows i*32+wave*8+(lane>>3)
  const int r7  = lane>>3;
  const int swz = ((lane&7) ^ r7) << 3;
  const int rr0 = wave*8 + r7, rr1 = 32 + wave*8 + r7;
  const size_t kOff0 = (size_t)rr0*64   + swz, kOff1 = (size_t)rr1*64   + swz;
  const size_t vOff0 = (size_t)rr0*2048 + swz, vOff1 = (size_t)rr1*2048 + swz;

  // Q fragment (B operand): lane holds Q[q=l15][d = kf*32 + l4*8 + e]
  bf16x8 qf[2];
  #pragma unroll
  for (int kf=0;kf<2;kf++)
    qf[kf] = *(const bf16x8*)(Qh + (size_t)(qt*64 + wave*16 + l15)*64 + kf*32 + l4*8);

  f32x4 cacc[4] = {};
  float mrun = -1e30f, lrun = 0.f;

  #define STAGE(sel, kv0) do { \
    const short* ksp = Kh + (size_t)(kv0)*64; \
    const short* vsp = Vth + (kv0); \
    short* kd = &Kt[sel][wave*512]; \
    short* vd = &Vt[sel][wave*512]; \
    gload16(ksp + kOff0, kd); \
    gload16(ksp + kOff1, kd + 2048); \
    gload16(vsp + vOff0, vd); \
    gload16(vsp + vOff1, vd + 2048); \
  } while(0)

  STAGE(0, 0);

  for (int tt = 0; tt < 32; ++tt){
    const int cur = tt & 1;
    if (tt < 31){
      STAGE(cur^1, (tt+1)*64);
      asm volatile("s_waitcnt vmcnt(4)" ::: "memory");
    } else {
      asm volatile("s_waitcnt vmcnt(0)" ::: "memory");
    }
    __builtin_amdgcn_sched_barrier(0);
    __builtin_amdgcn_s_barrier();
    __builtin_amdgcn_sched_barrier(0);

    const short* KtC = &Kt[cur][0];
    const short* VtC = &Vt[cur][0];

    // QK^T (swapped): sacc[mk][j] = S[q=l15][k = mk*16 + l4*4 + j]
    f32x4 sacc[4] = {};
    __builtin_amdgcn_s_setprio(1);
    #pragma unroll
    for (int kf=0;kf<2;kf++){
      #pragma unroll
      for (int mk=0;mk<4;mk++){
        int r = mk*16 + l15;
        bf16x8 kfr = *(const bf16x8*)(KtC + r*64 + (((kf*4+l4) ^ (l15&7))<<3));
        sacc[mk] = mfma16(kfr, qf[kf], sacc[mk]);
      }
    }
    __builtin_amdgcn_s_setprio(0);

    // online softmax (defer-max, THR=8)
    float mx = sacc[0][0];
    #pragma unroll
    for (int mk=0;mk<4;mk++)
      #pragma unroll
      for (int j=0;j<4;j++) mx = fmaxf(mx, sacc[mk][j]);
    mx = fmaxf(mx, __shfl_xor(mx, 16));
    mx = fmaxf(mx, __shfl_xor(mx, 32));
    if (!__all(mx - mrun <= 8.f)){
      float mnew = fmaxf(mrun, mx);
      float fac = __expf(mrun - mnew);
      mrun = mnew;
      lrun *= fac;
      #pragma unroll
      for (int j=0;j<4;j++){
        float fj = __shfl(fac, l4*4 + j);
        #pragma unroll
        for (int nf=0;nf<4;nf++) cacc[nf][j] *= fj;
      }
    }
    float psum = 0.f;
    #pragma unroll
    for (int mk=0;mk<4;mk++)
      #pragma unroll
      for (int j=0;j<4;j++){
        float pv = __expf(sacc[mk][j] - mrun);
        sacc[mk][j] = pv; psum += pv;
      }
    psum += __shfl_xor(psum, 16);
    psum += __shfl_xor(psum, 32);
    lrun += psum;

    // P -> bf16 pairs in-register
    int pk01[4], pk23[4];
    #pragma unroll
    for (int mk=0;mk<4;mk++){
      pk01[mk] = cvtpk(sacc[mk][0], sacc[mk][1]);
      pk23[mk] = cvtpk(sacc[mk][2], sacc[mk][3]);
    }

    // PV: A-frag via shfl gather; B-frag = V^T rows from Vt
    #pragma unroll
    for (int ks=0;ks<2;ks++){
      int srcA = l15 + ((l4&1)<<5);
      int srcB = srcA + 16;
      int hi = l4>>1;
      int w0a = __shfl(pk01[2*ks], srcA), w0b = __shfl(pk01[2*ks+1], srcA);
      int w1a = __shfl(pk23[2*ks], srcA), w1b = __shfl(pk23[2*ks+1], srcA);
      int w2a = __shfl(pk01[2*ks], srcB), w2b = __shfl(pk01[2*ks+1], srcB);
      int w3a = __shfl(pk23[2*ks], srcB), w3b = __shfl(pk23[2*ks+1], srcB);
      union { int w[4]; bf16x8 v; } pa;
      pa.w[0] = hi ? w0b : w0a;
      pa.w[1] = hi ? w1b : w1a;
      pa.w[2] = hi ? w2b : w2a;
      pa.w[3] = hi ? w3b : w3a;
      __builtin_amdgcn_s_setprio(1);
      #pragma unroll
      for (int nf=0;nf<4;nf++){
        int dh = nf*16 + l15;
        bf16x8 vf = *(const bf16x8*)(VtC + dh*64 + (((ks*4+l4) ^ (dh&7))<<3));
        cacc[nf] = mfma16(pa.v, vf, cacc[nf]);
      }
      __builtin_amdgcn_s_setprio(0);
    }

    __builtin_amdgcn_sched_barrier(0);
    __builtin_amdgcn_s_barrier();
  }
  #undef STAGE

  const int b = bh/12, h = bh%12;
  #pragma unroll
  for (int j=0;j<4;j++){
    float inv = 1.f / __shfl(lrun, l4*4 + j);
    int s = qt*64 + wave*16 + l4*4 + j;
    size_t base = ((size_t)b*2048 + s)*768 + h*64;
    #pragma unroll
    for (int nf=0;nf<4;nf++)
      ctx[base + nf*16 + l15] = f2bf(cacc[nf][j] * inv);
  }
}

extern "C" void kernel_launch(void* const* d_in, const int* in_sizes, int n_in,
                              void* d_out, int out_size, void* d_ws, size_t ws_size,
                              hipStream_t stream){
  (void)in_sizes; (void)n_in; (void)out_size;
  const float* src   = (const float*)d_in[0];
  const float* wq    = (const float*)d_in[1];
  const float* bq    = (const float*)d_in[2];
  const float* wk    = (const float*)d_in[3];
  const float* bk    = (const float*)d_in[4];
  const float* wv    = (const float*)d_in[5];
  const float* bv    = (const float*)d_in[6];
  const float* wo    = (const float*)d_in[7];
  const float* bo    = (const float*)d_in[8];
  const float* wfc1  = (const float*)d_in[9];
  const float* bfc1  = (const float*)d_in[10];
  const float* win   = (const float*)d_in[11];
  const float* wgate = (const float*)d_in[12];
  const float* wfc2  = (const float*)d_in[13];
  const float* bfc2  = (const float*)d_in[14];
  const float* gattn = (const float*)d_in[15];
  const float* gffn  = (const float*)d_in[16];

  char* ws = (char*)d_ws;
  constexpr size_t SZ_W768  = 768ull*768*2;
  constexpr size_t SZ_WFC   = 3072ull*768*2;
  constexpr size_t SZ_WFF   = 3072ull*3072*2;
  constexpr size_t SZ_ACT   = 4096ull*768*2;
  constexpr size_t SZ_ACTF  = 4096ull*768*4;
  constexpr size_t SZ_H     = 4096ull*3072*2;
  constexpr size_t OFF_WQ    = 0;
  constexpr size_t OFF_WK    = OFF_WQ + SZ_W768;
  constexpr size_t OFF_WV    = OFF_WK + SZ_W768;
  constexpr size_t OFF_WO    = OFF_WV + SZ_W768;
  constexpr size_t OFF_WFC1  = OFF_WO + SZ_W768;
  constexpr size_t OFF_WIN   = OFF_WFC1 + SZ_WFC;
  constexpr size_t OFF_WGATE = OFF_WIN + SZ_WFF;
  constexpr size_t OFF_WFC2  = OFF_WGATE + SZ_WFF;
  constexpr size_t OFF_XN    = OFF_WFC2 + SZ_WFC;
  constexpr size_t OFF_Q     = OFF_XN + SZ_ACT;
  constexpr size_t OFF_K     = OFF_Q + SZ_ACT;
  constexpr size_t OFF_V     = OFF_K + SZ_ACT;
  constexpr size_t OFF_RES   = OFF_V + SZ_ACT;
  constexpr size_t OFF_HIN   = OFF_RES + SZ_ACTF;
  constexpr size_t OFF_H2    = OFF_HIN + SZ_H;
  constexpr size_t WS_NEED   = OFF_H2 + SZ_H;
  if (ws_size < WS_NEED) return;

  short* wq_b    = (short*)(ws+OFF_WQ);
  short* wk_b    = (short*)(ws+OFF_WK);
  short* wv_b    = (short*)(ws+OFF_WV);
  short* wo_b    = (short*)(ws+OFF_WO);
  short* wfc1_b  = (short*)(ws+OFF_WFC1);
  short* win_b   = (short*)(ws+OFF_WIN);
  short* wgate_b = (short*)(ws+OFF_WGATE);
  short* wfc2_b  = (short*)(ws+OFF_WFC2);
  short* xn      = (short*)(ws+OFF_XN);
  short* ctxb    = (short*)(ws+OFF_XN);
  short* qb      = (short*)(ws+OFF_Q);
  short* yb      = (short*)(ws+OFF_Q);
  short* kb2     = (short*)(ws+OFF_K);
  short* vb2     = (short*)(ws+OFF_V);
  float* resid   = (float*)(ws+OFF_RES);
  short* h1      = (short*)(ws+OFF_K);
  short* hin     = (short*)(ws+OFF_HIN);
  short* h2      = (short*)(ws+OFF_H2);

  k_convert<<<576,  256, 0, stream>>>(wq,    wq_b,    589824);
  k_convert<<<576,  256, 0, stream>>>(wk,    wk_b,    589824);
  k_convert<<<576,  256, 0, stream>>>(wv,    wv_b,    589824);
  k_convert<<<576,  256, 0, stream>>>(wo,    wo_b,    589824);
  k_convert<<<2304, 256, 0, stream>>>(wfc1,  wfc1_b,  2359296);
  k_convert<<<9216, 256, 0, stream>>>(win,   win_b,   9437184);
  k_convert<<<9216, 256, 0, stream>>>(wgate, wgate_b, 9437184);
  k_convert<<<2304, 256, 0, stream>>>(wfc2,  wfc2_b,  2359296);

  k_rmsnorm<<<1024, 256, 0, stream>>>(src, gattn, xn);

  dim3 g768(6, 32), g3072(24, 32);
  k_gemm<EPI_Q><<<g768, 256, 0, stream>>>(xn, wq_b, qb,  bq, nullptr, 4096, 768, 768);
  k_gemm<EPI_K><<<g768, 256, 0, stream>>>(xn, wk_b, kb2, bk, nullptr, 4096, 768, 768);
  k_gemm<EPI_V><<<g768, 256, 0, stream>>>(xn, wv_b, vb2, bv, nullptr, 4096, 768, 768);

  k_attn<<<dim3(32, 24), 256, 0, stream>>>(qb, kb2, vb2, ctxb);

  k_gemm<EPI_RESID><<<g768, 256, 0, stream>>>(ctxb, wo_b, resid, bo, src, 4096, 768, 768);
  k_rmsnorm<<<1024, 256, 0, stream>>>(resid, gffn, yb);
  k_gemm<EPI_BF16><<<g3072, 256, 0, stream>>>(yb, wfc1_b, h1, bfc1, nullptr, 4096, 3072, 768);
  k_gemm<EPI_BF16><<<g3072, 256, 0, stream>>>(h1, win_b, hin, nullptr, nullptr, 4096, 3072, 3072);
  k_gemm<EPI_SWIGLU><<<g3072, 256, 0, stream>>>(h1, wgate_b, h2, nullptr, hin, 4096, 3072, 3072);
  k_gemm<EPI_FINAL><<<g768, 256, 0, stream>>>(h2, wfc2_b, d_out, bfc2, yb, 4096, 768, 3072);
}

// Round 4
// 383.821 us; speedup vs baseline: 1.4777x; 1.1698x over previous
//
#include <hip/hip_runtime.h>

#define DEV static __device__ __forceinline__

typedef __attribute__((ext_vector_type(8))) short bf16x8;
typedef __attribute__((ext_vector_type(4))) short short4v;
typedef __attribute__((ext_vector_type(4))) float f32x4;

DEV f32x4 mfma16(bf16x8 a, bf16x8 b, f32x4 c){
  return __builtin_amdgcn_mfma_f32_16x16x32_bf16(a, b, c, 0, 0, 0);
}
DEV float bf2f(short s){ union{unsigned u; float f;} v; v.u=((unsigned)(unsigned short)s)<<16; return v.f; }
DEV short f2bf(float f){ union{float f; unsigned u;} v; v.f=f; unsigned r=v.u+0x7fffu+((v.u>>16)&1u); return (short)(r>>16); }
DEV void gload16(const void* g, void* l){
  __builtin_amdgcn_global_load_lds((const __attribute__((address_space(1))) void*)g,
                                   (__attribute__((address_space(3))) void*)l, 16, 0, 0);
}
DEV int cvtpk(float lo, float hi){
  int r; asm("v_cvt_pk_bf16_f32 %0, %1, %2" : "=v"(r) : "v"(lo), "v"(hi)); return r;
}

enum { EPI_BF16=0, EPI_SWIGLU=1, EPI_RESID=2, EPI_FINAL=3, EPI_QKV=4 };

// ---------------- fused weight convert f32 -> bf16 (all 8 weights, contiguous dst) ----------------
__global__ void k_convert8(const float* __restrict__ p0, const float* __restrict__ p1,
                           const float* __restrict__ p2, const float* __restrict__ p3,
                           const float* __restrict__ p4, const float* __restrict__ p5,
                           const float* __restrict__ p6, const float* __restrict__ p7,
                           short* __restrict__ dst){
  int v = blockIdx.x * 256 + threadIdx.x;   // vec4 index, grid sized exactly
  const float* src; int rel;
  if      (v <  147456){ src=p0; rel=v; }
  else if (v <  294912){ src=p1; rel=v-147456; }
  else if (v <  442368){ src=p2; rel=v-294912; }
  else if (v <  589824){ src=p3; rel=v-442368; }
  else if (v < 1179648){ src=p4; rel=v-589824; }
  else if (v < 3538944){ src=p5; rel=v-1179648; }
  else if (v < 5898240){ src=p6; rel=v-3538944; }
  else                 { src=p7; rel=v-5898240; }
  float4 x = ((const float4*)src)[rel];
  short4v o; o.x=f2bf(x.x); o.y=f2bf(x.y); o.z=f2bf(x.z); o.w=f2bf(x.w);
  ((short4v*)dst)[v] = o;
}

// ---------------- RMSNorm over 768 f32 -> bf16 (1 wave / row) ----------------
__global__ void k_rmsnorm(const float* __restrict__ x, const float* __restrict__ g,
                          short* __restrict__ out){
  int row = blockIdx.x*4 + (threadIdx.x>>6);
  int lane = threadIdx.x & 63;
  const float* xr = x + (size_t)row*768;
  float4 v[3];
  float ss = 0.f;
  #pragma unroll
  for (int i=0;i<3;i++){
    v[i] = *(const float4*)(xr + i*256 + lane*4);
    ss += v[i].x*v[i].x + v[i].y*v[i].y + v[i].z*v[i].z + v[i].w*v[i].w;
  }
  #pragma unroll
  for (int d=32; d>0; d>>=1) ss += __shfl_xor(ss, d);
  float sc = rsqrtf(ss*(1.f/768.f) + 1.1920929e-7f);
  #pragma unroll
  for (int i=0;i<3;i++){
    int c0 = i*256 + lane*4;
    float4 gv = *(const float4*)(g + c0);
    short4v o;
    o.x = f2bf(v[i].x*sc*gv.x); o.y = f2bf(v[i].y*sc*gv.y);
    o.z = f2bf(v[i].z*sc*gv.z); o.w = f2bf(v[i].w*sc*gv.w);
    *(short4v*)(out + (size_t)row*768 + c0) = o;
  }
}

// ---------------- NT GEMM (m97 128x128): used for QKV (N=2304), Wo, fc2 ----------------
template<int EPI>
__launch_bounds__(256, 2)
__global__ void k_gemm(const short* __restrict__ Aptr, const short* __restrict__ Bptr,
                       void* __restrict__ Cout, const float* __restrict__ bias,
                       const void* __restrict__ aux, const float* __restrict__ bias2,
                       const float* __restrict__ bias3, const void* __restrict__ aux2,
                       int M, int N, int K){
  __shared__ short ldsA[128*32];
  __shared__ short ldsB[128*32];
  const int t = threadIdx.x;
  const int wave = t >> 6, lane = t & 63;
  const int l15 = lane & 15, l4 = lane >> 4;
  const int nwg = gridDim.x * gridDim.y;
  const int bid0 = blockIdx.y * gridDim.x + blockIdx.x;
  const int cpx = nwg >> 3;
  const int bid = (bid0 & 7) * cpx + (bid0 >> 3);
  const int bm = bid / gridDim.x, bn = bid % gridDim.x;
  const int wr = wave >> 1, wc = wave & 1;

  f32x4 acc[4][4] = {};

  const short* Ag = Aptr + (size_t)(bm*128 + wave*32 + (lane>>2))*K + (lane&3)*8;
  const short* Bg = Bptr + (size_t)(bn*128 + wave*32 + (lane>>2))*K + (lane&3)*8;
  short* lA = ldsA + wave*1024;
  short* lB = ldsB + wave*1024;

  for (int k0 = 0; k0 < K; k0 += 32){
    __syncthreads();
    gload16(Ag + k0,                lA);
    gload16(Ag + k0 + 16*(size_t)K, lA + 512);
    gload16(Bg + k0,                lB);
    gload16(Bg + k0 + 16*(size_t)K, lB + 512);
    __syncthreads();
    bf16x8 af[4], bfr[4];
    #pragma unroll
    for (int m=0;m<4;m++) af[m]  = *(const bf16x8*)(ldsA + (wr*64 + m*16 + l15)*32 + l4*8);
    #pragma unroll
    for (int n=0;n<4;n++) bfr[n] = *(const bf16x8*)(ldsB + (wc*64 + n*16 + l15)*32 + l4*8);
    #pragma unroll
    for (int m=0;m<4;m++)
      #pragma unroll
      for (int n=0;n<4;n++)
        acc[m][n] = mfma16(af[m], bfr[n], acc[m][n]);
  }

  const int row0 = bm*128 + wr*64;
  const int col0 = bn*128 + wc*64;

  if constexpr (EPI == EPI_RESID){
    float* C = (float*)Cout;
    const float* srcf = (const float*)aux;
    float bvv[4];
    #pragma unroll
    for (int n=0;n<4;n++) bvv[n] = bias[col0 + n*16 + l15];
    #pragma unroll
    for (int m=0;m<4;m++)
      #pragma unroll
      for (int j=0;j<4;j++){
        size_t rb = (size_t)(row0 + m*16 + l4*4 + j)*N + col0 + l15;
        #pragma unroll
        for (int n=0;n<4;n++) C[rb + n*16] = acc[m][n][j] + bvv[n] + srcf[rb + n*16];
      }
  } else if constexpr (EPI == EPI_FINAL){
    float* C = (float*)Cout;
    const short* yv = (const short*)aux;
    float bvv[4];
    #pragma unroll
    for (int n=0;n<4;n++) bvv[n] = bias[col0 + n*16 + l15];
    #pragma unroll
    for (int m=0;m<4;m++)
      #pragma unroll
      for (int j=0;j<4;j++){
        size_t rb = (size_t)(row0 + m*16 + l4*4 + j)*N + col0 + l15;
        #pragma unroll
        for (int n=0;n<4;n++) C[rb + n*16] = acc[m][n][j] + bvv[n] + bf2f(yv[rb + n*16]);
      }
  } else if constexpr (EPI == EPI_QKV){
    // col0 in [0,2304): proj 0=Q (rope+0.125), 1=K (rope), 2=V (write V^T [B,H,64,S])
    const int proj = col0 / 768;
    const int c768 = col0 - proj*768;
    const int h = c768 >> 6;
    const float* bs = proj==0 ? bias : (proj==1 ? bias2 : bias3);
    float bvv[4];
    #pragma unroll
    for (int n=0;n<4;n++) bvv[n] = bs[c768 + n*16 + l15];
    if (proj == 2){
      short* Ov = (short*)const_cast<void*>(aux2);
      #pragma unroll
      for (int m=0;m<4;m++){
        #pragma unroll
        for (int j=0;j<4;j++){
          int row = row0 + m*16 + l4*4 + j;
          int b = row >> 11, s = row & 2047;
          size_t hb = (size_t)(b*12 + h)*64;
          #pragma unroll
          for (int n=0;n<4;n++)
            Ov[(hb + n*16 + l15)*2048 + s] = f2bf(acc[m][n][j] + bvv[n]);
        }
      }
    } else {
      short* O = proj==0 ? (short*)Cout : (short*)const_cast<void*>(aux);
      const float sc = proj==0 ? 0.125f : 1.0f;
      const float RC = 0.41524101186092034f;  // log2(10000)/32
      float invf0 = exp2f(-(float)l15 * RC);
      float invf1 = exp2f(-(float)(16 + l15) * RC);
      #pragma unroll
      for (int m=0;m<4;m++){
        #pragma unroll
        for (int j=0;j<4;j++){
          int row = row0 + m*16 + l4*4 + j;
          int b = row >> 11, s = row & 2047;
          size_t obase = ((size_t)(b*12 + h)*2048 + (size_t)s)*64;
          float a0 = acc[m][0][j] + bvv[0];
          float a1 = acc[m][1][j] + bvv[1];
          float a2 = acc[m][2][j] + bvv[2];
          float a3 = acc[m][3][j] + bvv[3];
          float sn0, cs0, sn1, cs1;
          __sincosf((float)s * invf0, &sn0, &cs0);
          __sincosf((float)s * invf1, &sn1, &cs1);
          O[obase + l15]      = f2bf((a0*cs0 - a2*sn0)*sc);
          O[obase + 16 + l15] = f2bf((a1*cs1 - a3*sn1)*sc);
          O[obase + 32 + l15] = f2bf((a2*cs0 + a0*sn0)*sc);
          O[obase + 48 + l15] = f2bf((a3*cs1 + a1*sn1)*sc);
        }
      }
    }
  }
}

// ---------------- Pipelined NT GEMM for N=3072: 128x384 tile, BK=32, triple-buffered ----------------
// 512 threads (8 waves, 2x4). Counted vmcnt, raw barriers, bank-swizzled LDS (chunk c at c^((r>>1)&3)).
template<int EPI>
__launch_bounds__(512, 2)
__global__ void k_ff(const short* __restrict__ Aptr, const short* __restrict__ Bptr,
                     short* __restrict__ Cout, const float* __restrict__ bias,
                     const short* __restrict__ hinp, int N, int K){
  __shared__ short lds[3*16384];   // per buf: A [0,4096) = 128x32, B [4096,16384) = 384x32
  const int tid = threadIdx.x;
  const int wave = tid >> 6, lane = tid & 63;
  const int l15 = lane & 15, l4 = lane >> 4;
  const int wm = wave >> 2, wn = wave & 3;

  const int nwg = gridDim.x * gridDim.y;
  const int bid0 = blockIdx.y * gridDim.x + blockIdx.x;
  const int cpx = nwg >> 3;
  const int bid = (bid0 & 7) * cpx + (bid0 >> 3);
  const int bm = bid / gridDim.x, bn = bid % gridDim.x;

  // staging: thread's A chunk = wave*64+lane; B chunks = i*512 + wave*64 + lane (i=0..2)
  const int chA = wave*64 + lane;
  const int rowA = chA >> 2;
  const int cA = (chA & 3) ^ ((rowA >> 1) & 3);
  const size_t aOff = (size_t)(bm*128 + rowA)*K + cA*8;
  const int chB0 = wave*64 + lane, chB1 = 512 + chB0, chB2 = 1024 + chB0;
  const int rB0 = chB0>>2, rB1 = chB1>>2, rB2 = chB2>>2;
  const size_t bOff0 = (size_t)(bn*384 + rB0)*K + (((chB0&3) ^ ((rB0>>1)&3))*8);
  const size_t bOff1 = (size_t)(bn*384 + rB1)*K + (((chB1&3) ^ ((rB1>>1)&3))*8);
  const size_t bOff2 = (size_t)(bn*384 + rB2)*K + (((chB2&3) ^ ((rB2>>1)&3))*8);
  const int stA = wave*512;   // shorts, wave-uniform LDS base offset

  // ds_read offsets (shorts, within a buf)
  int offA[4], offB[6];
  #pragma unroll
  for (int m=0;m<4;m++){
    int r = wm*64 + m*16 + l15;
    offA[m] = r*32 + ((l4 ^ ((r>>1)&3))<<3);
  }
  #pragma unroll
  for (int n=0;n<6;n++){
    int r = wn*96 + n*16 + l15;
    offB[n] = 4096 + r*32 + ((l4 ^ ((r>>1)&3))<<3);
  }

  short *p0 = lds, *p1 = lds + 16384, *p2 = lds + 32768;
  f32x4 acc[4][6] = {};
  const int nt = K >> 5;

  #define FFSTAGE(buf, t) do{ \
    gload16(Aptr + aOff  + (size_t)(t)*32, (buf) + stA); \
    gload16(Bptr + bOff0 + (size_t)(t)*32, (buf) + 4096  + stA); \
    gload16(Bptr + bOff1 + (size_t)(t)*32, (buf) + 8192  + stA); \
    gload16(Bptr + bOff2 + (size_t)(t)*32, (buf) + 12288 + stA); \
  }while(0)

  FFSTAGE(p0, 0);
  FFSTAGE(p1, 1);

  for (int t = 0; t < nt; ++t){
    if (t + 2 < nt){
      FFSTAGE(p2, t+2);
      asm volatile("s_waitcnt vmcnt(8)" ::: "memory");
    } else if (t + 1 < nt){
      asm volatile("s_waitcnt vmcnt(4)" ::: "memory");
    } else {
      asm volatile("s_waitcnt vmcnt(0)" ::: "memory");
    }
    __builtin_amdgcn_sched_barrier(0);
    __builtin_amdgcn_s_barrier();
    __builtin_amdgcn_sched_barrier(0);

    bf16x8 bfr[6], afr[4];
    #pragma unroll
    for (int n=0;n<6;n++) bfr[n] = *(const bf16x8*)(p0 + offB[n]);
    #pragma unroll
    for (int m=0;m<4;m++) afr[m] = *(const bf16x8*)(p0 + offA[m]);
    __builtin_amdgcn_s_setprio(1);
    #pragma unroll
    for (int m=0;m<4;m++)
      #pragma unroll
      for (int n=0;n<6;n++)
        acc[m][n] = mfma16(afr[m], bfr[n], acc[m][n]);
    __builtin_amdgcn_s_setprio(0);

    __builtin_amdgcn_sched_barrier(0);
    __builtin_amdgcn_s_barrier();
    short* tmp = p0; p0 = p1; p1 = p2; p2 = tmp;
  }
  #undef FFSTAGE

  const int row0 = bm*128 + wm*64;
  const int col0 = bn*384 + wn*96;

  if constexpr (EPI == EPI_BF16){
    float bvv[6];
    #pragma unroll
    for (int n=0;n<6;n++) bvv[n] = bias ? bias[col0 + n*16 + l15] : 0.f;
    #pragma unroll
    for (int m=0;m<4;m++)
      #pragma unroll
      for (int j=0;j<4;j++){
        size_t rb = (size_t)(row0 + m*16 + l4*4 + j)*N + col0 + l15;
        #pragma unroll
        for (int n=0;n<6;n++) Cout[rb + n*16] = f2bf(acc[m][n][j] + bvv[n]);
      }
  } else { // EPI_SWIGLU
    #pragma unroll
    for (int m=0;m<4;m++)
      #pragma unroll
      for (int j=0;j<4;j++){
        size_t rb = (size_t)(row0 + m*16 + l4*4 + j)*N + col0 + l15;
        #pragma unroll
        for (int n=0;n<6;n++){
          float gt = acc[m][n][j];
          Cout[rb + n*16] = f2bf(bf2f(hinp[rb + n*16]) * gt / (1.f + __expf(-gt)));
        }
      }
  }
}

// ---------------- Flash attention: swapped-QK, double-buffered KV, counted vmcnt ----------------
__launch_bounds__(256, 3)
__global__ void k_attn(const short* __restrict__ Q, const short* __restrict__ Kb,
                       const short* __restrict__ Vb, short* __restrict__ ctx){
  __shared__ short Kt[2][4096];
  __shared__ short Vt[2][4096];
  const int t = threadIdx.x, wave = t>>6, lane = t&63;
  const int l15 = lane&15, l4 = lane>>4;
  const int qt = blockIdx.x, bh = blockIdx.y;
  const short* Qh  = Q  + (size_t)bh*2048*64;
  const short* Kh  = Kb + (size_t)bh*2048*64;
  const short* Vth = Vb + (size_t)bh*64*2048;

  const int r7  = lane>>3;
  const int swz = ((lane&7) ^ r7) << 3;
  const int rr0 = wave*8 + r7, rr1 = 32 + wave*8 + r7;
  const size_t kOff0 = (size_t)rr0*64   + swz, kOff1 = (size_t)rr1*64   + swz;
  const size_t vOff0 = (size_t)rr0*2048 + swz, vOff1 = (size_t)rr1*2048 + swz;

  bf16x8 qf[2];
  #pragma unroll
  for (int kf=0;kf<2;kf++)
    qf[kf] = *(const bf16x8*)(Qh + (size_t)(qt*64 + wave*16 + l15)*64 + kf*32 + l4*8);

  f32x4 cacc[4] = {};
  float mrun = -1e30f, lrun = 0.f;

  #define STAGE(sel, kv0) do { \
    const short* ksp = Kh + (size_t)(kv0)*64; \
    const short* vsp = Vth + (kv0); \
    short* kd = &Kt[sel][wave*512]; \
    short* vd = &Vt[sel][wave*512]; \
    gload16(ksp + kOff0, kd); \
    gload16(ksp + kOff1, kd + 2048); \
    gload16(vsp + vOff0, vd); \
    gload16(vsp + vOff1, vd + 2048); \
  } while(0)

  STAGE(0, 0);

  for (int tt = 0; tt < 32; ++tt){
    const int cur = tt & 1;
    if (tt < 31){
      STAGE(cur^1, (tt+1)*64);
      asm volatile("s_waitcnt vmcnt(4)" ::: "memory");
    } else {
      asm volatile("s_waitcnt vmcnt(0)" ::: "memory");
    }
    __builtin_amdgcn_sched_barrier(0);
    __builtin_amdgcn_s_barrier();
    __builtin_amdgcn_sched_barrier(0);

    const short* KtC = &Kt[cur][0];
    const short* VtC = &Vt[cur][0];

    f32x4 sacc[4] = {};
    __builtin_amdgcn_s_setprio(1);
    #pragma unroll
    for (int kf=0;kf<2;kf++){
      #pragma unroll
      for (int mk=0;mk<4;mk++){
        int r = mk*16 + l15;
        bf16x8 kfr = *(const bf16x8*)(KtC + r*64 + (((kf*4+l4) ^ (l15&7))<<3));
        sacc[mk] = mfma16(kfr, qf[kf], sacc[mk]);
      }
    }
    __builtin_amdgcn_s_setprio(0);

    float mx = sacc[0][0];
    #pragma unroll
    for (int mk=0;mk<4;mk++)
      #pragma unroll
      for (int j=0;j<4;j++) mx = fmaxf(mx, sacc[mk][j]);
    mx = fmaxf(mx, __shfl_xor(mx, 16));
    mx = fmaxf(mx, __shfl_xor(mx, 32));
    if (!__all(mx - mrun <= 8.f)){
      float mnew = fmaxf(mrun, mx);
      float fac = __expf(mrun - mnew);
      mrun = mnew;
      lrun *= fac;
      #pragma unroll
      for (int j=0;j<4;j++){
        float fj = __shfl(fac, l4*4 + j);
        #pragma unroll
        for (int nf=0;nf<4;nf++) cacc[nf][j] *= fj;
      }
    }
    float psum = 0.f;
    #pragma unroll
    for (int mk=0;mk<4;mk++)
      #pragma unroll
      for (int j=0;j<4;j++){
        float pv = __expf(sacc[mk][j] - mrun);
        sacc[mk][j] = pv; psum += pv;
      }
    psum += __shfl_xor(psum, 16);
    psum += __shfl_xor(psum, 32);
    lrun += psum;

    int pk01[4], pk23[4];
    #pragma unroll
    for (int mk=0;mk<4;mk++){
      pk01[mk] = cvtpk(sacc[mk][0], sacc[mk][1]);
      pk23[mk] = cvtpk(sacc[mk][2], sacc[mk][3]);
    }

    #pragma unroll
    for (int ks=0;ks<2;ks++){
      int srcA = l15 + ((l4&1)<<5);
      int srcB = srcA + 16;
      int hi = l4>>1;
      int w0a = __shfl(pk01[2*ks], srcA), w0b = __shfl(pk01[2*ks+1], srcA);
      int w1a = __shfl(pk23[2*ks], srcA), w1b = __shfl(pk23[2*ks+1], srcA);
      int w2a = __shfl(pk01[2*ks], srcB), w2b = __shfl(pk01[2*ks+1], srcB);
      int w3a = __shfl(pk23[2*ks], srcB), w3b = __shfl(pk23[2*ks+1], srcB);
      union { int w[4]; bf16x8 v; } pa;
      pa.w[0] = hi ? w0b : w0a;
      pa.w[1] = hi ? w1b : w1a;
      pa.w[2] = hi ? w2b : w2a;
      pa.w[3] = hi ? w3b : w3a;
      __builtin_amdgcn_s_setprio(1);
      #pragma unroll
      for (int nf=0;nf<4;nf++){
        int dh = nf*16 + l15;
        bf16x8 vf = *(const bf16x8*)(VtC + dh*64 + (((ks*4+l4) ^ (dh&7))<<3));
        cacc[nf] = mfma16(pa.v, vf, cacc[nf]);
      }
      __builtin_amdgcn_s_setprio(0);
    }

    __builtin_amdgcn_sched_barrier(0);
    __builtin_amdgcn_s_barrier();
  }
  #undef STAGE

  const int b = bh/12, h = bh%12;
  #pragma unroll
  for (int j=0;j<4;j++){
    float inv = 1.f / __shfl(lrun, l4*4 + j);
    int s = qt*64 + wave*16 + l4*4 + j;
    size_t base = ((size_t)b*2048 + s)*768 + h*64;
    #pragma unroll
    for (int nf=0;nf<4;nf++)
      ctx[base + nf*16 + l15] = f2bf(cacc[nf][j] * inv);
  }
}

extern "C" void kernel_launch(void* const* d_in, const int* in_sizes, int n_in,
                              void* d_out, int out_size, void* d_ws, size_t ws_size,
                              hipStream_t stream){
  (void)in_sizes; (void)n_in; (void)out_size;
  const float* src   = (const float*)d_in[0];
  const float* wq    = (const float*)d_in[1];
  const float* bq    = (const float*)d_in[2];
  const float* wk    = (const float*)d_in[3];
  const float* bk    = (const float*)d_in[4];
  const float* wv    = (const float*)d_in[5];
  const float* bv    = (const float*)d_in[6];
  const float* wo    = (const float*)d_in[7];
  const float* bo    = (const float*)d_in[8];
  const float* wfc1  = (const float*)d_in[9];
  const float* bfc1  = (const float*)d_in[10];
  const float* win   = (const float*)d_in[11];
  const float* wgate = (const float*)d_in[12];
  const float* wfc2  = (const float*)d_in[13];
  const float* bfc2  = (const float*)d_in[14];
  const float* gattn = (const float*)d_in[15];
  const float* gffn  = (const float*)d_in[16];

  char* ws = (char*)d_ws;
  constexpr size_t SZ_W768  = 768ull*768*2;
  constexpr size_t SZ_WFC   = 3072ull*768*2;
  constexpr size_t SZ_WFF   = 3072ull*3072*2;
  constexpr size_t SZ_ACT   = 4096ull*768*2;
  constexpr size_t SZ_ACTF  = 4096ull*768*4;
  constexpr size_t SZ_H     = 4096ull*3072*2;
  constexpr size_t OFF_WQ    = 0;
  constexpr size_t OFF_WK    = OFF_WQ + SZ_W768;
  constexpr size_t OFF_WV    = OFF_WK + SZ_W768;
  constexpr size_t OFF_WO    = OFF_WV + SZ_W768;
  constexpr size_t OFF_WFC1  = OFF_WO + SZ_W768;
  constexpr size_t OFF_WIN   = OFF_WFC1 + SZ_WFC;
  constexpr size_t OFF_WGATE = OFF_WIN + SZ_WFF;
  constexpr size_t OFF_WFC2  = OFF_WGATE + SZ_WFF;
  constexpr size_t OFF_XN    = OFF_WFC2 + SZ_WFC;
  constexpr size_t OFF_Q     = OFF_XN + SZ_ACT;
  constexpr size_t OFF_K     = OFF_Q + SZ_ACT;
  constexpr size_t OFF_V     = OFF_K + SZ_ACT;
  constexpr size_t OFF_RES   = OFF_V + SZ_ACT;
  constexpr size_t OFF_HIN   = OFF_RES + SZ_ACTF;
  constexpr size_t OFF_H2    = OFF_HIN + SZ_H;
  constexpr size_t WS_NEED   = OFF_H2 + SZ_H;
  if (ws_size < WS_NEED) return;

  short* wq_b    = (short*)(ws+OFF_WQ);     // contiguous wq,wk,wv for fused QKV GEMM
  short* wfc1_b  = (short*)(ws+OFF_WFC1);
  short* win_b   = (short*)(ws+OFF_WIN);
  short* wgate_b = (short*)(ws+OFF_WGATE);
  short* wfc2_b  = (short*)(ws+OFF_WFC2);
  short* wo_b    = (short*)(ws+OFF_WO);
  short* xn      = (short*)(ws+OFF_XN);
  short* ctxb    = (short*)(ws+OFF_XN);
  short* qb      = (short*)(ws+OFF_Q);
  short* yb      = (short*)(ws+OFF_Q);
  short* kb2     = (short*)(ws+OFF_K);
  short* vb2     = (short*)(ws+OFF_V);
  float* resid   = (float*)(ws+OFF_RES);
  short* h1      = (short*)(ws+OFF_K);
  short* hin     = (short*)(ws+OFF_HIN);
  short* h2      = (short*)(ws+OFF_H2);

  k_convert8<<<25344, 256, 0, stream>>>(wq, wk, wv, wo, wfc1, win, wgate, wfc2, wq_b);

  k_rmsnorm<<<1024, 256, 0, stream>>>(src, gattn, xn);

  // fused QKV: N=2304, B = [wq;wk;wv] contiguous
  k_gemm<EPI_QKV><<<dim3(18,32), 256, 0, stream>>>(xn, wq_b, qb, bq, kb2, bk, bv, vb2, 4096, 2304, 768);

  k_attn<<<dim3(32, 24), 256, 0, stream>>>(qb, kb2, vb2, ctxb);

  k_gemm<EPI_RESID><<<dim3(6,32), 256, 0, stream>>>(ctxb, wo_b, resid, bo, src, nullptr, nullptr, nullptr, 4096, 768, 768);
  k_rmsnorm<<<1024, 256, 0, stream>>>(resid, gffn, yb);

  dim3 gff(8, 32);
  k_ff<EPI_BF16><<<gff, 512, 0, stream>>>(yb, wfc1_b, h1, bfc1, nullptr, 3072, 768);
  k_ff<EPI_BF16><<<gff, 512, 0, stream>>>(h1, win_b, hin, nullptr, nullptr, 3072, 3072);
  k_ff<EPI_SWIGLU><<<gff, 512, 0, stream>>>(h1, wgate_b, h2, nullptr, hin, 3072, 3072);

  k_gemm<EPI_FINAL><<<dim3(6,32), 256, 0, stream>>>(h2, wfc2_b, d_out, bfc2, yb, nullptr, nullptr, nullptr, 4096, 768, 3072);
}

// Round 5
// 378.132 us; speedup vs baseline: 1.4999x; 1.0150x over previous
//
#include <hip/hip_runtime.h>

#define DEV static __device__ __forceinline__

typedef __attribute__((ext_vector_type(8))) short bf16x8;
typedef __attribute__((ext_vector_type(4))) short short4v;
typedef __attribute__((ext_vector_type(4))) float f32x4;

DEV f32x4 mfma16(bf16x8 a, bf16x8 b, f32x4 c){
  return __builtin_amdgcn_mfma_f32_16x16x32_bf16(a, b, c, 0, 0, 0);
}
DEV float bf2f(short s){ union{unsigned u; float f;} v; v.u=((unsigned)(unsigned short)s)<<16; return v.f; }
DEV short f2bf(float f){ union{float f; unsigned u;} v; v.f=f; unsigned r=v.u+0x7fffu+((v.u>>16)&1u); return (short)(r>>16); }
DEV void gload16(const void* g, void* l){
  __builtin_amdgcn_global_load_lds((const __attribute__((address_space(1))) void*)g,
                                   (__attribute__((address_space(3))) void*)l, 16, 0, 0);
}
DEV int cvtpk(float lo, float hi){
  int r; asm("v_cvt_pk_bf16_f32 %0, %1, %2" : "=v"(r) : "v"(lo), "v"(hi)); return r;
}

enum { EPI_BF16=0, EPI_SWIGLU=1, EPI_RESID=2, EPI_FINAL=3, EPI_QKV=4 };

// ---------------- fused weight convert f32 -> bf16 (all 8 weights, contiguous dst) ----------------
__global__ void k_convert8(const float* __restrict__ p0, const float* __restrict__ p1,
                           const float* __restrict__ p2, const float* __restrict__ p3,
                           const float* __restrict__ p4, const float* __restrict__ p5,
                           const float* __restrict__ p6, const float* __restrict__ p7,
                           short* __restrict__ dst){
  int v = blockIdx.x * 256 + threadIdx.x;   // vec4 index, grid sized exactly
  const float* src; int rel;
  if      (v <  147456){ src=p0; rel=v; }
  else if (v <  294912){ src=p1; rel=v-147456; }
  else if (v <  442368){ src=p2; rel=v-294912; }
  else if (v <  589824){ src=p3; rel=v-442368; }
  else if (v < 1179648){ src=p4; rel=v-589824; }
  else if (v < 3538944){ src=p5; rel=v-1179648; }
  else if (v < 5898240){ src=p6; rel=v-3538944; }
  else                 { src=p7; rel=v-5898240; }
  float4 x = ((const float4*)src)[rel];
  short4v o; o.x=f2bf(x.x); o.y=f2bf(x.y); o.z=f2bf(x.z); o.w=f2bf(x.w);
  ((short4v*)dst)[v] = o;
}

// ---------------- RMSNorm over 768 f32 -> bf16 (1 wave / row) ----------------
__global__ void k_rmsnorm(const float* __restrict__ x, const float* __restrict__ g,
                          short* __restrict__ out){
  int row = blockIdx.x*4 + (threadIdx.x>>6);
  int lane = threadIdx.x & 63;
  const float* xr = x + (size_t)row*768;
  float4 v[3];
  float ss = 0.f;
  #pragma unroll
  for (int i=0;i<3;i++){
    v[i] = *(const float4*)(xr + i*256 + lane*4);
    ss += v[i].x*v[i].x + v[i].y*v[i].y + v[i].z*v[i].z + v[i].w*v[i].w;
  }
  #pragma unroll
  for (int d=32; d>0; d>>=1) ss += __shfl_xor(ss, d);
  float sc = rsqrtf(ss*(1.f/768.f) + 1.1920929e-7f);
  #pragma unroll
  for (int i=0;i<3;i++){
    int c0 = i*256 + lane*4;
    float4 gv = *(const float4*)(g + c0);
    short4v o;
    o.x = f2bf(v[i].x*sc*gv.x); o.y = f2bf(v[i].y*sc*gv.y);
    o.z = f2bf(v[i].z*sc*gv.z); o.w = f2bf(v[i].w*sc*gv.w);
    *(short4v*)(out + (size_t)row*768 + c0) = o;
  }
}

// ---------------- NT GEMM (m97 128x128): used for QKV (N=2304), Wo, fc2 ----------------
template<int EPI>
__launch_bounds__(256, 2)
__global__ void k_gemm(const short* __restrict__ Aptr, const short* __restrict__ Bptr,
                       void* __restrict__ Cout, const float* __restrict__ bias,
                       const void* __restrict__ aux, const float* __restrict__ bias2,
                       const float* __restrict__ bias3, const void* __restrict__ aux2,
                       int M, int N, int K){
  __shared__ short ldsA[128*32];
  __shared__ short ldsB[128*32];
  const int t = threadIdx.x;
  const int wave = t >> 6, lane = t & 63;
  const int l15 = lane & 15, l4 = lane >> 4;
  const int nwg = gridDim.x * gridDim.y;
  const int bid0 = blockIdx.y * gridDim.x + blockIdx.x;
  const int cpx = nwg >> 3;
  const int bid = (bid0 & 7) * cpx + (bid0 >> 3);
  const int bm = bid / gridDim.x, bn = bid % gridDim.x;
  const int wr = wave >> 1, wc = wave & 1;

  f32x4 acc[4][4] = {};

  const short* Ag = Aptr + (size_t)(bm*128 + wave*32 + (lane>>2))*K + (lane&3)*8;
  const short* Bg = Bptr + (size_t)(bn*128 + wave*32 + (lane>>2))*K + (lane&3)*8;
  short* lA = ldsA + wave*1024;
  short* lB = ldsB + wave*1024;

  for (int k0 = 0; k0 < K; k0 += 32){
    __syncthreads();
    gload16(Ag + k0,                lA);
    gload16(Ag + k0 + 16*(size_t)K, lA + 512);
    gload16(Bg + k0,                lB);
    gload16(Bg + k0 + 16*(size_t)K, lB + 512);
    __syncthreads();
    bf16x8 af[4], bfr[4];
    #pragma unroll
    for (int m=0;m<4;m++) af[m]  = *(const bf16x8*)(ldsA + (wr*64 + m*16 + l15)*32 + l4*8);
    #pragma unroll
    for (int n=0;n<4;n++) bfr[n] = *(const bf16x8*)(ldsB + (wc*64 + n*16 + l15)*32 + l4*8);
    #pragma unroll
    for (int m=0;m<4;m++)
      #pragma unroll
      for (int n=0;n<4;n++)
        acc[m][n] = mfma16(af[m], bfr[n], acc[m][n]);
  }

  const int row0 = bm*128 + wr*64;
  const int col0 = bn*128 + wc*64;

  if constexpr (EPI == EPI_RESID){
    float* C = (float*)Cout;
    const float* srcf = (const float*)aux;
    float bvv[4];
    #pragma unroll
    for (int n=0;n<4;n++) bvv[n] = bias[col0 + n*16 + l15];
    #pragma unroll
    for (int m=0;m<4;m++)
      #pragma unroll
      for (int j=0;j<4;j++){
        size_t rb = (size_t)(row0 + m*16 + l4*4 + j)*N + col0 + l15;
        #pragma unroll
        for (int n=0;n<4;n++) C[rb + n*16] = acc[m][n][j] + bvv[n] + srcf[rb + n*16];
      }
  } else if constexpr (EPI == EPI_FINAL){
    float* C = (float*)Cout;
    const short* yv = (const short*)aux;
    float bvv[4];
    #pragma unroll
    for (int n=0;n<4;n++) bvv[n] = bias[col0 + n*16 + l15];
    #pragma unroll
    for (int m=0;m<4;m++)
      #pragma unroll
      for (int j=0;j<4;j++){
        size_t rb = (size_t)(row0 + m*16 + l4*4 + j)*N + col0 + l15;
        #pragma unroll
        for (int n=0;n<4;n++) C[rb + n*16] = acc[m][n][j] + bvv[n] + bf2f(yv[rb + n*16]);
      }
  } else if constexpr (EPI == EPI_QKV){
    // col0 in [0,2304): proj 0=Q (rope+0.125), 1=K (rope), 2=V (write V^T [B,H,64,S])
    const int proj = col0 / 768;
    const int c768 = col0 - proj*768;
    const int h = c768 >> 6;
    const float* bs = proj==0 ? bias : (proj==1 ? bias2 : bias3);
    float bvv[4];
    #pragma unroll
    for (int n=0;n<4;n++) bvv[n] = bs[c768 + n*16 + l15];
    if (proj == 2){
      short* Ov = (short*)const_cast<void*>(aux2);
      #pragma unroll
      for (int m=0;m<4;m++){
        #pragma unroll
        for (int j=0;j<4;j++){
          int row = row0 + m*16 + l4*4 + j;
          int b = row >> 11, s = row & 2047;
          size_t hb = (size_t)(b*12 + h)*64;
          #pragma unroll
          for (int n=0;n<4;n++)
            Ov[(hb + n*16 + l15)*2048 + s] = f2bf(acc[m][n][j] + bvv[n]);
        }
      }
    } else {
      short* O = proj==0 ? (short*)Cout : (short*)const_cast<void*>(aux);
      const float sc = proj==0 ? 0.125f : 1.0f;
      const float RC = 0.41524101186092034f;  // log2(10000)/32
      float invf0 = exp2f(-(float)l15 * RC);
      float invf1 = exp2f(-(float)(16 + l15) * RC);
      #pragma unroll
      for (int m=0;m<4;m++){
        #pragma unroll
        for (int j=0;j<4;j++){
          int row = row0 + m*16 + l4*4 + j;
          int b = row >> 11, s = row & 2047;
          size_t obase = ((size_t)(b*12 + h)*2048 + (size_t)s)*64;
          float a0 = acc[m][0][j] + bvv[0];
          float a1 = acc[m][1][j] + bvv[1];
          float a2 = acc[m][2][j] + bvv[2];
          float a3 = acc[m][3][j] + bvv[3];
          float sn0, cs0, sn1, cs1;
          __sincosf((float)s * invf0, &sn0, &cs0);
          __sincosf((float)s * invf1, &sn1, &cs1);
          O[obase + l15]      = f2bf((a0*cs0 - a2*sn0)*sc);
          O[obase + 16 + l15] = f2bf((a1*cs1 - a3*sn1)*sc);
          O[obase + 32 + l15] = f2bf((a2*cs0 + a0*sn0)*sc);
          O[obase + 48 + l15] = f2bf((a3*cs1 + a1*sn1)*sc);
        }
      }
    }
  }
}

// ---------------- Pipelined NT GEMM, 128x384 (fc1 only now) ----------------
template<int EPI>
__launch_bounds__(512, 2)
__global__ void k_ff(const short* __restrict__ Aptr, const short* __restrict__ Bptr,
                     short* __restrict__ Cout, const float* __restrict__ bias,
                     const short* __restrict__ hinp, int N, int K){
  __shared__ short lds[3*16384];
  const int tid = threadIdx.x;
  const int wave = tid >> 6, lane = tid & 63;
  const int l15 = lane & 15, l4 = lane >> 4;
  const int wm = wave >> 2, wn = wave & 3;

  const int nwg = gridDim.x * gridDim.y;
  const int bid0 = blockIdx.y * gridDim.x + blockIdx.x;
  const int cpx = nwg >> 3;
  const int bid = (bid0 & 7) * cpx + (bid0 >> 3);
  const int bm = bid / gridDim.x, bn = bid % gridDim.x;

  const int chA = wave*64 + lane;
  const int rowA = chA >> 2;
  const int cA = (chA & 3) ^ ((rowA >> 1) & 3);
  const size_t aOff = (size_t)(bm*128 + rowA)*K + cA*8;
  const int chB0 = wave*64 + lane, chB1 = 512 + chB0, chB2 = 1024 + chB0;
  const int rB0 = chB0>>2, rB1 = chB1>>2, rB2 = chB2>>2;
  const size_t bOff0 = (size_t)(bn*384 + rB0)*K + (((chB0&3) ^ ((rB0>>1)&3))*8);
  const size_t bOff1 = (size_t)(bn*384 + rB1)*K + (((chB1&3) ^ ((rB1>>1)&3))*8);
  const size_t bOff2 = (size_t)(bn*384 + rB2)*K + (((chB2&3) ^ ((rB2>>1)&3))*8);
  const int stA = wave*512;

  int offA[4], offB[6];
  #pragma unroll
  for (int m=0;m<4;m++){
    int r = wm*64 + m*16 + l15;
    offA[m] = r*32 + ((l4 ^ ((r>>1)&3))<<3);
  }
  #pragma unroll
  for (int n=0;n<6;n++){
    int r = wn*96 + n*16 + l15;
    offB[n] = 4096 + r*32 + ((l4 ^ ((r>>1)&3))<<3);
  }

  short *p0 = lds, *p1 = lds + 16384, *p2 = lds + 32768;
  f32x4 acc[4][6] = {};
  const int nt = K >> 5;

  #define FFSTAGE(buf, t) do{ \
    gload16(Aptr + aOff  + (size_t)(t)*32, (buf) + stA); \
    gload16(Bptr + bOff0 + (size_t)(t)*32, (buf) + 4096  + stA); \
    gload16(Bptr + bOff1 + (size_t)(t)*32, (buf) + 8192  + stA); \
    gload16(Bptr + bOff2 + (size_t)(t)*32, (buf) + 12288 + stA); \
  }while(0)

  FFSTAGE(p0, 0);
  FFSTAGE(p1, 1);

  for (int t = 0; t < nt; ++t){
    if (t + 2 < nt){
      FFSTAGE(p2, t+2);
      asm volatile("s_waitcnt vmcnt(8)" ::: "memory");
    } else if (t + 1 < nt){
      asm volatile("s_waitcnt vmcnt(4)" ::: "memory");
    } else {
      asm volatile("s_waitcnt vmcnt(0)" ::: "memory");
    }
    __builtin_amdgcn_sched_barrier(0);
    __builtin_amdgcn_s_barrier();
    __builtin_amdgcn_sched_barrier(0);

    bf16x8 bfr[6], afr[4];
    #pragma unroll
    for (int n=0;n<6;n++) bfr[n] = *(const bf16x8*)(p0 + offB[n]);
    #pragma unroll
    for (int m=0;m<4;m++) afr[m] = *(const bf16x8*)(p0 + offA[m]);
    __builtin_amdgcn_s_setprio(1);
    #pragma unroll
    for (int m=0;m<4;m++)
      #pragma unroll
      for (int n=0;n<6;n++)
        acc[m][n] = mfma16(afr[m], bfr[n], acc[m][n]);
    __builtin_amdgcn_s_setprio(0);

    __builtin_amdgcn_sched_barrier(0);
    __builtin_amdgcn_s_barrier();
    short* tmp = p0; p0 = p1; p1 = p2; p2 = tmp;
  }
  #undef FFSTAGE

  const int row0 = bm*128 + wm*64;
  const int col0 = bn*384 + wn*96;

  if constexpr (EPI == EPI_BF16){
    float bvv[6];
    #pragma unroll
    for (int n=0;n<6;n++) bvv[n] = bias ? bias[col0 + n*16 + l15] : 0.f;
    #pragma unroll
    for (int m=0;m<4;m++)
      #pragma unroll
      for (int j=0;j<4;j++){
        size_t rb = (size_t)(row0 + m*16 + l4*4 + j)*N + col0 + l15;
        #pragma unroll
        for (int n=0;n<6;n++) Cout[rb + n*16] = f2bf(acc[m][n][j] + bvv[n]);
      }
  } else {
    #pragma unroll
    for (int m=0;m<4;m++)
      #pragma unroll
      for (int j=0;j<4;j++){
        size_t rb = (size_t)(row0 + m*16 + l4*4 + j)*N + col0 + l15;
        #pragma unroll
        for (int n=0;n<6;n++){
          float gt = acc[m][n][j];
          Cout[rb + n*16] = f2bf(bf2f(hinp[rb + n*16]) * gt / (1.f + __expf(-gt)));
        }
      }
  }
}

// ---------------- Fused SwiGLU GEMM: h2 = (A@Wv^T) * silu(A@Wg^T), shared A ----------------
// BM=128, BN=192 (per weight), BK=32, 512 threads (8 waves 2x4), dbuf 64KB -> 2 blocks/CU.
// Per buf: A [0,4096), Bv [4096,10240), Bg [10240,16384) shorts. Chunk c of row r at c^((r>>1)&3).
__launch_bounds__(512, 2)
__global__ void k_ffglu(const short* __restrict__ Aptr, const short* __restrict__ Wv,
                        const short* __restrict__ Wg, short* __restrict__ Cout){
  __shared__ short lds[2*16384];
  const int tid = threadIdx.x;
  const int wave = tid >> 6, lane = tid & 63;
  const int l15 = lane & 15, l4 = lane >> 4;
  const int wm = wave >> 2, wn = wave & 3;
  const int K = 3072, N = 3072;

  const int nwg = gridDim.x * gridDim.y;
  const int bid0 = blockIdx.y * gridDim.x + blockIdx.x;
  const int cpx = nwg >> 3;
  const int bid = (bid0 & 7) * cpx + (bid0 >> 3);
  const int bm = bid / gridDim.x, bn = bid % gridDim.x;

  // staging plan: 32 wave-issues/tile, 4 per wave. cb = wave*4+i.
  // cb 0..7 -> A (512 chunks); cb 8..19 -> Bv (768); cb 20..31 -> Bg (768).
  const short* gsrc[4];
  int lof[4];
  #pragma unroll
  for (int i=0;i<4;i++){
    int cb = wave*4 + i;
    if (cb < 8){
      int ch = cb*64 + lane;
      int row = ch >> 2, c = (ch & 3) ^ ((row >> 1) & 3);
      gsrc[i] = Aptr + (size_t)(bm*128 + row)*K + c*8;
      lof[i] = cb*512;   // == ch*8 - lane*8 + lane*8 ; wave-uniform base cb*512
    } else if (cb < 20){
      int lb = (cb-8)*64 + lane;
      int row = lb >> 2, c = (lb & 3) ^ ((row >> 1) & 3);
      gsrc[i] = Wv + (size_t)(bn*192 + row)*K + c*8;
      lof[i] = 4096 + (cb-8)*512;
    } else {
      int lb = (cb-20)*64 + lane;
      int row = lb >> 2, c = (lb & 3) ^ ((row >> 1) & 3);
      gsrc[i] = Wg + (size_t)(bn*192 + row)*K + c*8;
      lof[i] = 10240 + (cb-20)*512;
    }
  }

  int offA[4], offV[3], offG[3];
  #pragma unroll
  for (int m=0;m<4;m++){
    int r = wm*64 + m*16 + l15;
    offA[m] = r*32 + ((l4 ^ ((r>>1)&3))<<3);
  }
  #pragma unroll
  for (int n=0;n<3;n++){
    int r = wn*48 + n*16 + l15;
    offV[n] = 4096  + r*32 + ((l4 ^ ((r>>1)&3))<<3);
    offG[n] = 10240 + r*32 + ((l4 ^ ((r>>1)&3))<<3);
  }

  f32x4 accv[4][3] = {};
  f32x4 accg[4][3] = {};
  const int nt = K >> 5;   // 96

  #define GLUSTAGE(buf, t) do{ \
    gload16(gsrc[0] + (size_t)(t)*32, (buf) + lof[0]); \
    gload16(gsrc[1] + (size_t)(t)*32, (buf) + lof[1]); \
    gload16(gsrc[2] + (size_t)(t)*32, (buf) + lof[2]); \
    gload16(gsrc[3] + (size_t)(t)*32, (buf) + lof[3]); \
  }while(0)

  short *pc = lds, *pn = lds + 16384;
  GLUSTAGE(pc, 0);

  for (int t = 0; t < nt; ++t){
    if (t + 1 < nt){
      GLUSTAGE(pn, t+1);
      asm volatile("s_waitcnt vmcnt(4)" ::: "memory");
    } else {
      asm volatile("s_waitcnt vmcnt(0)" ::: "memory");
    }
    __builtin_amdgcn_sched_barrier(0);
    __builtin_amdgcn_s_barrier();
    __builtin_amdgcn_sched_barrier(0);

    bf16x8 afr[4];
    #pragma unroll
    for (int m=0;m<4;m++) afr[m] = *(const bf16x8*)(pc + offA[m]);
    #pragma unroll
    for (int n=0;n<3;n++){
      bf16x8 bv = *(const bf16x8*)(pc + offV[n]);
      bf16x8 bg = *(const bf16x8*)(pc + offG[n]);
      __builtin_amdgcn_s_setprio(1);
      #pragma unroll
      for (int m=0;m<4;m++){
        accv[m][n] = mfma16(afr[m], bv, accv[m][n]);
        accg[m][n] = mfma16(afr[m], bg, accg[m][n]);
      }
      __builtin_amdgcn_s_setprio(0);
    }

    __builtin_amdgcn_sched_barrier(0);
    __builtin_amdgcn_s_barrier();
    short* tmp = pc; pc = pn; pn = tmp;
  }
  #undef GLUSTAGE

  const int row0 = bm*128 + wm*64;
  const int col0 = bn*192 + wn*48;
  #pragma unroll
  for (int m=0;m<4;m++)
    #pragma unroll
    for (int j=0;j<4;j++){
      size_t rb = (size_t)(row0 + m*16 + l4*4 + j)*N + col0 + l15;
      #pragma unroll
      for (int n=0;n<3;n++){
        float g = accg[m][n][j];
        float v = accv[m][n][j];
        Cout[rb + n*16] = f2bf(v * g / (1.f + __expf(-g)));
      }
    }
}

// ---------------- Flash attention: swapped-QK, double-buffered KV, counted vmcnt ----------------
__launch_bounds__(256, 3)
__global__ void k_attn(const short* __restrict__ Q, const short* __restrict__ Kb,
                       const short* __restrict__ Vb, short* __restrict__ ctx){
  __shared__ short Kt[2][4096];
  __shared__ short Vt[2][4096];
  const int t = threadIdx.x, wave = t>>6, lane = t&63;
  const int l15 = lane&15, l4 = lane>>4;
  const int qt = blockIdx.x, bh = blockIdx.y;
  const short* Qh  = Q  + (size_t)bh*2048*64;
  const short* Kh  = Kb + (size_t)bh*2048*64;
  const short* Vth = Vb + (size_t)bh*64*2048;

  const int r7  = lane>>3;
  const int swz = ((lane&7) ^ r7) << 3;
  const int rr0 = wave*8 + r7, rr1 = 32 + wave*8 + r7;
  const size_t kOff0 = (size_t)rr0*64   + swz, kOff1 = (size_t)rr1*64   + swz;
  const size_t vOff0 = (size_t)rr0*2048 + swz, vOff1 = (size_t)rr1*2048 + swz;

  bf16x8 qf[2];
  #pragma unroll
  for (int kf=0;kf<2;kf++)
    qf[kf] = *(const bf16x8*)(Qh + (size_t)(qt*64 + wave*16 + l15)*64 + kf*32 + l4*8);

  f32x4 cacc[4] = {};
  float mrun = -1e30f, lrun = 0.f;

  #define STAGE(sel, kv0) do { \
    const short* ksp = Kh + (size_t)(kv0)*64; \
    const short* vsp = Vth + (kv0); \
    short* kd = &Kt[sel][wave*512]; \
    short* vd = &Vt[sel][wave*512]; \
    gload16(ksp + kOff0, kd); \
    gload16(ksp + kOff1, kd + 2048); \
    gload16(vsp + vOff0, vd); \
    gload16(vsp + vOff1, vd + 2048); \
  } while(0)

  STAGE(0, 0);

  for (int tt = 0; tt < 32; ++tt){
    const int cur = tt & 1;
    if (tt < 31){
      STAGE(cur^1, (tt+1)*64);
      asm volatile("s_waitcnt vmcnt(4)" ::: "memory");
    } else {
      asm volatile("s_waitcnt vmcnt(0)" ::: "memory");
    }
    __builtin_amdgcn_sched_barrier(0);
    __builtin_amdgcn_s_barrier();
    __builtin_amdgcn_sched_barrier(0);

    const short* KtC = &Kt[cur][0];
    const short* VtC = &Vt[cur][0];

    f32x4 sacc[4] = {};
    __builtin_amdgcn_s_setprio(1);
    #pragma unroll
    for (int kf=0;kf<2;kf++){
      #pragma unroll
      for (int mk=0;mk<4;mk++){
        int r = mk*16 + l15;
        bf16x8 kfr = *(const bf16x8*)(KtC + r*64 + (((kf*4+l4) ^ (l15&7))<<3));
        sacc[mk] = mfma16(kfr, qf[kf], sacc[mk]);
      }
    }
    __builtin_amdgcn_s_setprio(0);

    float mx = sacc[0][0];
    #pragma unroll
    for (int mk=0;mk<4;mk++)
      #pragma unroll
      for (int j=0;j<4;j++) mx = fmaxf(mx, sacc[mk][j]);
    mx = fmaxf(mx, __shfl_xor(mx, 16));
    mx = fmaxf(mx, __shfl_xor(mx, 32));
    if (!__all(mx - mrun <= 8.f)){
      float mnew = fmaxf(mrun, mx);
      float fac = __expf(mrun - mnew);
      mrun = mnew;
      lrun *= fac;
      #pragma unroll
      for (int j=0;j<4;j++){
        float fj = __shfl(fac, l4*4 + j);
        #pragma unroll
        for (int nf=0;nf<4;nf++) cacc[nf][j] *= fj;
      }
    }
    float psum = 0.f;
    #pragma unroll
    for (int mk=0;mk<4;mk++)
      #pragma unroll
      for (int j=0;j<4;j++){
        float pv = __expf(sacc[mk][j] - mrun);
        sacc[mk][j] = pv; psum += pv;
      }
    psum += __shfl_xor(psum, 16);
    psum += __shfl_xor(psum, 32);
    lrun += psum;

    int pk01[4], pk23[4];
    #pragma unroll
    for (int mk=0;mk<4;mk++){
      pk01[mk] = cvtpk(sacc[mk][0], sacc[mk][1]);
      pk23[mk] = cvtpk(sacc[mk][2], sacc[mk][3]);
    }

    #pragma unroll
    for (int ks=0;ks<2;ks++){
      int srcA = l15 + ((l4&1)<<5);
      int srcB = srcA + 16;
      int hi = l4>>1;
      int w0a = __shfl(pk01[2*ks], srcA), w0b = __shfl(pk01[2*ks+1], srcA);
      int w1a = __shfl(pk23[2*ks], srcA), w1b = __shfl(pk23[2*ks+1], srcA);
      int w2a = __shfl(pk01[2*ks], srcB), w2b = __shfl(pk01[2*ks+1], srcB);
      int w3a = __shfl(pk23[2*ks], srcB), w3b = __shfl(pk23[2*ks+1], srcB);
      union { int w[4]; bf16x8 v; } pa;
      pa.w[0] = hi ? w0b : w0a;
      pa.w[1] = hi ? w1b : w1a;
      pa.w[2] = hi ? w2b : w2a;
      pa.w[3] = hi ? w3b : w3a;
      __builtin_amdgcn_s_setprio(1);
      #pragma unroll
      for (int nf=0;nf<4;nf++){
        int dh = nf*16 + l15;
        bf16x8 vf = *(const bf16x8*)(VtC + dh*64 + (((ks*4+l4) ^ (dh&7))<<3));
        cacc[nf] = mfma16(pa.v, vf, cacc[nf]);
      }
      __builtin_amdgcn_s_setprio(0);
    }

    __builtin_amdgcn_sched_barrier(0);
    __builtin_amdgcn_s_barrier();
  }
  #undef STAGE

  const int b = bh/12, h = bh%12;
  #pragma unroll
  for (int j=0;j<4;j++){
    float inv = 1.f / __shfl(lrun, l4*4 + j);
    int s = qt*64 + wave*16 + l4*4 + j;
    size_t base = ((size_t)b*2048 + s)*768 + h*64;
    #pragma unroll
    for (int nf=0;nf<4;nf++)
      ctx[base + nf*16 + l15] = f2bf(cacc[nf][j] * inv);
  }
}

extern "C" void kernel_launch(void* const* d_in, const int* in_sizes, int n_in,
                              void* d_out, int out_size, void* d_ws, size_t ws_size,
                              hipStream_t stream){
  (void)in_sizes; (void)n_in; (void)out_size;
  const float* src   = (const float*)d_in[0];
  const float* wq    = (const float*)d_in[1];
  const float* bq    = (const float*)d_in[2];
  const float* wk    = (const float*)d_in[3];
  const float* bk    = (const float*)d_in[4];
  const float* wv    = (const float*)d_in[5];
  const float* bv    = (const float*)d_in[6];
  const float* wo    = (const float*)d_in[7];
  const float* bo    = (const float*)d_in[8];
  const float* wfc1  = (const float*)d_in[9];
  const float* bfc1  = (const float*)d_in[10];
  const float* win   = (const float*)d_in[11];
  const float* wgate = (const float*)d_in[12];
  const float* wfc2  = (const float*)d_in[13];
  const float* bfc2  = (const float*)d_in[14];
  const float* gattn = (const float*)d_in[15];
  const float* gffn  = (const float*)d_in[16];

  char* ws = (char*)d_ws;
  constexpr size_t SZ_W768  = 768ull*768*2;
  constexpr size_t SZ_WFC   = 3072ull*768*2;
  constexpr size_t SZ_WFF   = 3072ull*3072*2;
  constexpr size_t SZ_ACT   = 4096ull*768*2;
  constexpr size_t SZ_ACTF  = 4096ull*768*4;
  constexpr size_t SZ_H     = 4096ull*3072*2;
  constexpr size_t OFF_WQ    = 0;
  constexpr size_t OFF_WK    = OFF_WQ + SZ_W768;
  constexpr size_t OFF_WV    = OFF_WK + SZ_W768;
  constexpr size_t OFF_WO    = OFF_WV + SZ_W768;
  constexpr size_t OFF_WFC1  = OFF_WO + SZ_W768;
  constexpr size_t OFF_WIN   = OFF_WFC1 + SZ_WFC;
  constexpr size_t OFF_WGATE = OFF_WIN + SZ_WFF;
  constexpr size_t OFF_WFC2  = OFF_WGATE + SZ_WFF;
  constexpr size_t OFF_XN    = OFF_WFC2 + SZ_WFC;
  constexpr size_t OFF_Q     = OFF_XN + SZ_ACT;
  constexpr size_t OFF_K     = OFF_Q + SZ_ACT;
  constexpr size_t OFF_V     = OFF_K + SZ_ACT;
  constexpr size_t OFF_RES   = OFF_V + SZ_ACT;
  constexpr size_t OFF_HIN   = OFF_RES + SZ_ACTF;
  constexpr size_t OFF_H2    = OFF_HIN + SZ_H;
  constexpr size_t WS_NEED   = OFF_H2 + SZ_H;
  if (ws_size < WS_NEED) return;

  short* wq_b    = (short*)(ws+OFF_WQ);     // contiguous wq,wk,wv for fused QKV GEMM
  short* wfc1_b  = (short*)(ws+OFF_WFC1);
  short* win_b   = (short*)(ws+OFF_WIN);
  short* wgate_b = (short*)(ws+OFF_WGATE);
  short* wfc2_b  = (short*)(ws+OFF_WFC2);
  short* wo_b    = (short*)(ws+OFF_WO);
  short* xn      = (short*)(ws+OFF_XN);
  short* ctxb    = (short*)(ws+OFF_XN);
  short* qb      = (short*)(ws+OFF_Q);
  short* yb      = (short*)(ws+OFF_Q);
  short* kb2     = (short*)(ws+OFF_K);
  short* vb2     = (short*)(ws+OFF_V);
  float* resid   = (float*)(ws+OFF_RES);
  short* h1      = (short*)(ws+OFF_K);
  short* h2      = (short*)(ws+OFF_H2);

  k_convert8<<<25344, 256, 0, stream>>>(wq, wk, wv, wo, wfc1, win, wgate, wfc2, wq_b);

  k_rmsnorm<<<1024, 256, 0, stream>>>(src, gattn, xn);

  // fused QKV: N=2304, B = [wq;wk;wv] contiguous
  k_gemm<EPI_QKV><<<dim3(18,32), 256, 0, stream>>>(xn, wq_b, qb, bq, kb2, bk, bv, vb2, 4096, 2304, 768);

  k_attn<<<dim3(32, 24), 256, 0, stream>>>(qb, kb2, vb2, ctxb);

  k_gemm<EPI_RESID><<<dim3(6,32), 256, 0, stream>>>(ctxb, wo_b, resid, bo, src, nullptr, nullptr, nullptr, 4096, 768, 768);
  k_rmsnorm<<<1024, 256, 0, stream>>>(resid, gffn, yb);

  k_ff<EPI_BF16><<<dim3(8,32), 512, 0, stream>>>(yb, wfc1_b, h1, bfc1, nullptr, 3072, 768);

  // fused SwiGLU: h2 = (h1@win^T) * silu(h1@wgate^T)
  k_ffglu<<<dim3(16,32), 512, 0, stream>>>(h1, win_b, wgate_b, h2);

  k_gemm<EPI_FINAL><<<dim3(6,32), 256, 0, stream>>>(h2, wfc2_b, d_out, bfc2, yb, nullptr, nullptr, nullptr, 4096, 768, 3072);
}

// Round 6
// 369.991 us; speedup vs baseline: 1.5329x; 1.0220x over previous
//
#include <hip/hip_runtime.h>

#define DEV static __device__ __forceinline__

typedef __attribute__((ext_vector_type(8))) short bf16x8;
typedef __attribute__((ext_vector_type(4))) short short4v;
typedef __attribute__((ext_vector_type(4))) float f32x4;

DEV f32x4 mfma16(bf16x8 a, bf16x8 b, f32x4 c){
  return __builtin_amdgcn_mfma_f32_16x16x32_bf16(a, b, c, 0, 0, 0);
}
DEV float bf2f(short s){ union{unsigned u; float f;} v; v.u=((unsigned)(unsigned short)s)<<16; return v.f; }
DEV short f2bf(float f){ union{float f; unsigned u;} v; v.f=f; unsigned r=v.u+0x7fffu+((v.u>>16)&1u); return (short)(r>>16); }
DEV void gload16(const void* g, void* l){
  __builtin_amdgcn_global_load_lds((const __attribute__((address_space(1))) void*)g,
                                   (__attribute__((address_space(3))) void*)l, 16, 0, 0);
}
DEV int cvtpk(float lo, float hi){
  int r; asm("v_cvt_pk_bf16_f32 %0, %1, %2" : "=v"(r) : "v"(lo), "v"(hi)); return r;
}

enum { EPI_BF16=0, EPI_SWIGLU=1, EPI_RESID=2, EPI_FINAL=3, EPI_QKV=4 };

// ---------------- fused weight convert f32 -> bf16 ----------------
__global__ void k_convert8(const float* __restrict__ p0, const float* __restrict__ p1,
                           const float* __restrict__ p2, const float* __restrict__ p3,
                           const float* __restrict__ p4, const float* __restrict__ p5,
                           const float* __restrict__ p6, const float* __restrict__ p7,
                           short* __restrict__ dst){
  int v = blockIdx.x * 256 + threadIdx.x;
  const float* src; int rel;
  if      (v <  147456){ src=p0; rel=v; }
  else if (v <  294912){ src=p1; rel=v-147456; }
  else if (v <  442368){ src=p2; rel=v-294912; }
  else if (v <  589824){ src=p3; rel=v-442368; }
  else if (v < 1179648){ src=p4; rel=v-589824; }
  else if (v < 3538944){ src=p5; rel=v-1179648; }
  else if (v < 5898240){ src=p6; rel=v-3538944; }
  else                 { src=p7; rel=v-5898240; }
  float4 x = ((const float4*)src)[rel];
  short4v o; o.x=f2bf(x.x); o.y=f2bf(x.y); o.z=f2bf(x.z); o.w=f2bf(x.w);
  ((short4v*)dst)[v] = o;
}

// ---------------- RMSNorm over 768 f32 -> bf16 (1 wave / row) ----------------
__global__ void k_rmsnorm(const float* __restrict__ x, const float* __restrict__ g,
                          short* __restrict__ out){
  int row = blockIdx.x*4 + (threadIdx.x>>6);
  int lane = threadIdx.x & 63;
  const float* xr = x + (size_t)row*768;
  float4 v[3];
  float ss = 0.f;
  #pragma unroll
  for (int i=0;i<3;i++){
    v[i] = *(const float4*)(xr + i*256 + lane*4);
    ss += v[i].x*v[i].x + v[i].y*v[i].y + v[i].z*v[i].z + v[i].w*v[i].w;
  }
  #pragma unroll
  for (int d=32; d>0; d>>=1) ss += __shfl_xor(ss, d);
  float sc = rsqrtf(ss*(1.f/768.f) + 1.1920929e-7f);
  #pragma unroll
  for (int i=0;i<3;i++){
    int c0 = i*256 + lane*4;
    float4 gv = *(const float4*)(g + c0);
    short4v o;
    o.x = f2bf(v[i].x*sc*gv.x); o.y = f2bf(v[i].y*sc*gv.y);
    o.z = f2bf(v[i].z*sc*gv.z); o.w = f2bf(v[i].w*sc*gv.w);
    *(short4v*)(out + (size_t)row*768 + c0) = o;
  }
}

// ---------------- NT GEMM (m97 128x128): QKV (N=2304), Wo, fc2 ----------------
template<int EPI>
__launch_bounds__(256, 2)
__global__ void k_gemm(const short* __restrict__ Aptr, const short* __restrict__ Bptr,
                       void* __restrict__ Cout, const float* __restrict__ bias,
                       const void* __restrict__ aux, const float* __restrict__ bias2,
                       const float* __restrict__ bias3, const void* __restrict__ aux2,
                       int M, int N, int K){
  __shared__ short ldsA[128*32];
  __shared__ short ldsB[128*32];
  const int t = threadIdx.x;
  const int wave = t >> 6, lane = t & 63;
  const int l15 = lane & 15, l4 = lane >> 4;
  const int nwg = gridDim.x * gridDim.y;
  const int bid0 = blockIdx.y * gridDim.x + blockIdx.x;
  const int cpx = nwg >> 3;
  const int bid = (bid0 & 7) * cpx + (bid0 >> 3);
  const int bm = bid / gridDim.x, bn = bid % gridDim.x;
  const int wr = wave >> 1, wc = wave & 1;

  f32x4 acc[4][4] = {};

  const short* Ag = Aptr + (size_t)(bm*128 + wave*32 + (lane>>2))*K + (lane&3)*8;
  const short* Bg = Bptr + (size_t)(bn*128 + wave*32 + (lane>>2))*K + (lane&3)*8;
  short* lA = ldsA + wave*1024;
  short* lB = ldsB + wave*1024;

  for (int k0 = 0; k0 < K; k0 += 32){
    __syncthreads();
    gload16(Ag + k0,                lA);
    gload16(Ag + k0 + 16*(size_t)K, lA + 512);
    gload16(Bg + k0,                lB);
    gload16(Bg + k0 + 16*(size_t)K, lB + 512);
    __syncthreads();
    bf16x8 af[4], bfr[4];
    #pragma unroll
    for (int m=0;m<4;m++) af[m]  = *(const bf16x8*)(ldsA + (wr*64 + m*16 + l15)*32 + l4*8);
    #pragma unroll
    for (int n=0;n<4;n++) bfr[n] = *(const bf16x8*)(ldsB + (wc*64 + n*16 + l15)*32 + l4*8);
    #pragma unroll
    for (int m=0;m<4;m++)
      #pragma unroll
      for (int n=0;n<4;n++)
        acc[m][n] = mfma16(af[m], bfr[n], acc[m][n]);
  }

  const int row0 = bm*128 + wr*64;
  const int col0 = bn*128 + wc*64;

  if constexpr (EPI == EPI_RESID){
    float* C = (float*)Cout;
    const float* srcf = (const float*)aux;
    float bvv[4];
    #pragma unroll
    for (int n=0;n<4;n++) bvv[n] = bias[col0 + n*16 + l15];
    #pragma unroll
    for (int m=0;m<4;m++)
      #pragma unroll
      for (int j=0;j<4;j++){
        size_t rb = (size_t)(row0 + m*16 + l4*4 + j)*N + col0 + l15;
        #pragma unroll
        for (int n=0;n<4;n++) C[rb + n*16] = acc[m][n][j] + bvv[n] + srcf[rb + n*16];
      }
  } else if constexpr (EPI == EPI_FINAL){
    float* C = (float*)Cout;
    const short* yv = (const short*)aux;
    float bvv[4];
    #pragma unroll
    for (int n=0;n<4;n++) bvv[n] = bias[col0 + n*16 + l15];
    #pragma unroll
    for (int m=0;m<4;m++)
      #pragma unroll
      for (int j=0;j<4;j++){
        size_t rb = (size_t)(row0 + m*16 + l4*4 + j)*N + col0 + l15;
        #pragma unroll
        for (int n=0;n<4;n++) C[rb + n*16] = acc[m][n][j] + bvv[n] + bf2f(yv[rb + n*16]);
      }
  } else if constexpr (EPI == EPI_QKV){
    const int proj = col0 / 768;
    const int c768 = col0 - proj*768;
    const int h = c768 >> 6;
    const float* bs = proj==0 ? bias : (proj==1 ? bias2 : bias3);
    float bvv[4];
    #pragma unroll
    for (int n=0;n<4;n++) bvv[n] = bs[c768 + n*16 + l15];
    if (proj == 2){
      short* Ov = (short*)const_cast<void*>(aux2);
      #pragma unroll
      for (int m=0;m<4;m++){
        #pragma unroll
        for (int j=0;j<4;j++){
          int row = row0 + m*16 + l4*4 + j;
          int b = row >> 11, s = row & 2047;
          size_t hb = (size_t)(b*12 + h)*64;
          #pragma unroll
          for (int n=0;n<4;n++)
            Ov[(hb + n*16 + l15)*2048 + s] = f2bf(acc[m][n][j] + bvv[n]);
        }
      }
    } else {
      short* O = proj==0 ? (short*)Cout : (short*)const_cast<void*>(aux);
      const float sc = proj==0 ? 0.125f : 1.0f;
      const float RC = 0.41524101186092034f;  // log2(10000)/32
      float invf0 = exp2f(-(float)l15 * RC);
      float invf1 = exp2f(-(float)(16 + l15) * RC);
      #pragma unroll
      for (int m=0;m<4;m++){
        #pragma unroll
        for (int j=0;j<4;j++){
          int row = row0 + m*16 + l4*4 + j;
          int b = row >> 11, s = row & 2047;
          size_t obase = ((size_t)(b*12 + h)*2048 + (size_t)s)*64;
          float a0 = acc[m][0][j] + bvv[0];
          float a1 = acc[m][1][j] + bvv[1];
          float a2 = acc[m][2][j] + bvv[2];
          float a3 = acc[m][3][j] + bvv[3];
          float sn0, cs0, sn1, cs1;
          __sincosf((float)s * invf0, &sn0, &cs0);
          __sincosf((float)s * invf1, &sn1, &cs1);
          O[obase + l15]      = f2bf((a0*cs0 - a2*sn0)*sc);
          O[obase + 16 + l15] = f2bf((a1*cs1 - a3*sn1)*sc);
          O[obase + 32 + l15] = f2bf((a2*cs0 + a0*sn0)*sc);
          O[obase + 48 + l15] = f2bf((a3*cs1 + a1*sn1)*sc);
        }
      }
    }
  }
}

// ---------------- Pipelined NT GEMM, 128x384 (fc1) ----------------
template<int EPI>
__launch_bounds__(512, 2)
__global__ void k_ff(const short* __restrict__ Aptr, const short* __restrict__ Bptr,
                     short* __restrict__ Cout, const float* __restrict__ bias,
                     const short* __restrict__ hinp, int N, int K){
  __shared__ short lds[3*16384];
  const int tid = threadIdx.x;
  const int wave = tid >> 6, lane = tid & 63;
  const int l15 = lane & 15, l4 = lane >> 4;
  const int wm = wave >> 2, wn = wave & 3;

  const int nwg = gridDim.x * gridDim.y;
  const int bid0 = blockIdx.y * gridDim.x + blockIdx.x;
  const int cpx = nwg >> 3;
  const int bid = (bid0 & 7) * cpx + (bid0 >> 3);
  const int bm = bid / gridDim.x, bn = bid % gridDim.x;

  const int chA = wave*64 + lane;
  const int rowA = chA >> 2;
  const int cA = (chA & 3) ^ ((rowA >> 1) & 3);
  const size_t aOff = (size_t)(bm*128 + rowA)*K + cA*8;
  const int chB0 = wave*64 + lane, chB1 = 512 + chB0, chB2 = 1024 + chB0;
  const int rB0 = chB0>>2, rB1 = chB1>>2, rB2 = chB2>>2;
  const size_t bOff0 = (size_t)(bn*384 + rB0)*K + (((chB0&3) ^ ((rB0>>1)&3))*8);
  const size_t bOff1 = (size_t)(bn*384 + rB1)*K + (((chB1&3) ^ ((rB1>>1)&3))*8);
  const size_t bOff2 = (size_t)(bn*384 + rB2)*K + (((chB2&3) ^ ((rB2>>1)&3))*8);
  const int stA = wave*512;

  int offA[4], offB[6];
  #pragma unroll
  for (int m=0;m<4;m++){
    int r = wm*64 + m*16 + l15;
    offA[m] = r*32 + ((l4 ^ ((r>>1)&3))<<3);
  }
  #pragma unroll
  for (int n=0;n<6;n++){
    int r = wn*96 + n*16 + l15;
    offB[n] = 4096 + r*32 + ((l4 ^ ((r>>1)&3))<<3);
  }

  short *p0 = lds, *p1 = lds + 16384, *p2 = lds + 32768;
  f32x4 acc[4][6] = {};
  const int nt = K >> 5;

  #define FFSTAGE(buf, t) do{ \
    gload16(Aptr + aOff  + (size_t)(t)*32, (buf) + stA); \
    gload16(Bptr + bOff0 + (size_t)(t)*32, (buf) + 4096  + stA); \
    gload16(Bptr + bOff1 + (size_t)(t)*32, (buf) + 8192  + stA); \
    gload16(Bptr + bOff2 + (size_t)(t)*32, (buf) + 12288 + stA); \
  }while(0)

  FFSTAGE(p0, 0);
  FFSTAGE(p1, 1);

  for (int t = 0; t < nt; ++t){
    if (t + 2 < nt){
      FFSTAGE(p2, t+2);
      asm volatile("s_waitcnt vmcnt(8)" ::: "memory");
    } else if (t + 1 < nt){
      asm volatile("s_waitcnt vmcnt(4)" ::: "memory");
    } else {
      asm volatile("s_waitcnt vmcnt(0)" ::: "memory");
    }
    __builtin_amdgcn_sched_barrier(0);
    __builtin_amdgcn_s_barrier();
    __builtin_amdgcn_sched_barrier(0);

    bf16x8 bfr[6], afr[4];
    #pragma unroll
    for (int n=0;n<6;n++) bfr[n] = *(const bf16x8*)(p0 + offB[n]);
    #pragma unroll
    for (int m=0;m<4;m++) afr[m] = *(const bf16x8*)(p0 + offA[m]);
    __builtin_amdgcn_s_setprio(1);
    #pragma unroll
    for (int m=0;m<4;m++)
      #pragma unroll
      for (int n=0;n<6;n++)
        acc[m][n] = mfma16(afr[m], bfr[n], acc[m][n]);
    __builtin_amdgcn_s_setprio(0);

    __builtin_amdgcn_sched_barrier(0);
    __builtin_amdgcn_s_barrier();
    short* tmp = p0; p0 = p1; p1 = p2; p2 = tmp;
  }
  #undef FFSTAGE

  const int row0 = bm*128 + wm*64;
  const int col0 = bn*384 + wn*96;

  if constexpr (EPI == EPI_BF16){
    float bvv[6];
    #pragma unroll
    for (int n=0;n<6;n++) bvv[n] = bias ? bias[col0 + n*16 + l15] : 0.f;
    #pragma unroll
    for (int m=0;m<4;m++)
      #pragma unroll
      for (int j=0;j<4;j++){
        size_t rb = (size_t)(row0 + m*16 + l4*4 + j)*N + col0 + l15;
        #pragma unroll
        for (int n=0;n<6;n++) Cout[rb + n*16] = f2bf(acc[m][n][j] + bvv[n]);
      }
  } else {
    #pragma unroll
    for (int m=0;m<4;m++)
      #pragma unroll
      for (int j=0;j<4;j++){
        size_t rb = (size_t)(row0 + m*16 + l4*4 + j)*N + col0 + l15;
        #pragma unroll
        for (int n=0;n<6;n++){
          float gt = acc[m][n][j];
          Cout[rb + n*16] = f2bf(bf2f(hinp[rb + n*16]) * gt / (1.f + __expf(-gt)));
        }
      }
  }
}

// ---------------- Fused SwiGLU GEMM, 4-phase pipelined ----------------
// BM=256, BN=64(v)+64(g) interleaved at 16-col granularity. 4 waves (2M x 1N... wm=wave>>1, wn=wave&1).
// Wave output = 128 rows x 64 cols (8 m-frags x 4 n-frags; nf even=v, odd=g, v/g pairs share cols).
// BK=32, triple-buffered (3 x 24KB = 72KB -> 2 blocks/CU). 4 phases/K-tile, counted vmcnt(6).
// LDS buf: A [0,8192) shorts = 256x32; B [8192,12288) = 128 logical rows x 32.
// Swizzle: 16B chunk c of row r at c^((r>>1)&3), both sides (involution).
__launch_bounds__(256, 2)
__global__ void k_ffglu(const short* __restrict__ Aptr, const short* __restrict__ Wv,
                        const short* __restrict__ Wg, short* __restrict__ Cout){
  __shared__ short lds[3*12288];
  const int tid = threadIdx.x;
  const int wave = tid >> 6, lane = tid & 63;
  const int l15 = lane & 15, l4 = lane >> 4;
  const int wm = wave >> 1, wn = wave & 1;
  const int K = 3072, N = 3072;
  const int nt = 96;

  // grid (48, 16): x=bn, y=bm. XCD swizzle (768 blocks, cpx=96).
  const int bid0 = blockIdx.y * 48 + blockIdx.x;
  const int bid = (bid0 & 7) * 96 + (bid0 >> 3);
  const int bm = bid / 48, bn = bid % 48;

  // source chunk swizzle (same for all slots): (lane&3) ^ ((lane>>3)&3)
  const int srcC = ((lane & 3) ^ ((lane >> 3) & 3)) * 8;

  // A staging: slot s = i*4+wave stages rows [s*16, s*16+16); lane -> row s*16+(lane>>2)
  const short* aSrc[4];
  int aDst[4];
  #pragma unroll
  for (int i=0;i<4;i++){
    int s = i*4 + wave;
    int row = s*16 + (lane>>2);
    aSrc[i] = Aptr + (size_t)(bm*256 + row)*K + srcC;
    aDst[i] = s*512;
  }
  // B staging: slot j = i*4+wave stages logical rows [j*16, j*16+16)
  // logical row r: panel=(r>>4)&1 (0=v,1=g), pidx=((r>>5)<<4)+(r&15)
  const short* bSrc[2];
  int bDst[2];
  #pragma unroll
  for (int i=0;i<2;i++){
    int j = i*4 + wave;
    int pidx = (j>>1)*16 + (lane>>2);
    const short* W = (j & 1) ? Wg : Wv;
    bSrc[i] = W + (size_t)(bn*64 + pidx)*K + srcC;
    bDst[i] = 8192 + j*512;
  }

  // ds_read offsets
  int offA[8], offB[4];
  #pragma unroll
  for (int m=0;m<8;m++){
    int r = wm*128 + m*16 + l15;
    offA[m] = r*32 + ((l4 ^ ((l15>>1)&3))<<3);
  }
  #pragma unroll
  for (int nf=0;nf<4;nf++){
    int r = wn*64 + nf*16 + l15;
    offB[nf] = 8192 + r*32 + ((l4 ^ ((l15>>1)&3))<<3);
  }

  f32x4 accv[8][2] = {};
  f32x4 accg[8][2] = {};

  short *b0 = lds, *b1 = lds + 12288, *b2 = lds + 24576;

  #define GSTAGE_ALL(buf, t) do{ \
    gload16(aSrc[0] + (size_t)(t)*32, (buf) + aDst[0]); \
    gload16(aSrc[1] + (size_t)(t)*32, (buf) + aDst[1]); \
    gload16(aSrc[2] + (size_t)(t)*32, (buf) + aDst[2]); \
    gload16(aSrc[3] + (size_t)(t)*32, (buf) + aDst[3]); \
    gload16(bSrc[0] + (size_t)(t)*32, (buf) + bDst[0]); \
    gload16(bSrc[1] + (size_t)(t)*32, (buf) + bDst[1]); \
  }while(0)

  GSTAGE_ALL(b0, 0);
  GSTAGE_ALL(b1, 1);

  for (int t = 0; t < nt; ++t){
    const size_t k2 = (size_t)(t+2)*32;
    const bool st = (t + 2 < nt);
    if (t < nt-1){
      asm volatile("s_waitcnt vmcnt(6)" ::: "memory");
    } else {
      asm volatile("s_waitcnt vmcnt(0)" ::: "memory");
    }
    __builtin_amdgcn_sched_barrier(0);
    __builtin_amdgcn_s_barrier();
    __builtin_amdgcn_sched_barrier(0);

    // ---- PH0: read A0-3, B0(v),B1(g); stage A0,A1 of t+2; MFMA m0-3 x pair0
    bf16x8 a0 = *(const bf16x8*)(b0 + offA[0]);
    bf16x8 a1 = *(const bf16x8*)(b0 + offA[1]);
    bf16x8 a2 = *(const bf16x8*)(b0 + offA[2]);
    bf16x8 a3 = *(const bf16x8*)(b0 + offA[3]);
    bf16x8 v0 = *(const bf16x8*)(b0 + offB[0]);
    bf16x8 g0 = *(const bf16x8*)(b0 + offB[1]);
    if (st){
      gload16(aSrc[0] + k2, b2 + aDst[0]);
      gload16(aSrc[1] + k2, b2 + aDst[1]);
    }
    __builtin_amdgcn_s_barrier();
    asm volatile("s_waitcnt lgkmcnt(0)" ::: "memory");
    __builtin_amdgcn_sched_barrier(0);
    __builtin_amdgcn_s_setprio(1);
    accv[0][0] = mfma16(a0, v0, accv[0][0]);  accg[0][0] = mfma16(a0, g0, accg[0][0]);
    accv[1][0] = mfma16(a1, v0, accv[1][0]);  accg[1][0] = mfma16(a1, g0, accg[1][0]);
    accv[2][0] = mfma16(a2, v0, accv[2][0]);  accg[2][0] = mfma16(a2, g0, accg[2][0]);
    accv[3][0] = mfma16(a3, v0, accv[3][0]);  accg[3][0] = mfma16(a3, g0, accg[3][0]);
    __builtin_amdgcn_s_setprio(0);
    __builtin_amdgcn_s_barrier();

    // ---- PH1: read A4-7; stage A2,A3; MFMA m4-7 x pair0
    bf16x8 a4 = *(const bf16x8*)(b0 + offA[4]);
    bf16x8 a5 = *(const bf16x8*)(b0 + offA[5]);
    bf16x8 a6 = *(const bf16x8*)(b0 + offA[6]);
    bf16x8 a7 = *(const bf16x8*)(b0 + offA[7]);
    if (st){
      gload16(aSrc[2] + k2, b2 + aDst[2]);
      gload16(aSrc[3] + k2, b2 + aDst[3]);
    }
    __builtin_amdgcn_s_barrier();
    asm volatile("s_waitcnt lgkmcnt(0)" ::: "memory");
    __builtin_amdgcn_sched_barrier(0);
    __builtin_amdgcn_s_setprio(1);
    accv[4][0] = mfma16(a4, v0, accv[4][0]);  accg[4][0] = mfma16(a4, g0, accg[4][0]);
    accv[5][0] = mfma16(a5, v0, accv[5][0]);  accg[5][0] = mfma16(a5, g0, accg[5][0]);
    accv[6][0] = mfma16(a6, v0, accv[6][0]);  accg[6][0] = mfma16(a6, g0, accg[6][0]);
    accv[7][0] = mfma16(a7, v0, accv[7][0]);  accg[7][0] = mfma16(a7, g0, accg[7][0]);
    __builtin_amdgcn_s_setprio(0);
    __builtin_amdgcn_s_barrier();

    // ---- PH2: read B2(v),B3(g); stage B0,B1; MFMA m0-3 x pair1
    bf16x8 v1 = *(const bf16x8*)(b0 + offB[2]);
    bf16x8 g1 = *(const bf16x8*)(b0 + offB[3]);
    if (st){
      gload16(bSrc[0] + k2, b2 + bDst[0]);
      gload16(bSrc[1] + k2, b2 + bDst[1]);
    }
    __builtin_amdgcn_s_barrier();
    asm volatile("s_waitcnt lgkmcnt(0)" ::: "memory");
    __builtin_amdgcn_sched_barrier(0);
    __builtin_amdgcn_s_setprio(1);
    accv[0][1] = mfma16(a0, v1, accv[0][1]);  accg[0][1] = mfma16(a0, g1, accg[0][1]);
    accv[1][1] = mfma16(a1, v1, accv[1][1]);  accg[1][1] = mfma16(a1, g1, accg[1][1]);
    accv[2][1] = mfma16(a2, v1, accv[2][1]);  accg[2][1] = mfma16(a2, g1, accg[2][1]);
    accv[3][1] = mfma16(a3, v1, accv[3][1]);  accg[3][1] = mfma16(a3, g1, accg[3][1]);
    __builtin_amdgcn_s_setprio(0);
    __builtin_amdgcn_s_barrier();

    // ---- PH3: MFMA m4-7 x pair1 (no reads, no stage)
    __builtin_amdgcn_s_setprio(1);
    accv[4][1] = mfma16(a4, v1, accv[4][1]);  accg[4][1] = mfma16(a4, g1, accg[4][1]);
    accv[5][1] = mfma16(a5, v1, accv[5][1]);  accg[5][1] = mfma16(a5, g1, accg[5][1]);
    accv[6][1] = mfma16(a6, v1, accv[6][1]);  accg[6][1] = mfma16(a6, g1, accg[6][1]);
    accv[7][1] = mfma16(a7, v1, accv[7][1]);  accg[7][1] = mfma16(a7, g1, accg[7][1]);
    __builtin_amdgcn_s_setprio(0);

    short* tmp = b0; b0 = b1; b1 = b2; b2 = tmp;
  }
  #undef GSTAGE_ALL

  const int row0 = bm*256 + wm*128;
  #pragma unroll
  for (int m=0;m<8;m++){
    #pragma unroll
    for (int j=0;j<4;j++){
      size_t rb = (size_t)(row0 + m*16 + l4*4 + j)*N + bn*64 + wn*32 + l15;
      #pragma unroll
      for (int p=0;p<2;p++){
        float g = accg[m][p][j];
        float v = accv[m][p][j];
        Cout[rb + p*16] = f2bf(v * g / (1.f + __expf(-g)));
      }
    }
  }
}

// ---------------- Flash attention: swapped-QK, double-buffered KV, counted vmcnt ----------------
__launch_bounds__(256, 3)
__global__ void k_attn(const short* __restrict__ Q, const short* __restrict__ Kb,
                       const short* __restrict__ Vb, short* __restrict__ ctx){
  __shared__ short Kt[2][4096];
  __shared__ short Vt[2][4096];
  const int t = threadIdx.x, wave = t>>6, lane = t&63;
  const int l15 = lane&15, l4 = lane>>4;
  const int qt = blockIdx.x, bh = blockIdx.y;
  const short* Qh  = Q  + (size_t)bh*2048*64;
  const short* Kh  = Kb + (size_t)bh*2048*64;
  const short* Vth = Vb + (size_t)bh*64*2048;

  const int r7  = lane>>3;
  const int swz = ((lane&7) ^ r7) << 3;
  const int rr0 = wave*8 + r7, rr1 = 32 + wave*8 + r7;
  const size_t kOff0 = (size_t)rr0*64   + swz, kOff1 = (size_t)rr1*64   + swz;
  const size_t vOff0 = (size_t)rr0*2048 + swz, vOff1 = (size_t)rr1*2048 + swz;

  bf16x8 qf[2];
  #pragma unroll
  for (int kf=0;kf<2;kf++)
    qf[kf] = *(const bf16x8*)(Qh + (size_t)(qt*64 + wave*16 + l15)*64 + kf*32 + l4*8);

  f32x4 cacc[4] = {};
  float mrun = -1e30f, lrun = 0.f;

  #define STAGE(sel, kv0) do { \
    const short* ksp = Kh + (size_t)(kv0)*64; \
    const short* vsp = Vth + (kv0); \
    short* kd = &Kt[sel][wave*512]; \
    short* vd = &Vt[sel][wave*512]; \
    gload16(ksp + kOff0, kd); \
    gload16(ksp + kOff1, kd + 2048); \
    gload16(vsp + vOff0, vd); \
    gload16(vsp + vOff1, vd + 2048); \
  } while(0)

  STAGE(0, 0);

  for (int tt = 0; tt < 32; ++tt){
    const int cur = tt & 1;
    if (tt < 31){
      STAGE(cur^1, (tt+1)*64);
      asm volatile("s_waitcnt vmcnt(4)" ::: "memory");
    } else {
      asm volatile("s_waitcnt vmcnt(0)" ::: "memory");
    }
    __builtin_amdgcn_sched_barrier(0);
    __builtin_amdgcn_s_barrier();
    __builtin_amdgcn_sched_barrier(0);

    const short* KtC = &Kt[cur][0];
    const short* VtC = &Vt[cur][0];

    f32x4 sacc[4] = {};
    __builtin_amdgcn_s_setprio(1);
    #pragma unroll
    for (int kf=0;kf<2;kf++){
      #pragma unroll
      for (int mk=0;mk<4;mk++){
        int r = mk*16 + l15;
        bf16x8 kfr = *(const bf16x8*)(KtC + r*64 + (((kf*4+l4) ^ (l15&7))<<3));
        sacc[mk] = mfma16(kfr, qf[kf], sacc[mk]);
      }
    }
    __builtin_amdgcn_s_setprio(0);

    float mx = sacc[0][0];
    #pragma unroll
    for (int mk=0;mk<4;mk++)
      #pragma unroll
      for (int j=0;j<4;j++) mx = fmaxf(mx, sacc[mk][j]);
    mx = fmaxf(mx, __shfl_xor(mx, 16));
    mx = fmaxf(mx, __shfl_xor(mx, 32));
    if (!__all(mx - mrun <= 8.f)){
      float mnew = fmaxf(mrun, mx);
      float fac = __expf(mrun - mnew);
      mrun = mnew;
      lrun *= fac;
      #pragma unroll
      for (int j=0;j<4;j++){
        float fj = __shfl(fac, l4*4 + j);
        #pragma unroll
        for (int nf=0;nf<4;nf++) cacc[nf][j] *= fj;
      }
    }
    float psum = 0.f;
    #pragma unroll
    for (int mk=0;mk<4;mk++)
      #pragma unroll
      for (int j=0;j<4;j++){
        float pv = __expf(sacc[mk][j] - mrun);
        sacc[mk][j] = pv; psum += pv;
      }
    psum += __shfl_xor(psum, 16);
    psum += __shfl_xor(psum, 32);
    lrun += psum;

    int pk01[4], pk23[4];
    #pragma unroll
    for (int mk=0;mk<4;mk++){
      pk01[mk] = cvtpk(sacc[mk][0], sacc[mk][1]);
      pk23[mk] = cvtpk(sacc[mk][2], sacc[mk][3]);
    }

    #pragma unroll
    for (int ks=0;ks<2;ks++){
      int srcA = l15 + ((l4&1)<<5);
      int srcB = srcA + 16;
      int hi = l4>>1;
      int w0a = __shfl(pk01[2*ks], srcA), w0b = __shfl(pk01[2*ks+1], srcA);
      int w1a = __shfl(pk23[2*ks], srcA), w1b = __shfl(pk23[2*ks+1], srcA);
      int w2a = __shfl(pk01[2*ks], srcB), w2b = __shfl(pk01[2*ks+1], srcB);
      int w3a = __shfl(pk23[2*ks], srcB), w3b = __shfl(pk23[2*ks+1], srcB);
      union { int w[4]; bf16x8 v; } pa;
      pa.w[0] = hi ? w0b : w0a;
      pa.w[1] = hi ? w1b : w1a;
      pa.w[2] = hi ? w2b : w2a;
      pa.w[3] = hi ? w3b : w3a;
      __builtin_amdgcn_s_setprio(1);
      #pragma unroll
      for (int nf=0;nf<4;nf++){
        int dh = nf*16 + l15;
        bf16x8 vf = *(const bf16x8*)(VtC + dh*64 + (((ks*4+l4) ^ (dh&7))<<3));
        cacc[nf] = mfma16(pa.v, vf, cacc[nf]);
      }
      __builtin_amdgcn_s_setprio(0);
    }

    __builtin_amdgcn_sched_barrier(0);
    __builtin_amdgcn_s_barrier();
  }
  #undef STAGE

  const int b = bh/12, h = bh%12;
  #pragma unroll
  for (int j=0;j<4;j++){
    float inv = 1.f / __shfl(lrun, l4*4 + j);
    int s = qt*64 + wave*16 + l4*4 + j;
    size_t base = ((size_t)b*2048 + s)*768 + h*64;
    #pragma unroll
    for (int nf=0;nf<4;nf++)
      ctx[base + nf*16 + l15] = f2bf(cacc[nf][j] * inv);
  }
}

extern "C" void kernel_launch(void* const* d_in, const int* in_sizes, int n_in,
                              void* d_out, int out_size, void* d_ws, size_t ws_size,
                              hipStream_t stream){
  (void)in_sizes; (void)n_in; (void)out_size;
  const float* src   = (const float*)d_in[0];
  const float* wq    = (const float*)d_in[1];
  const float* bq    = (const float*)d_in[2];
  const float* wk    = (const float*)d_in[3];
  const float* bk    = (const float*)d_in[4];
  const float* wv    = (const float*)d_in[5];
  const float* bv    = (const float*)d_in[6];
  const float* wo    = (const float*)d_in[7];
  const float* bo    = (const float*)d_in[8];
  const float* wfc1  = (const float*)d_in[9];
  const float* bfc1  = (const float*)d_in[10];
  const float* win   = (const float*)d_in[11];
  const float* wgate = (const float*)d_in[12];
  const float* wfc2  = (const float*)d_in[13];
  const float* bfc2  = (const float*)d_in[14];
  const float* gattn = (const float*)d_in[15];
  const float* gffn  = (const float*)d_in[16];

  char* ws = (char*)d_ws;
  constexpr size_t SZ_W768  = 768ull*768*2;
  constexpr size_t SZ_WFC   = 3072ull*768*2;
  constexpr size_t SZ_WFF   = 3072ull*3072*2;
  constexpr size_t SZ_ACT   = 4096ull*768*2;
  constexpr size_t SZ_ACTF  = 4096ull*768*4;
  constexpr size_t SZ_H     = 4096ull*3072*2;
  constexpr size_t OFF_WQ    = 0;
  constexpr size_t OFF_WK    = OFF_WQ + SZ_W768;
  constexpr size_t OFF_WV    = OFF_WK + SZ_W768;
  constexpr size_t OFF_WO    = OFF_WV + SZ_W768;
  constexpr size_t OFF_WFC1  = OFF_WO + SZ_W768;
  constexpr size_t OFF_WIN   = OFF_WFC1 + SZ_WFC;
  constexpr size_t OFF_WGATE = OFF_WIN + SZ_WFF;
  constexpr size_t OFF_WFC2  = OFF_WGATE + SZ_WFF;
  constexpr size_t OFF_XN    = OFF_WFC2 + SZ_WFC;
  constexpr size_t OFF_Q     = OFF_XN + SZ_ACT;
  constexpr size_t OFF_K     = OFF_Q + SZ_ACT;
  constexpr size_t OFF_V     = OFF_K + SZ_ACT;
  constexpr size_t OFF_RES   = OFF_V + SZ_ACT;
  constexpr size_t OFF_HIN   = OFF_RES + SZ_ACTF;
  constexpr size_t OFF_H2    = OFF_HIN + SZ_H;
  constexpr size_t WS_NEED   = OFF_H2 + SZ_H;
  if (ws_size < WS_NEED) return;

  short* wq_b    = (short*)(ws+OFF_WQ);
  short* wfc1_b  = (short*)(ws+OFF_WFC1);
  short* win_b   = (short*)(ws+OFF_WIN);
  short* wgate_b = (short*)(ws+OFF_WGATE);
  short* wfc2_b  = (short*)(ws+OFF_WFC2);
  short* wo_b    = (short*)(ws+OFF_WO);
  short* xn      = (short*)(ws+OFF_XN);
  short* ctxb    = (short*)(ws+OFF_XN);
  short* qb      = (short*)(ws+OFF_Q);
  short* yb      = (short*)(ws+OFF_Q);
  short* kb2     = (short*)(ws+OFF_K);
  short* vb2     = (short*)(ws+OFF_V);
  float* resid   = (float*)(ws+OFF_RES);
  short* h1      = (short*)(ws+OFF_K);
  short* h2      = (short*)(ws+OFF_H2);

  k_convert8<<<25344, 256, 0, stream>>>(wq, wk, wv, wo, wfc1, win, wgate, wfc2, wq_b);

  k_rmsnorm<<<1024, 256, 0, stream>>>(src, gattn, xn);

  k_gemm<EPI_QKV><<<dim3(18,32), 256, 0, stream>>>(xn, wq_b, qb, bq, kb2, bk, bv, vb2, 4096, 2304, 768);

  k_attn<<<dim3(32, 24), 256, 0, stream>>>(qb, kb2, vb2, ctxb);

  k_gemm<EPI_RESID><<<dim3(6,32), 256, 0, stream>>>(ctxb, wo_b, resid, bo, src, nullptr, nullptr, nullptr, 4096, 768, 768);
  k_rmsnorm<<<1024, 256, 0, stream>>>(resid, gffn, yb);

  k_ff<EPI_BF16><<<dim3(8,32), 512, 0, stream>>>(yb, wfc1_b, h1, bfc1, nullptr, 3072, 768);

  // fused SwiGLU, 4-phase pipelined: h2 = (h1@win^T) * silu(h1@wgate^T)
  k_ffglu<<<dim3(48,16), 256, 0, stream>>>(h1, win_b, wgate_b, h2);

  k_gemm<EPI_FINAL><<<dim3(6,32), 256, 0, stream>>>(h2, wfc2_b, d_out, bfc2, yb, nullptr, nullptr, nullptr, 4096, 768, 3072);
}

// Round 7
// 349.356 us; speedup vs baseline: 1.6235x; 1.0591x over previous
//
#include <hip/hip_runtime.h>

#define DEV static __device__ __forceinline__

typedef __attribute__((ext_vector_type(8))) short bf16x8;
typedef __attribute__((ext_vector_type(4))) short short4v;
typedef __attribute__((ext_vector_type(4))) float f32x4;

DEV f32x4 mfma16(bf16x8 a, bf16x8 b, f32x4 c){
  return __builtin_amdgcn_mfma_f32_16x16x32_bf16(a, b, c, 0, 0, 0);
}
DEV float bf2f(short s){ union{unsigned u; float f;} v; v.u=((unsigned)(unsigned short)s)<<16; return v.f; }
DEV short f2bf(float f){ union{float f; unsigned u;} v; v.f=f; unsigned r=v.u+0x7fffu+((v.u>>16)&1u); return (short)(r>>16); }
DEV void gload16(const void* g, void* l){
  __builtin_amdgcn_global_load_lds((const __attribute__((address_space(1))) void*)g,
                                   (__attribute__((address_space(3))) void*)l, 16, 0, 0);
}
DEV int cvtpk(float lo, float hi){
  int r; asm("v_cvt_pk_bf16_f32 %0, %1, %2" : "=v"(r) : "v"(lo), "v"(hi)); return r;
}

enum { EPI_BF16=0, EPI_SWIGLU=1, EPI_RESID=2, EPI_QKV=4 };

// ---------------- fused weight convert f32 -> bf16 ----------------
__global__ void k_convert8(const float* __restrict__ p0, const float* __restrict__ p1,
                           const float* __restrict__ p2, const float* __restrict__ p3,
                           const float* __restrict__ p4, const float* __restrict__ p5,
                           const float* __restrict__ p6, const float* __restrict__ p7,
                           short* __restrict__ dst){
  int v = blockIdx.x * 256 + threadIdx.x;
  const float* src; int rel;
  if      (v <  147456){ src=p0; rel=v; }
  else if (v <  294912){ src=p1; rel=v-147456; }
  else if (v <  442368){ src=p2; rel=v-294912; }
  else if (v <  589824){ src=p3; rel=v-442368; }
  else if (v < 1179648){ src=p4; rel=v-589824; }
  else if (v < 3538944){ src=p5; rel=v-1179648; }
  else if (v < 5898240){ src=p6; rel=v-3538944; }
  else                 { src=p7; rel=v-5898240; }
  float4 x = ((const float4*)src)[rel];
  short4v o; o.x=f2bf(x.x); o.y=f2bf(x.y); o.z=f2bf(x.z); o.w=f2bf(x.w);
  ((short4v*)dst)[v] = o;
}

// ---------------- RMSNorm over 768 f32 -> bf16 (1 wave / row) ----------------
__global__ void k_rmsnorm(const float* __restrict__ x, const float* __restrict__ g,
                          short* __restrict__ out){
  int row = blockIdx.x*4 + (threadIdx.x>>6);
  int lane = threadIdx.x & 63;
  const float* xr = x + (size_t)row*768;
  float4 v[3];
  float ss = 0.f;
  #pragma unroll
  for (int i=0;i<3;i++){
    v[i] = *(const float4*)(xr + i*256 + lane*4);
    ss += v[i].x*v[i].x + v[i].y*v[i].y + v[i].z*v[i].z + v[i].w*v[i].w;
  }
  #pragma unroll
  for (int d=32; d>0; d>>=1) ss += __shfl_xor(ss, d);
  float sc = rsqrtf(ss*(1.f/768.f) + 1.1920929e-7f);
  #pragma unroll
  for (int i=0;i<3;i++){
    int c0 = i*256 + lane*4;
    float4 gv = *(const float4*)(g + c0);
    short4v o;
    o.x = f2bf(v[i].x*sc*gv.x); o.y = f2bf(v[i].y*sc*gv.y);
    o.z = f2bf(v[i].z*sc*gv.z); o.w = f2bf(v[i].w*sc*gv.w);
    *(short4v*)(out + (size_t)row*768 + c0) = o;
  }
}

// ---------------- NT GEMM (m97 128x128): QKV (N=2304), Wo ----------------
template<int EPI>
__launch_bounds__(256, 2)
__global__ void k_gemm(const short* __restrict__ Aptr, const short* __restrict__ Bptr,
                       void* __restrict__ Cout, const float* __restrict__ bias,
                       const void* __restrict__ aux, const float* __restrict__ bias2,
                       const float* __restrict__ bias3, const void* __restrict__ aux2,
                       int M, int N, int K){
  __shared__ short ldsA[128*32];
  __shared__ short ldsB[128*32];
  const int t = threadIdx.x;
  const int wave = t >> 6, lane = t & 63;
  const int l15 = lane & 15, l4 = lane >> 4;
  const int nwg = gridDim.x * gridDim.y;
  const int bid0 = blockIdx.y * gridDim.x + blockIdx.x;
  const int cpx = nwg >> 3;
  const int bid = (bid0 & 7) * cpx + (bid0 >> 3);
  const int bm = bid / gridDim.x, bn = bid % gridDim.x;
  const int wr = wave >> 1, wc = wave & 1;

  f32x4 acc[4][4] = {};

  const short* Ag = Aptr + (size_t)(bm*128 + wave*32 + (lane>>2))*K + (lane&3)*8;
  const short* Bg = Bptr + (size_t)(bn*128 + wave*32 + (lane>>2))*K + (lane&3)*8;
  short* lA = ldsA + wave*1024;
  short* lB = ldsB + wave*1024;

  for (int k0 = 0; k0 < K; k0 += 32){
    __syncthreads();
    gload16(Ag + k0,                lA);
    gload16(Ag + k0 + 16*(size_t)K, lA + 512);
    gload16(Bg + k0,                lB);
    gload16(Bg + k0 + 16*(size_t)K, lB + 512);
    __syncthreads();
    bf16x8 af[4], bfr[4];
    #pragma unroll
    for (int m=0;m<4;m++) af[m]  = *(const bf16x8*)(ldsA + (wr*64 + m*16 + l15)*32 + l4*8);
    #pragma unroll
    for (int n=0;n<4;n++) bfr[n] = *(const bf16x8*)(ldsB + (wc*64 + n*16 + l15)*32 + l4*8);
    #pragma unroll
    for (int m=0;m<4;m++)
      #pragma unroll
      for (int n=0;n<4;n++)
        acc[m][n] = mfma16(af[m], bfr[n], acc[m][n]);
  }

  const int row0 = bm*128 + wr*64;
  const int col0 = bn*128 + wc*64;

  if constexpr (EPI == EPI_RESID){
    float* C = (float*)Cout;
    const float* srcf = (const float*)aux;
    float bvv[4];
    #pragma unroll
    for (int n=0;n<4;n++) bvv[n] = bias[col0 + n*16 + l15];
    #pragma unroll
    for (int m=0;m<4;m++)
      #pragma unroll
      for (int j=0;j<4;j++){
        size_t rb = (size_t)(row0 + m*16 + l4*4 + j)*N + col0 + l15;
        #pragma unroll
        for (int n=0;n<4;n++) C[rb + n*16] = acc[m][n][j] + bvv[n] + srcf[rb + n*16];
      }
  } else if constexpr (EPI == EPI_QKV){
    const int proj = col0 / 768;
    const int c768 = col0 - proj*768;
    const int h = c768 >> 6;
    const float* bs = proj==0 ? bias : (proj==1 ? bias2 : bias3);
    float bvv[4];
    #pragma unroll
    for (int n=0;n<4;n++) bvv[n] = bs[c768 + n*16 + l15];
    if (proj == 2){
      short* Ov = (short*)const_cast<void*>(aux2);
      #pragma unroll
      for (int m=0;m<4;m++){
        #pragma unroll
        for (int j=0;j<4;j++){
          int row = row0 + m*16 + l4*4 + j;
          int b = row >> 11, s = row & 2047;
          size_t hb = (size_t)(b*12 + h)*64;
          #pragma unroll
          for (int n=0;n<4;n++)
            Ov[(hb + n*16 + l15)*2048 + s] = f2bf(acc[m][n][j] + bvv[n]);
        }
      }
    } else {
      short* O = proj==0 ? (short*)Cout : (short*)const_cast<void*>(aux);
      const float sc = proj==0 ? 0.125f : 1.0f;
      const float RC = 0.41524101186092034f;  // log2(10000)/32
      float invf0 = exp2f(-(float)l15 * RC);
      float invf1 = exp2f(-(float)(16 + l15) * RC);
      #pragma unroll
      for (int m=0;m<4;m++){
        #pragma unroll
        for (int j=0;j<4;j++){
          int row = row0 + m*16 + l4*4 + j;
          int b = row >> 11, s = row & 2047;
          size_t obase = ((size_t)(b*12 + h)*2048 + (size_t)s)*64;
          float a0 = acc[m][0][j] + bvv[0];
          float a1 = acc[m][1][j] + bvv[1];
          float a2 = acc[m][2][j] + bvv[2];
          float a3 = acc[m][3][j] + bvv[3];
          float sn0, cs0, sn1, cs1;
          __sincosf((float)s * invf0, &sn0, &cs0);
          __sincosf((float)s * invf1, &sn1, &cs1);
          O[obase + l15]      = f2bf((a0*cs0 - a2*sn0)*sc);
          O[obase + 16 + l15] = f2bf((a1*cs1 - a3*sn1)*sc);
          O[obase + 32 + l15] = f2bf((a2*cs0 + a0*sn0)*sc);
          O[obase + 48 + l15] = f2bf((a3*cs1 + a1*sn1)*sc);
        }
      }
    }
  }
}

// ---------------- fc2 split-K partial GEMM: P[z] = h2[:, z*768:(z+1)*768] @ wfc2_slice^T ----------------
// grid (6, 32, 4). m97 structure, K-slice = 768.
__launch_bounds__(256, 2)
__global__ void k_part(const short* __restrict__ Aptr, const short* __restrict__ Bptr,
                       float* __restrict__ Pa, float* __restrict__ Pb){
  __shared__ short ldsA[128*32];
  __shared__ short ldsB[128*32];
  const int t = threadIdx.x;
  const int wave = t >> 6, lane = t & 63;
  const int l15 = lane & 15, l4 = lane >> 4;
  const int K = 3072;
  const int z = blockIdx.z;
  const int koff = z * 768;
  const int bid0 = blockIdx.y * 6 + blockIdx.x;     // 0..191
  const int bid = (bid0 & 7) * 24 + (bid0 >> 3);
  const int bm = bid / 6, bn = bid % 6;
  const int wr = wave >> 1, wc = wave & 1;

  f32x4 acc[4][4] = {};

  const short* Ag = Aptr + (size_t)(bm*128 + wave*32 + (lane>>2))*K + (lane&3)*8 + koff;
  const short* Bg = Bptr + (size_t)(bn*128 + wave*32 + (lane>>2))*K + (lane&3)*8 + koff;
  short* lA = ldsA + wave*1024;
  short* lB = ldsB + wave*1024;

  for (int k0 = 0; k0 < 768; k0 += 32){
    __syncthreads();
    gload16(Ag + k0,                lA);
    gload16(Ag + k0 + 16*(size_t)K, lA + 512);
    gload16(Bg + k0,                lB);
    gload16(Bg + k0 + 16*(size_t)K, lB + 512);
    __syncthreads();
    bf16x8 af[4], bfr[4];
    #pragma unroll
    for (int m=0;m<4;m++) af[m]  = *(const bf16x8*)(ldsA + (wr*64 + m*16 + l15)*32 + l4*8);
    #pragma unroll
    for (int n=0;n<4;n++) bfr[n] = *(const bf16x8*)(ldsB + (wc*64 + n*16 + l15)*32 + l4*8);
    #pragma unroll
    for (int m=0;m<4;m++)
      #pragma unroll
      for (int n=0;n<4;n++)
        acc[m][n] = mfma16(af[m], bfr[n], acc[m][n]);
  }

  float* P = (z < 2) ? (Pa + (size_t)z*3145728) : (Pb + (size_t)(z-2)*3145728);
  const int row0 = bm*128 + wr*64;
  const int col0 = bn*128 + wc*64;
  #pragma unroll
  for (int m=0;m<4;m++)
    #pragma unroll
    for (int j=0;j<4;j++){
      size_t rb = (size_t)(row0 + m*16 + l4*4 + j)*768 + col0 + l15;
      #pragma unroll
      for (int n=0;n<4;n++) P[rb + n*16] = acc[m][n][j];
    }
}

// ---------------- fc2 reduce: out = p0+p1+p2+p3 + bias + y ----------------
__global__ void k_fc2red(const float* __restrict__ Pa, const float* __restrict__ Pb,
                         const float* __restrict__ bias, const short* __restrict__ yv,
                         float* __restrict__ out){
  int i = blockIdx.x * 256 + threadIdx.x;     // float4 index, 786432 total
  float4 a = ((const float4*)Pa)[i];
  float4 b = ((const float4*)(Pa + 3145728))[i];
  float4 c = ((const float4*)Pb)[i];
  float4 d = ((const float4*)(Pb + 3145728))[i];
  float4 bv = *(const float4*)(bias + (i % 192)*4);
  short4v y = ((const short4v*)yv)[i];
  float4 o;
  o.x = a.x + b.x + c.x + d.x + bv.x + bf2f(y.x);
  o.y = a.y + b.y + c.y + d.y + bv.y + bf2f(y.y);
  o.z = a.z + b.z + c.z + d.z + bv.z + bf2f(y.z);
  o.w = a.w + b.w + c.w + d.w + bv.w + bf2f(y.w);
  ((float4*)out)[i] = o;
}

// ---------------- Pipelined NT GEMM, 128x384 (fc1) ----------------
template<int EPI>
__launch_bounds__(512, 2)
__global__ void k_ff(const short* __restrict__ Aptr, const short* __restrict__ Bptr,
                     short* __restrict__ Cout, const float* __restrict__ bias,
                     const short* __restrict__ hinp, int N, int K){
  __shared__ short lds[3*16384];
  const int tid = threadIdx.x;
  const int wave = tid >> 6, lane = tid & 63;
  const int l15 = lane & 15, l4 = lane >> 4;
  const int wm = wave >> 2, wn = wave & 3;

  const int nwg = gridDim.x * gridDim.y;
  const int bid0 = blockIdx.y * gridDim.x + blockIdx.x;
  const int cpx = nwg >> 3;
  const int bid = (bid0 & 7) * cpx + (bid0 >> 3);
  const int bm = bid / gridDim.x, bn = bid % gridDim.x;

  const int chA = wave*64 + lane;
  const int rowA = chA >> 2;
  const int cA = (chA & 3) ^ ((rowA >> 1) & 3);
  const size_t aOff = (size_t)(bm*128 + rowA)*K + cA*8;
  const int chB0 = wave*64 + lane, chB1 = 512 + chB0, chB2 = 1024 + chB0;
  const int rB0 = chB0>>2, rB1 = chB1>>2, rB2 = chB2>>2;
  const size_t bOff0 = (size_t)(bn*384 + rB0)*K + (((chB0&3) ^ ((rB0>>1)&3))*8);
  const size_t bOff1 = (size_t)(bn*384 + rB1)*K + (((chB1&3) ^ ((rB1>>1)&3))*8);
  const size_t bOff2 = (size_t)(bn*384 + rB2)*K + (((chB2&3) ^ ((rB2>>1)&3))*8);
  const int stA = wave*512;

  int offA[4], offB[6];
  #pragma unroll
  for (int m=0;m<4;m++){
    int r = wm*64 + m*16 + l15;
    offA[m] = r*32 + ((l4 ^ ((r>>1)&3))<<3);
  }
  #pragma unroll
  for (int n=0;n<6;n++){
    int r = wn*96 + n*16 + l15;
    offB[n] = 4096 + r*32 + ((l4 ^ ((r>>1)&3))<<3);
  }

  short *p0 = lds, *p1 = lds + 16384, *p2 = lds + 32768;
  f32x4 acc[4][6] = {};
  const int nt = K >> 5;

  #define FFSTAGE(buf, t) do{ \
    gload16(Aptr + aOff  + (size_t)(t)*32, (buf) + stA); \
    gload16(Bptr + bOff0 + (size_t)(t)*32, (buf) + 4096  + stA); \
    gload16(Bptr + bOff1 + (size_t)(t)*32, (buf) + 8192  + stA); \
    gload16(Bptr + bOff2 + (size_t)(t)*32, (buf) + 12288 + stA); \
  }while(0)

  FFSTAGE(p0, 0);
  FFSTAGE(p1, 1);

  for (int t = 0; t < nt; ++t){
    if (t + 2 < nt){
      FFSTAGE(p2, t+2);
      asm volatile("s_waitcnt vmcnt(8)" ::: "memory");
    } else if (t + 1 < nt){
      asm volatile("s_waitcnt vmcnt(4)" ::: "memory");
    } else {
      asm volatile("s_waitcnt vmcnt(0)" ::: "memory");
    }
    __builtin_amdgcn_sched_barrier(0);
    __builtin_amdgcn_s_barrier();
    __builtin_amdgcn_sched_barrier(0);

    bf16x8 bfr[6], afr[4];
    #pragma unroll
    for (int n=0;n<6;n++) bfr[n] = *(const bf16x8*)(p0 + offB[n]);
    #pragma unroll
    for (int m=0;m<4;m++) afr[m] = *(const bf16x8*)(p0 + offA[m]);
    __builtin_amdgcn_s_setprio(1);
    #pragma unroll
    for (int m=0;m<4;m++)
      #pragma unroll
      for (int n=0;n<6;n++)
        acc[m][n] = mfma16(afr[m], bfr[n], acc[m][n]);
    __builtin_amdgcn_s_setprio(0);

    __builtin_amdgcn_sched_barrier(0);
    __builtin_amdgcn_s_barrier();
    short* tmp = p0; p0 = p1; p1 = p2; p2 = tmp;
  }
  #undef FFSTAGE

  const int row0 = bm*128 + wm*64;
  const int col0 = bn*384 + wn*96;

  if constexpr (EPI == EPI_BF16){
    float bvv[6];
    #pragma unroll
    for (int n=0;n<6;n++) bvv[n] = bias ? bias[col0 + n*16 + l15] : 0.f;
    #pragma unroll
    for (int m=0;m<4;m++)
      #pragma unroll
      for (int j=0;j<4;j++){
        size_t rb = (size_t)(row0 + m*16 + l4*4 + j)*N + col0 + l15;
        #pragma unroll
        for (int n=0;n<6;n++) Cout[rb + n*16] = f2bf(acc[m][n][j] + bvv[n]);
      }
  } else {
    #pragma unroll
    for (int m=0;m<4;m++)
      #pragma unroll
      for (int j=0;j<4;j++){
        size_t rb = (size_t)(row0 + m*16 + l4*4 + j)*N + col0 + l15;
        #pragma unroll
        for (int n=0;n<6;n++){
          float gt = acc[m][n][j];
          Cout[rb + n*16] = f2bf(bf2f(hinp[rb + n*16]) * gt / (1.f + __expf(-gt)));
        }
      }
  }
}

// ---------------- Fused SwiGLU GEMM, 2-phase pipelined ----------------
// BM=256, BN=64(v)+64(g) interleaved. 4 waves (wm=wave>>1, wn=wave&1), wave = 128x64.
// BK=32, triple-buffered (72KB -> 2 blocks/CU), counted vmcnt(6), 2 phases / 4 barriers per tile.
// XCD rectangle swizzle: each XCD gets 8bm x 12bn.
__launch_bounds__(256, 2)
__global__ void k_ffglu(const short* __restrict__ Aptr, const short* __restrict__ Wv,
                        const short* __restrict__ Wg, short* __restrict__ Cout){
  __shared__ short lds[3*12288];
  const int tid = threadIdx.x;
  const int wave = tid >> 6, lane = tid & 63;
  const int l15 = lane & 15, l4 = lane >> 4;
  const int wm = wave >> 1, wn = wave & 1;
  const int K = 3072, N = 3072;
  const int nt = 96;

  // grid (48,16). XCD rectangle: 8bm x 12bn per XCD.
  const int lin = blockIdx.y * 48 + blockIdx.x;
  const int xcd = lin & 7, idx = lin >> 3;       // idx 0..95
  const int bm = ((xcd & 1) << 3) + idx / 12;    // 0..15
  const int bn = (xcd >> 1) * 12 + idx % 12;     // 0..47

  const int srcC = ((lane & 3) ^ ((lane >> 3) & 3)) * 8;

  const short* aSrc[4];
  int aDst[4];
  #pragma unroll
  for (int i=0;i<4;i++){
    int s = i*4 + wave;
    int row = s*16 + (lane>>2);
    aSrc[i] = Aptr + (size_t)(bm*256 + row)*K + srcC;
    aDst[i] = s*512;
  }
  const short* bSrc[2];
  int bDst[2];
  #pragma unroll
  for (int i=0;i<2;i++){
    int j = i*4 + wave;
    int pidx = (j>>1)*16 + (lane>>2);
    const short* W = (j & 1) ? Wg : Wv;
    bSrc[i] = W + (size_t)(bn*64 + pidx)*K + srcC;
    bDst[i] = 8192 + j*512;
  }

  int offA[8], offB[4];
  #pragma unroll
  for (int m=0;m<8;m++){
    int r = wm*128 + m*16 + l15;
    offA[m] = r*32 + ((l4 ^ ((l15>>1)&3))<<3);
  }
  #pragma unroll
  for (int nf=0;nf<4;nf++){
    int r = wn*64 + nf*16 + l15;
    offB[nf] = 8192 + r*32 + ((l4 ^ ((l15>>1)&3))<<3);
  }

  f32x4 accv[8][2] = {};
  f32x4 accg[8][2] = {};

  short *b0 = lds, *b1 = lds + 12288, *b2 = lds + 24576;

  #define GSTAGE_ALL(buf, t) do{ \
    gload16(aSrc[0] + (size_t)(t)*32, (buf) + aDst[0]); \
    gload16(aSrc[1] + (size_t)(t)*32, (buf) + aDst[1]); \
    gload16(aSrc[2] + (size_t)(t)*32, (buf) + aDst[2]); \
    gload16(aSrc[3] + (size_t)(t)*32, (buf) + aDst[3]); \
    gload16(bSrc[0] + (size_t)(t)*32, (buf) + bDst[0]); \
    gload16(bSrc[1] + (size_t)(t)*32, (buf) + bDst[1]); \
  }while(0)

  GSTAGE_ALL(b0, 0);
  GSTAGE_ALL(b1, 1);

  for (int t = 0; t < nt; ++t){
    const size_t k2 = (size_t)(t+2)*32;
    const bool st = (t + 2 < nt);
    if (t < nt-1){
      asm volatile("s_waitcnt vmcnt(6)" ::: "memory");
    } else {
      asm volatile("s_waitcnt vmcnt(0)" ::: "memory");
    }
    __builtin_amdgcn_sched_barrier(0);
    __builtin_amdgcn_s_barrier();
    __builtin_amdgcn_sched_barrier(0);

    // ---- P0: read A0-3 + all 4 B frags; stage A0,A1,B0; MFMA m0-3 x both pairs (16)
    bf16x8 a0 = *(const bf16x8*)(b0 + offA[0]);
    bf16x8 a1 = *(const bf16x8*)(b0 + offA[1]);
    bf16x8 a2 = *(const bf16x8*)(b0 + offA[2]);
    bf16x8 a3 = *(const bf16x8*)(b0 + offA[3]);
    bf16x8 v0 = *(const bf16x8*)(b0 + offB[0]);
    bf16x8 g0 = *(const bf16x8*)(b0 + offB[1]);
    bf16x8 v1 = *(const bf16x8*)(b0 + offB[2]);
    bf16x8 g1 = *(const bf16x8*)(b0 + offB[3]);
    if (st){
      gload16(aSrc[0] + k2, b2 + aDst[0]);
      gload16(aSrc[1] + k2, b2 + aDst[1]);
      gload16(bSrc[0] + k2, b2 + bDst[0]);
    }
    __builtin_amdgcn_s_barrier();
    asm volatile("s_waitcnt lgkmcnt(0)" ::: "memory");
    __builtin_amdgcn_sched_barrier(0);
    __builtin_amdgcn_s_setprio(1);
    accv[0][0] = mfma16(a0, v0, accv[0][0]);  accg[0][0] = mfma16(a0, g0, accg[0][0]);
    accv[1][0] = mfma16(a1, v0, accv[1][0]);  accg[1][0] = mfma16(a1, g0, accg[1][0]);
    accv[2][0] = mfma16(a2, v0, accv[2][0]);  accg[2][0] = mfma16(a2, g0, accg[2][0]);
    accv[3][0] = mfma16(a3, v0, accv[3][0]);  accg[3][0] = mfma16(a3, g0, accg[3][0]);
    accv[0][1] = mfma16(a0, v1, accv[0][1]);  accg[0][1] = mfma16(a0, g1, accg[0][1]);
    accv[1][1] = mfma16(a1, v1, accv[1][1]);  accg[1][1] = mfma16(a1, g1, accg[1][1]);
    accv[2][1] = mfma16(a2, v1, accv[2][1]);  accg[2][1] = mfma16(a2, g1, accg[2][1]);
    accv[3][1] = mfma16(a3, v1, accv[3][1]);  accg[3][1] = mfma16(a3, g1, accg[3][1]);
    __builtin_amdgcn_s_setprio(0);
    __builtin_amdgcn_s_barrier();

    // ---- P1: read A4-7; stage A2,A3,B1; MFMA m4-7 x both pairs (16)
    bf16x8 a4 = *(const bf16x8*)(b0 + offA[4]);
    bf16x8 a5 = *(const bf16x8*)(b0 + offA[5]);
    bf16x8 a6 = *(const bf16x8*)(b0 + offA[6]);
    bf16x8 a7 = *(const bf16x8*)(b0 + offA[7]);
    if (st){
      gload16(aSrc[2] + k2, b2 + aDst[2]);
      gload16(aSrc[3] + k2, b2 + aDst[3]);
      gload16(bSrc[1] + k2, b2 + bDst[1]);
    }
    __builtin_amdgcn_s_barrier();
    asm volatile("s_waitcnt lgkmcnt(0)" ::: "memory");
    __builtin_amdgcn_sched_barrier(0);
    __builtin_amdgcn_s_setprio(1);
    accv[4][0] = mfma16(a4, v0, accv[4][0]);  accg[4][0] = mfma16(a4, g0, accg[4][0]);
    accv[5][0] = mfma16(a5, v0, accv[5][0]);  accg[5][0] = mfma16(a5, g0, accg[5][0]);
    accv[6][0] = mfma16(a6, v0, accv[6][0]);  accg[6][0] = mfma16(a6, g0, accg[6][0]);
    accv[7][0] = mfma16(a7, v0, accv[7][0]);  accg[7][0] = mfma16(a7, g0, accg[7][0]);
    accv[4][1] = mfma16(a4, v1, accv[4][1]);  accg[4][1] = mfma16(a4, g1, accg[4][1]);
    accv[5][1] = mfma16(a5, v1, accv[5][1]);  accg[5][1] = mfma16(a5, g1, accg[5][1]);
    accv[6][1] = mfma16(a6, v1, accv[6][1]);  accg[6][1] = mfma16(a6, g1, accg[6][1]);
    accv[7][1] = mfma16(a7, v1, accv[7][1]);  accg[7][1] = mfma16(a7, g1, accg[7][1]);
    __builtin_amdgcn_s_setprio(0);

    short* tmp = b0; b0 = b1; b1 = b2; b2 = tmp;
  }
  #undef GSTAGE_ALL

  const int row0 = bm*256 + wm*128;
  #pragma unroll
  for (int m=0;m<8;m++){
    #pragma unroll
    for (int j=0;j<4;j++){
      size_t rb = (size_t)(row0 + m*16 + l4*4 + j)*N + bn*64 + wn*32 + l15;
      #pragma unroll
      for (int p=0;p<2;p++){
        float g = accg[m][p][j];
        float v = accv[m][p][j];
        Cout[rb + p*16] = f2bf(v * g / (1.f + __expf(-g)));
      }
    }
  }
}

// ---------------- Flash attention: swapped-QK, double-buffered KV, counted vmcnt ----------------
__launch_bounds__(256, 3)
__global__ void k_attn(const short* __restrict__ Q, const short* __restrict__ Kb,
                       const short* __restrict__ Vb, short* __restrict__ ctx){
  __shared__ short Kt[2][4096];
  __shared__ short Vt[2][4096];
  const int t = threadIdx.x, wave = t>>6, lane = t&63;
  const int l15 = lane&15, l4 = lane>>4;
  const int qt = blockIdx.x, bh = blockIdx.y;
  const short* Qh  = Q  + (size_t)bh*2048*64;
  const short* Kh  = Kb + (size_t)bh*2048*64;
  const short* Vth = Vb + (size_t)bh*64*2048;

  const int r7  = lane>>3;
  const int swz = ((lane&7) ^ r7) << 3;
  const int rr0 = wave*8 + r7, rr1 = 32 + wave*8 + r7;
  const size_t kOff0 = (size_t)rr0*64   + swz, kOff1 = (size_t)rr1*64   + swz;
  const size_t vOff0 = (size_t)rr0*2048 + swz, vOff1 = (size_t)rr1*2048 + swz;

  bf16x8 qf[2];
  #pragma unroll
  for (int kf=0;kf<2;kf++)
    qf[kf] = *(const bf16x8*)(Qh + (size_t)(qt*64 + wave*16 + l15)*64 + kf*32 + l4*8);

  f32x4 cacc[4] = {};
  float mrun = -1e30f, lrun = 0.f;

  #define STAGE(sel, kv0) do { \
    const short* ksp = Kh + (size_t)(kv0)*64; \
    const short* vsp = Vth + (kv0); \
    short* kd = &Kt[sel][wave*512]; \
    short* vd = &Vt[sel][wave*512]; \
    gload16(ksp + kOff0, kd); \
    gload16(ksp + kOff1, kd + 2048); \
    gload16(vsp + vOff0, vd); \
    gload16(vsp + vOff1, vd + 2048); \
  } while(0)

  STAGE(0, 0);

  for (int tt = 0; tt < 32; ++tt){
    const int cur = tt & 1;
    if (tt < 31){
      STAGE(cur^1, (tt+1)*64);
      asm volatile("s_waitcnt vmcnt(4)" ::: "memory");
    } else {
      asm volatile("s_waitcnt vmcnt(0)" ::: "memory");
    }
    __builtin_amdgcn_sched_barrier(0);
    __builtin_amdgcn_s_barrier();
    __builtin_amdgcn_sched_barrier(0);

    const short* KtC = &Kt[cur][0];
    const short* VtC = &Vt[cur][0];

    f32x4 sacc[4] = {};
    __builtin_amdgcn_s_setprio(1);
    #pragma unroll
    for (int kf=0;kf<2;kf++){
      #pragma unroll
      for (int mk=0;mk<4;mk++){
        int r = mk*16 + l15;
        bf16x8 kfr = *(const bf16x8*)(KtC + r*64 + (((kf*4+l4) ^ (l15&7))<<3));
        sacc[mk] = mfma16(kfr, qf[kf], sacc[mk]);
      }
    }
    __builtin_amdgcn_s_setprio(0);

    float mx = sacc[0][0];
    #pragma unroll
    for (int mk=0;mk<4;mk++)
      #pragma unroll
      for (int j=0;j<4;j++) mx = fmaxf(mx, sacc[mk][j]);
    mx = fmaxf(mx, __shfl_xor(mx, 16));
    mx = fmaxf(mx, __shfl_xor(mx, 32));
    if (!__all(mx - mrun <= 8.f)){
      float mnew = fmaxf(mrun, mx);
      float fac = __expf(mrun - mnew);
      mrun = mnew;
      lrun *= fac;
      #pragma unroll
      for (int j=0;j<4;j++){
        float fj = __shfl(fac, l4*4 + j);
        #pragma unroll
        for (int nf=0;nf<4;nf++) cacc[nf][j] *= fj;
      }
    }
    float psum = 0.f;
    #pragma unroll
    for (int mk=0;mk<4;mk++)
      #pragma unroll
      for (int j=0;j<4;j++){
        float pv = __expf(sacc[mk][j] - mrun);
        sacc[mk][j] = pv; psum += pv;
      }
    psum += __shfl_xor(psum, 16);
    psum += __shfl_xor(psum, 32);
    lrun += psum;

    int pk01[4], pk23[4];
    #pragma unroll
    for (int mk=0;mk<4;mk++){
      pk01[mk] = cvtpk(sacc[mk][0], sacc[mk][1]);
      pk23[mk] = cvtpk(sacc[mk][2], sacc[mk][3]);
    }

    #pragma unroll
    for (int ks=0;ks<2;ks++){
      int srcA = l15 + ((l4&1)<<5);
      int srcB = srcA + 16;
      int hi = l4>>1;
      int w0a = __shfl(pk01[2*ks], srcA), w0b = __shfl(pk01[2*ks+1], srcA);
      int w1a = __shfl(pk23[2*ks], srcA), w1b = __shfl(pk23[2*ks+1], srcA);
      int w2a = __shfl(pk01[2*ks], srcB), w2b = __shfl(pk01[2*ks+1], srcB);
      int w3a = __shfl(pk23[2*ks], srcB), w3b = __shfl(pk23[2*ks+1], srcB);
      union { int w[4]; bf16x8 v; } pa;
      pa.w[0] = hi ? w0b : w0a;
      pa.w[1] = hi ? w1b : w1a;
      pa.w[2] = hi ? w2b : w2a;
      pa.w[3] = hi ? w3b : w3a;
      __builtin_amdgcn_s_setprio(1);
      #pragma unroll
      for (int nf=0;nf<4;nf++){
        int dh = nf*16 + l15;
        bf16x8 vf = *(const bf16x8*)(VtC + dh*64 + (((ks*4+l4) ^ (dh&7))<<3));
        cacc[nf] = mfma16(pa.v, vf, cacc[nf]);
      }
      __builtin_amdgcn_s_setprio(0);
    }

    __builtin_amdgcn_sched_barrier(0);
    __builtin_amdgcn_s_barrier();
  }
  #undef STAGE

  const int b = bh/12, h = bh%12;
  #pragma unroll
  for (int j=0;j<4;j++){
    float inv = 1.f / __shfl(lrun, l4*4 + j);
    int s = qt*64 + wave*16 + l4*4 + j;
    size_t base = ((size_t)b*2048 + s)*768 + h*64;
    #pragma unroll
    for (int nf=0;nf<4;nf++)
      ctx[base + nf*16 + l15] = f2bf(cacc[nf][j] * inv);
  }
}

extern "C" void kernel_launch(void* const* d_in, const int* in_sizes, int n_in,
                              void* d_out, int out_size, void* d_ws, size_t ws_size,
                              hipStream_t stream){
  (void)in_sizes; (void)n_in; (void)out_size;
  const float* src   = (const float*)d_in[0];
  const float* wq    = (const float*)d_in[1];
  const float* bq    = (const float*)d_in[2];
  const float* wk    = (const float*)d_in[3];
  const float* bk    = (const float*)d_in[4];
  const float* wv    = (const float*)d_in[5];
  const float* bv    = (const float*)d_in[6];
  const float* wo    = (const float*)d_in[7];
  const float* bo    = (const float*)d_in[8];
  const float* wfc1  = (const float*)d_in[9];
  const float* bfc1  = (const float*)d_in[10];
  const float* win   = (const float*)d_in[11];
  const float* wgate = (const float*)d_in[12];
  const float* wfc2  = (const float*)d_in[13];
  const float* bfc2  = (const float*)d_in[14];
  const float* gattn = (const float*)d_in[15];
  const float* gffn  = (const float*)d_in[16];

  char* ws = (char*)d_ws;
  constexpr size_t SZ_W768  = 768ull*768*2;
  constexpr size_t SZ_WFC   = 3072ull*768*2;
  constexpr size_t SZ_WFF   = 3072ull*3072*2;
  constexpr size_t SZ_ACT   = 4096ull*768*2;
  constexpr size_t SZ_ACTF  = 4096ull*768*4;
  constexpr size_t SZ_H     = 4096ull*3072*2;
  constexpr size_t OFF_WQ    = 0;
  constexpr size_t OFF_WK    = OFF_WQ + SZ_W768;
  constexpr size_t OFF_WV    = OFF_WK + SZ_W768;
  constexpr size_t OFF_WO    = OFF_WV + SZ_W768;
  constexpr size_t OFF_WFC1  = OFF_WO + SZ_W768;
  constexpr size_t OFF_WIN   = OFF_WFC1 + SZ_WFC;
  constexpr size_t OFF_WGATE = OFF_WIN + SZ_WFF;
  constexpr size_t OFF_WFC2  = OFF_WGATE + SZ_WFF;
  constexpr size_t OFF_XN    = OFF_WFC2 + SZ_WFC;
  constexpr size_t OFF_Q     = OFF_XN + SZ_ACT;
  constexpr size_t OFF_K     = OFF_Q + SZ_ACT;
  constexpr size_t OFF_V     = OFF_K + SZ_ACT;
  constexpr size_t OFF_RES   = OFF_V + SZ_ACT;
  constexpr size_t OFF_HIN   = OFF_RES + SZ_ACTF;
  constexpr size_t OFF_H2    = OFF_HIN + SZ_H;
  constexpr size_t WS_NEED   = OFF_H2 + SZ_H;
  if (ws_size < WS_NEED) return;

  short* wq_b    = (short*)(ws+OFF_WQ);
  short* wfc1_b  = (short*)(ws+OFF_WFC1);
  short* win_b   = (short*)(ws+OFF_WIN);
  short* wgate_b = (short*)(ws+OFF_WGATE);
  short* wfc2_b  = (short*)(ws+OFF_WFC2);
  short* wo_b    = (short*)(ws+OFF_WO);
  short* xn      = (short*)(ws+OFF_XN);
  short* ctxb    = (short*)(ws+OFF_XN);
  short* qb      = (short*)(ws+OFF_Q);
  short* yb      = (short*)(ws+OFF_Q);
  short* kb2     = (short*)(ws+OFF_K);
  short* vb2     = (short*)(ws+OFF_V);
  float* resid   = (float*)(ws+OFF_RES);
  short* h1      = (short*)(ws+OFF_K);
  short* h2      = (short*)(ws+OFF_H2);
  float* partA   = (float*)(ws+OFF_HIN);   // 2 x 12.58MB (hin region, free)
  float* partB   = (float*)(ws+OFF_K);     // 2 x 12.58MB (h1 region, free after ffglu)

  k_convert8<<<25344, 256, 0, stream>>>(wq, wk, wv, wo, wfc1, win, wgate, wfc2, wq_b);

  k_rmsnorm<<<1024, 256, 0, stream>>>(src, gattn, xn);

  k_gemm<EPI_QKV><<<dim3(18,32), 256, 0, stream>>>(xn, wq_b, qb, bq, kb2, bk, bv, vb2, 4096, 2304, 768);

  k_attn<<<dim3(32, 24), 256, 0, stream>>>(qb, kb2, vb2, ctxb);

  k_gemm<EPI_RESID><<<dim3(6,32), 256, 0, stream>>>(ctxb, wo_b, resid, bo, src, nullptr, nullptr, nullptr, 4096, 768, 768);
  k_rmsnorm<<<1024, 256, 0, stream>>>(resid, gffn, yb);

  k_ff<EPI_BF16><<<dim3(8,32), 512, 0, stream>>>(yb, wfc1_b, h1, bfc1, nullptr, 3072, 768);

  // fused SwiGLU, 2-phase pipelined: h2 = (h1@win^T) * silu(h1@wgate^T)
  k_ffglu<<<dim3(48,16), 256, 0, stream>>>(h1, win_b, wgate_b, h2);

  // fc2 split-K=4 + fused reduce (bias + y residual) -> d_out
  k_part<<<dim3(6,32,4), 256, 0, stream>>>(h2, wfc2_b, partA, partB);
  k_fc2red<<<3072, 256, 0, stream>>>(partA, partB, bfc2, yb, (float*)d_out);
}